// Round 2
// baseline (1096.934 us; speedup 1.0000x reference)
//
#include <hip/hip_runtime.h>

#define D_MODEL   2048
#define D_INNER   4096
#define HEADDIM   64
#define NHEADS    64
#define D_STATE   128
#define CHUNK     256
#define CONV_DIM  4352
#define D_IN_PROJ 8512
#define NPAD      8576
#define NX        4480      // xBC + dt + pad columns (35*128)
#define BATCH     2
#define SEQ       2048
#define NCHUNK    8
#define NROWS     4096
#define EPSV      1e-5f

typedef __attribute__((ext_vector_type(8))) short bf16x8;
typedef __attribute__((ext_vector_type(4))) float f32x4;

#define AS1 __attribute__((address_space(1)))
#define AS3 __attribute__((address_space(3)))

__device__ __forceinline__ unsigned short f2bf(float f) {
  unsigned int x = __float_as_uint(f);
  unsigned int r = (x + 0x7fffu + ((x >> 16) & 1u)) >> 16;
  return (unsigned short)r;
}
__device__ __forceinline__ float bf2f(unsigned short u) {
  return __uint_as_float((unsigned int)u << 16);
}

__global__ void k_sentinel(float* out) { if (threadIdx.x == 0) out[0] = 1.0e6f; }

// ---------------- converts ----------------
__global__ void k_f32_to_bf16_v4(const float* __restrict__ in, unsigned short* __restrict__ out, long n4) {
  long i = (long)blockIdx.x * blockDim.x + threadIdx.x;
  long stride = (long)gridDim.x * blockDim.x;
  for (; i < n4; i += stride) {
    float4 v = ((const float4*)in)[i];
    ushort4 o = make_ushort4(f2bf(v.x), f2bf(v.y), f2bf(v.z), f2bf(v.w));
    ((ushort4*)out)[i] = o;
  }
}

__global__ void k_convert_win(const float* __restrict__ W, unsigned short* __restrict__ out) {
  const long n4 = (long)NPAD * D_MODEL / 4;
  const long valid4 = (long)D_IN_PROJ * D_MODEL / 4;
  long i = (long)blockIdx.x * blockDim.x + threadIdx.x;
  long stride = (long)gridDim.x * blockDim.x;
  for (; i < n4; i += stride) {
    ushort4 o = make_ushort4(0, 0, 0, 0);
    if (i < valid4) {
      float4 v = ((const float4*)W)[i];
      o = make_ushort4(f2bf(v.x), f2bf(v.y), f2bf(v.z), f2bf(v.w));
    }
    ((ushort4*)out)[i] = o;
  }
}

// ---------------- GEMM (A[M][K] @ B[N][K]^T -> C[M][N]), bf16 MFMA ----------------
template <int BF16OUT>
__global__ __launch_bounds__(256) void k_gemm_bt(const unsigned short* __restrict__ A,
                                                 const unsigned short* __restrict__ B,
                                                 void* __restrict__ Cv, int M, int N, int K) {
  __shared__ short As[128 * 32];
  __shared__ short Bs[128 * 32];
  const int t = threadIdx.x;
  const int lane = t & 63;
  const int wr = (t >> 7) & 1;
  const int wc = (t >> 6) & 1;
  const int m0 = blockIdx.y * 128;
  const int n0 = blockIdx.x * 128;

  f32x4 acc[4][4];
#pragma unroll
  for (int i = 0; i < 4; ++i)
#pragma unroll
    for (int j = 0; j < 4; ++j) { f32x4 z = {0.f, 0.f, 0.f, 0.f}; acc[i][j] = z; }

  const unsigned short* gA0 = A + (size_t)(m0 + (t >> 2)) * K + (t & 3) * 8;
  const unsigned short* gA1 = gA0 + (size_t)64 * K;
  const unsigned short* gB0 = B + (size_t)(n0 + (t >> 2)) * K + (t & 3) * 8;
  const unsigned short* gB1 = gB0 + (size_t)64 * K;
  char* lA0 = (char*)As + t * 16;
  char* lA1 = lA0 + 4096;
  char* lB0 = (char*)Bs + t * 16;
  char* lB1 = lB0 + 4096;

  const int kofs = (lane >> 4) * 8;
  const int ra = wr * 64 + (lane & 15);
  const int rb = wc * 64 + (lane & 15);

  for (int kt = 0; kt < K; kt += 32) {
    __syncthreads();
    __builtin_amdgcn_global_load_lds((const AS1 void*)(gA0 + kt), (AS3 void*)lA0, 16, 0, 0);
    __builtin_amdgcn_global_load_lds((const AS1 void*)(gA1 + kt), (AS3 void*)lA1, 16, 0, 0);
    __builtin_amdgcn_global_load_lds((const AS1 void*)(gB0 + kt), (AS3 void*)lB0, 16, 0, 0);
    __builtin_amdgcn_global_load_lds((const AS1 void*)(gB1 + kt), (AS3 void*)lB1, 16, 0, 0);
    asm volatile("s_waitcnt vmcnt(0)" ::: "memory");
    __syncthreads();

    bf16x8 af[4], bfr[4];
#pragma unroll
    for (int i = 0; i < 4; ++i) af[i] = *(const bf16x8*)(As + (ra + i * 16) * 32 + kofs);
#pragma unroll
    for (int j = 0; j < 4; ++j) bfr[j] = *(const bf16x8*)(Bs + (rb + j * 16) * 32 + kofs);
#pragma unroll
    for (int i = 0; i < 4; ++i)
#pragma unroll
      for (int j = 0; j < 4; ++j)
        acc[i][j] = __builtin_amdgcn_mfma_f32_16x16x32_bf16(af[i], bfr[j], acc[i][j], 0, 0, 0);
  }

  const int crow = (lane >> 4) * 4;
  const int ccol = lane & 15;
#pragma unroll
  for (int i = 0; i < 4; ++i)
#pragma unroll
    for (int j = 0; j < 4; ++j) {
      size_t base = (size_t)(m0 + wr * 64 + i * 16 + crow) * N + (n0 + wc * 64 + j * 16 + ccol);
      if (BF16OUT) {
        unsigned short* C = (unsigned short*)Cv;
#pragma unroll
        for (int r = 0; r < 4; ++r) C[base + (size_t)r * N] = f2bf(acc[i][j][r]);
      } else {
        float* C = (float*)Cv;
#pragma unroll
        for (int r = 0; r < 4; ++r) C[base + (size_t)r * N] = acc[i][j][r];
      }
    }
}

// ---------------- dt: exact f32 skinny GEMM + softplus ----------------
__global__ __launch_bounds__(256) void k_dt(const float* __restrict__ u, const float* __restrict__ W_in,
                                            const float* __restrict__ dt_bias, float* __restrict__ dt_t) {
  __shared__ float Wl[64][129];
  __shared__ float ul[4][128];
  const int t = threadIdx.x;
  const int r = t >> 6, h = t & 63;
  const int row0 = blockIdx.x * 4;
  float acc = 0.f;
  for (int k0 = 0; k0 < D_MODEL; k0 += 128) {
    __syncthreads();
    for (int i = t; i < 64 * 128; i += 256) { int rr = i >> 7, kk = i & 127; Wl[rr][kk] = W_in[(size_t)(8448 + rr) * D_MODEL + k0 + kk]; }
    for (int i = t; i < 4 * 128; i += 256) { int rr = i >> 7, kk = i & 127; ul[rr][kk] = u[(size_t)(row0 + rr) * D_MODEL + k0 + kk]; }
    __syncthreads();
#pragma unroll 8
    for (int kk = 0; kk < 128; ++kk) acc += ul[r][kk] * Wl[h][kk];
  }
  float x = acc + dt_bias[h];
  float dtv = (x > 20.f) ? x : log1pf(expf(x));
  int row = row0 + r; int b = row >> 11; int l = row & 2047;
  dt_t[((size_t)(b * NHEADS + h)) * SEQ + l] = dtv;
}

// ---------------- conv1d + silu (bf16 in/out) ----------------
__global__ void k_conv_silu(const unsigned short* __restrict__ xb, const float* __restrict__ conv_w,
                            const float* __restrict__ conv_b, unsigned short* __restrict__ out) {
  const long n = (long)NROWS * CONV_DIM;
  long idx = (long)blockIdx.x * blockDim.x + threadIdx.x;
  long stride = (long)gridDim.x * blockDim.x;
  for (; idx < n; idx += stride) {
    int ch = (int)(idx % CONV_DIM);
    long bl = idx / CONV_DIM;
    int l = (int)(bl & (SEQ - 1));
    long brow = bl - l;
    float acc = conv_b[ch];
#pragma unroll
    for (int w = 0; w < 4; ++w) {
      int ls = l + w - 3;
      if (ls >= 0) acc += bf2f(xb[(brow + ls) * (long)NX + ch]) * conv_w[ch * 4 + w];
    }
    out[bl * (long)CONV_DIM + ch] = f2bf(acc / (1.f + expf(-acc)));
  }
}

// ---------------- per-chunk cumsum of dA ----------------
__global__ __launch_bounds__(256) void k_cumsum(const float* __restrict__ dt_t, const float* __restrict__ A_log,
                                                float* __restrict__ A_cum) {
  const int bid = blockIdx.x;           // (b*NHEADS+h)*NCHUNK + c
  const int c = bid & 7;
  const int bh = bid >> 3;
  const int h = bh & 63;
  const int l = threadIdx.x;
  float A = -expf(A_log[h]);
  __shared__ float s[256];
  s[l] = dt_t[(size_t)bh * SEQ + c * CHUNK + l] * A;
  __syncthreads();
  for (int off = 1; off < 256; off <<= 1) {
    float x = (l >= off) ? s[l - off] : 0.f;
    __syncthreads();
    s[l] += x;
    __syncthreads();
  }
  A_cum[(size_t)bid * CHUNK + l] = s[l];
}

// ---------------- CBTT[s][l] = B_s . C_l  per (b,c) ----------------
__global__ __launch_bounds__(256) void k_cbtt(const unsigned short* __restrict__ xbc, float* __restrict__ cbtt) {
  const int bid = blockIdx.x;           // (b*NCHUNK+c)*4 + stile
  const int stile = bid & 3;
  const int bc = bid >> 2;
  const int b = bc >> 3, c = bc & 7;
  __shared__ float Bl[64][132];
  __shared__ float Cl[32][132];
  const int t = threadIdx.x;
  const int sr = t >> 2, q = t & 3;
  const long rowbase = (long)b * SEQ + c * CHUNK;
  for (int i = t; i < 64 * 128; i += 256) {
    int rr = i >> 7, n = i & 127;
    Bl[rr][n] = bf2f(xbc[(rowbase + stile * 64 + rr) * (long)CONV_DIM + D_INNER + n]);
  }
  float* outbase = cbtt + (long)bc * CHUNK * CHUNK;
  for (int lp = 0; lp < 8; ++lp) {
    __syncthreads();
    for (int i = t; i < 32 * 128; i += 256) {
      int rr = i >> 7, n = i & 127;
      Cl[rr][n] = bf2f(xbc[(rowbase + lp * 32 + rr) * (long)CONV_DIM + D_INNER + D_STATE + n]);
    }
    __syncthreads();
    for (int li = q * 8; li < q * 8 + 8; ++li) {
      float acc = 0.f;
#pragma unroll 8
      for (int n = 0; n < 128; ++n) acc += Bl[sr][n] * Cl[li][n];
      outbase[(long)(stile * 64 + sr) * CHUNK + lp * 32 + li] = acc;
    }
  }
}

// ---------------- per-(b,c,h) chunk states ----------------
__global__ __launch_bounds__(256) void k_states(const unsigned short* __restrict__ xbc, const float* __restrict__ dt_t,
                                                const float* __restrict__ A_cum, float* __restrict__ states) {
  const int bid = blockIdx.x;           // (b*NCHUNK+c)*NHEADS + h
  const int h = bid & 63;
  const int bc = bid >> 6;
  const int b = bc >> 3, c = bc & 7;
  const int t = threadIdx.x;
  const int p = t & 63;
  const int j0 = (t >> 6) * 32;
  __shared__ __align__(16) float xl[64][64];
  __shared__ __align__(16) float Blds[64][128];
  __shared__ float wv[64];
  const long rowbase = (long)b * SEQ + c * CHUNK;
  const long bh8 = ((long)(b * NHEADS + h)) * NCHUNK + c;
  const float cs_last = A_cum[bh8 * CHUNK + 255];
  const float* dtp = dt_t + (size_t)(b * NHEADS + h) * SEQ + c * CHUNK;
  float acc[32];
#pragma unroll
  for (int j = 0; j < 32; ++j) acc[j] = 0.f;
  for (int lp = 0; lp < 4; ++lp) {
    __syncthreads();
    for (int i = t; i < 64 * 64; i += 256) { int rr = i >> 6, pp = i & 63; xl[rr][pp] = bf2f(xbc[(rowbase + lp * 64 + rr) * (long)CONV_DIM + h * HEADDIM + pp]); }
    for (int i = t; i < 64 * 128; i += 256) { int rr = i >> 7, n = i & 127; Blds[rr][n] = bf2f(xbc[(rowbase + lp * 64 + rr) * (long)CONV_DIM + D_INNER + n]); }
    if (t < 64) wv[t] = expf(cs_last - A_cum[bh8 * CHUNK + lp * 64 + t]) * dtp[lp * 64 + t];
    __syncthreads();
    for (int i = 0; i < 64; ++i) {
      float xw = wv[i] * xl[i][p];
#pragma unroll
      for (int j4 = 0; j4 < 8; ++j4) {
        float4 bv = *(const float4*)&Blds[i][j0 + j4 * 4];
        acc[j4 * 4 + 0] += xw * bv.x;
        acc[j4 * 4 + 1] += xw * bv.y;
        acc[j4 * 4 + 2] += xw * bv.z;
        acc[j4 * 4 + 3] += xw * bv.w;
      }
    }
  }
  float* sp = states + ((long)bc * NHEADS + h) * (HEADDIM * D_STATE) + p * D_STATE + j0;
#pragma unroll
  for (int j = 0; j < 32; ++j) sp[j] = acc[j];
}

// ---------------- inter-chunk scan -> prev_states ----------------
__global__ void k_scan(const float* __restrict__ states, const float* __restrict__ A_cum, float* __restrict__ PS) {
  long idx = (long)blockIdx.x * blockDim.x + threadIdx.x;   // ((b*NHEADS+h)*HEADDIM+p)*D_STATE+n
  if (idx >= (long)BATCH * NHEADS * HEADDIM * D_STATE) return;
  int n = idx & 127;
  long rest = idx >> 7;
  int p = (int)(rest & 63);
  long bh = rest >> 6;           // b*NHEADS+h
  int h = (int)(bh & 63);
  int b = (int)(bh >> 6);
  float S = 0.f;
  for (int c = 0; c < NCHUNK; ++c) {
    long soff = (((long)(b * NCHUNK + c) * NHEADS + h) * (HEADDIM * D_STATE)) + p * D_STATE + n;
    PS[soff] = S;
    float decay = expf(A_cum[(bh * NCHUNK + c) * CHUNK + 255]);
    S = S * decay + states[soff];
  }
}

// ---------------- Y = Y_diag + Y_off + x*D (bf16 out) ----------------
__global__ __launch_bounds__(256) void k_y(const unsigned short* __restrict__ xbc, const float* __restrict__ dt_t,
                                           const float* __restrict__ A_cum, const float* __restrict__ cbtt,
                                           const float* __restrict__ PS, const float* __restrict__ Dp,
                                           unsigned short* __restrict__ y) {
  const int bid = blockIdx.x;           // (b*NCHUNK+c)*NHEADS + h
  const int h = bid & 63;
  const int bc = bid >> 6;
  const int b = bc >> 3, c = bc & 7;
  const int t = threadIdx.x;            // = l
  __shared__ __align__(16) float PST[128][68];
  __shared__ __align__(16) float pool[4352];     // Cl[256][17] phase1 / xl[64][64] phase2
  __shared__ float csl[64], dtl[64];
  float (*Cl)[17] = (float(*)[17])pool;
  float (*xl)[64] = (float(*)[64])pool;
  const long rowbase = (long)b * SEQ + c * CHUNK;
  const long bh8 = ((long)(b * NHEADS + h)) * NCHUNK + c;
  const float* acum = A_cum + bh8 * CHUNK;
  const float cs_l = acum[t];
  const float* psbase = PS + ((long)bc * NHEADS + h) * (HEADDIM * D_STATE);
  for (int i = t; i < D_STATE * HEADDIM; i += 256) {
    int n = i & 127, p = i >> 7;
    PST[n][p] = psbase[(long)p * D_STATE + n];
  }
  float yacc[64];
#pragma unroll
  for (int p = 0; p < 64; ++p) yacc[p] = 0.f;

  // phase 1: Y_off (pre-scale)
  for (int qq = 0; qq < 8; ++qq) {
    __syncthreads();
    for (int i = t; i < 256 * 16; i += 256) {
      int rr = i >> 4, nn = i & 15;
      Cl[rr][nn] = bf2f(xbc[(rowbase + rr) * (long)CONV_DIM + (D_INNER + D_STATE) + qq * 16 + nn]);
    }
    __syncthreads();
    for (int nn = 0; nn < 16; ++nn) {
      float cv = Cl[t][nn];
      int n = qq * 16 + nn;
#pragma unroll
      for (int p4 = 0; p4 < 16; ++p4) {
        float4 pv = *(const float4*)&PST[n][p4 * 4];
        yacc[p4 * 4 + 0] += cv * pv.x;
        yacc[p4 * 4 + 1] += cv * pv.y;
        yacc[p4 * 4 + 2] += cv * pv.z;
        yacc[p4 * 4 + 3] += cv * pv.w;
      }
    }
  }
  {
    float el = expf(cs_l);
#pragma unroll
    for (int p = 0; p < 64; ++p) yacc[p] *= el;
  }

  // phase 2: Y_diag
  const float* cbt = cbtt + (long)bc * (CHUNK * CHUNK);
  const float* dtp = dt_t + ((long)(b * NHEADS + h)) * SEQ + c * CHUNK;
  const int wvid = t >> 6;
  for (int sp = 0; sp < 4; ++sp) {
    __syncthreads();
    for (int i = t; i < 64 * 64; i += 256) {
      int rr = i >> 6, pp = i & 63;
      xl[rr][pp] = bf2f(xbc[(rowbase + sp * 64 + rr) * (long)CONV_DIM + h * HEADDIM + pp]);
    }
    if (t < 64) { csl[t] = acum[sp * 64 + t]; dtl[t] = dtp[sp * 64 + t]; }
    __syncthreads();
    if (sp > wvid) continue;            // whole wave has no s<=l in this panel
    for (int si = 0; si < 64; ++si) {
      int s = sp * 64 + si;
      float w = 0.f;
      if (s <= t) w = cbt[(long)s * CHUNK + t] * expf(cs_l - csl[si]) * dtl[si];
#pragma unroll
      for (int p4 = 0; p4 < 16; ++p4) {
        float4 xv = *(const float4*)&xl[si][p4 * 4];
        yacc[p4 * 4 + 0] += w * xv.x;
        yacc[p4 * 4 + 1] += w * xv.y;
        yacc[p4 * 4 + 2] += w * xv.z;
        yacc[p4 * 4 + 3] += w * xv.w;
      }
    }
  }

  // skip connection + store (bf16)
  const float Dh = Dp[h];
  const unsigned short* xrow = xbc + (rowbase + t) * (long)CONV_DIM + h * HEADDIM;
  unsigned short* yrow = y + (rowbase + t) * (long)D_INNER + h * HEADDIM;
#pragma unroll
  for (int p4 = 0; p4 < 16; ++p4) {
    ushort4 xv = *(const ushort4*)(xrow + p4 * 4);
    ushort4 o;
    o.x = f2bf(yacc[p4 * 4 + 0] + bf2f(xv.x) * Dh);
    o.y = f2bf(yacc[p4 * 4 + 1] + bf2f(xv.y) * Dh);
    o.z = f2bf(yacc[p4 * 4 + 2] + bf2f(xv.z) * Dh);
    o.w = f2bf(yacc[p4 * 4 + 3] + bf2f(xv.w) * Dh);
    *(ushort4*)(yrow + p4 * 4) = o;
  }
}

// ---------------- gated RMSNorm (bf16 y,z in; bf16 out, in-place over y ok) ----------------
__global__ __launch_bounds__(256) void k_norm(unsigned short* yz, const unsigned short* __restrict__ zb,
                                              const float* __restrict__ norm_w, unsigned short* out) {
  const int row = blockIdx.x;
  const int t = threadIdx.x;
  const unsigned short* yr = yz + (size_t)row * D_INNER;
  const unsigned short* zr = zb + (size_t)row * D_INNER;
  float yv[16];
  float ss = 0.f;
#pragma unroll
  for (int j = 0; j < 4; ++j) {
    int e = (t + j * 256) * 4;
    ushort4 yy = *(const ushort4*)(yr + e);
    ushort4 zz = *(const ushort4*)(zr + e);
    float z0 = bf2f(zz.x), z1 = bf2f(zz.y), z2 = bf2f(zz.z), z3 = bf2f(zz.w);
    float g0 = bf2f(yy.x) * z0 / (1.f + expf(-z0));
    float g1 = bf2f(yy.y) * z1 / (1.f + expf(-z1));
    float g2 = bf2f(yy.z) * z2 / (1.f + expf(-z2));
    float g3 = bf2f(yy.w) * z3 / (1.f + expf(-z3));
    ss += g0 * g0 + g1 * g1 + g2 * g2 + g3 * g3;
    yv[j * 4 + 0] = g0; yv[j * 4 + 1] = g1; yv[j * 4 + 2] = g2; yv[j * 4 + 3] = g3;
  }
#pragma unroll
  for (int off = 32; off > 0; off >>= 1) ss += __shfl_xor(ss, off);
  __shared__ float red[4];
  if ((t & 63) == 0) red[t >> 6] = ss;
  __syncthreads();
  float tot = red[0] + red[1] + red[2] + red[3];
  float scale = rsqrtf(tot / (float)D_INNER + EPSV);
  unsigned short* orow = out + (size_t)row * D_INNER;
#pragma unroll
  for (int j = 0; j < 4; ++j) {
    int e = (t + j * 256) * 4;
    float4 w = *(const float4*)(norm_w + e);
    ushort4 o = make_ushort4(f2bf(yv[j * 4 + 0] * scale * w.x), f2bf(yv[j * 4 + 1] * scale * w.y),
                             f2bf(yv[j * 4 + 2] * scale * w.z), f2bf(yv[j * 4 + 3] * scale * w.w));
    *(ushort4*)(orow + e) = o;
  }
}

extern "C" void kernel_launch(void* const* d_in, const int* in_sizes, int n_in,
                              void* d_out, int out_size, void* d_ws, size_t ws_size,
                              hipStream_t stream) {
  const float* u       = (const float*)d_in[0];
  const float* W_in    = (const float*)d_in[1];
  const float* conv_w  = (const float*)d_in[2];
  const float* conv_b  = (const float*)d_in[3];
  const float* dt_bias = (const float*)d_in[4];
  const float* A_log   = (const float*)d_in[5];
  const float* Dp      = (const float*)d_in[6];
  const float* norm_w  = (const float*)d_in[7];
  const float* W_out   = (const float*)d_in[8];
  float* out = (float*)d_out;

  char* ws = (char*)d_ws;
  size_t off = 0;
  auto alloc = [&](size_t bytes) { char* p = ws + off; off += (bytes + 255) & ~(size_t)255; return p; };
  unsigned short* ub   = (unsigned short*)alloc((size_t)NROWS * D_MODEL * 2);       // 16.8 MB; -> wob later
  unsigned short* winb = (unsigned short*)alloc((size_t)NPAD * D_MODEL * 2);        // 35.1 MB; -> ps later
  unsigned short* zb   = (unsigned short*)alloc((size_t)NROWS * D_INNER * 2);       // 33.6 MB
  unsigned short* xb   = (unsigned short*)alloc((size_t)NROWS * NX * 2);            // 36.7 MB; -> yb later
  unsigned short* xbcb = (unsigned short*)alloc((size_t)NROWS * CONV_DIM * 2);      // 35.7 MB
  float* dtt  = (float*)alloc((size_t)BATCH * NHEADS * SEQ * 4);                    // 2.1 MB
  float* acum = (float*)alloc((size_t)BATCH * NHEADS * NCHUNK * CHUNK * 4);         // 2.1 MB
  float* cbt  = (float*)alloc((size_t)BATCH * NCHUNK * CHUNK * CHUNK * 4);          // 4.2 MB
  unsigned short* wob = ub;                   // W_out bf16 (16.8 MB), after GEMM1s
  float* ps = (float*)winb;                   // prev_states (33.6 MB), after GEMM1s
  unsigned short* yb = xb;                    // y bf16 (33.6 MB), after conv
  float* states = (float*)d_out;              // 33.6 MB scratch == out_size; overwritten by GEMM2

  if (off > ws_size) {   // ws too small: write sentinel so the failure mode is identifiable
    k_sentinel<<<1, 64, 0, stream>>>(out);
    return;
  }

  k_f32_to_bf16_v4<<<2048, 256, 0, stream>>>(u, ub, (long)NROWS * D_MODEL / 4);
  k_convert_win<<<4096, 256, 0, stream>>>(W_in, winb);
  k_gemm_bt<1><<<dim3(D_INNER / 128, NROWS / 128), 256, 0, stream>>>(ub, winb, zb, NROWS, D_INNER, D_MODEL);
  k_gemm_bt<1><<<dim3(NX / 128, NROWS / 128), 256, 0, stream>>>(ub, winb + (size_t)D_INNER * D_MODEL, xb, NROWS, NX, D_MODEL);
  k_dt<<<NROWS / 4, 256, 0, stream>>>(u, W_in, dt_bias, dtt);
  k_conv_silu<<<4096, 256, 0, stream>>>(xb, conv_w, conv_b, xbcb);
  k_cumsum<<<BATCH * NHEADS * NCHUNK, 256, 0, stream>>>(dtt, A_log, acum);
  k_cbtt<<<BATCH * NCHUNK * 4, 256, 0, stream>>>(xbcb, cbt);
  k_states<<<BATCH * NCHUNK * NHEADS, 256, 0, stream>>>(xbcb, dtt, acum, states);
  k_scan<<<4096, 256, 0, stream>>>(states, acum, ps);
  k_y<<<BATCH * NCHUNK * NHEADS, 256, 0, stream>>>(xbcb, dtt, acum, cbt, ps, Dp, yb);
  k_norm<<<NROWS, 256, 0, stream>>>(yb, zb, norm_w, yb);
  k_f32_to_bf16_v4<<<2048, 256, 0, stream>>>(W_out, wob, (long)D_MODEL * D_INNER / 4);
  k_gemm_bt<0><<<dim3(D_MODEL / 128, NROWS / 128), 256, 0, stream>>>(yb, wob, out, NROWS, D_MODEL, D_INNER);
}

// Round 3
// 755.133 us; speedup vs baseline: 1.4526x; 1.4526x over previous
//
#include <hip/hip_runtime.h>

#define D_MODEL   2048
#define D_INNER   4096
#define HEADDIM   64
#define NHEADS    64
#define D_STATE   128
#define CHUNK     256
#define CONV_DIM  4352
#define D_IN_PROJ 8512
#define NPAD      8576
#define NX        4480      // xBC + dt + pad columns (35*128)
#define BATCH     2
#define SEQ       2048
#define NCHUNK    8
#define NROWS     4096
#define EPSV      1e-5f

typedef __attribute__((ext_vector_type(8))) short bf16x8;
typedef __attribute__((ext_vector_type(8))) unsigned short u16x8;
typedef __attribute__((ext_vector_type(4))) float f32x4;

#define AS1 __attribute__((address_space(1)))
#define AS3 __attribute__((address_space(3)))

__device__ __forceinline__ unsigned short f2bf(float f) {
  unsigned int x = __float_as_uint(f);
  unsigned int r = (x + 0x7fffu + ((x >> 16) & 1u)) >> 16;
  return (unsigned short)r;
}
__device__ __forceinline__ float bf2f(unsigned short u) {
  return __uint_as_float((unsigned int)u << 16);
}

__global__ void k_sentinel(float* out) { if (threadIdx.x == 0) out[0] = 1.0e6f; }

// ---------------- converts ----------------
__global__ void k_f32_to_bf16_v4(const float* __restrict__ in, unsigned short* __restrict__ out, long n4) {
  long i = (long)blockIdx.x * blockDim.x + threadIdx.x;
  long stride = (long)gridDim.x * blockDim.x;
  for (; i < n4; i += stride) {
    float4 v = ((const float4*)in)[i];
    ushort4 o = make_ushort4(f2bf(v.x), f2bf(v.y), f2bf(v.z), f2bf(v.w));
    ((ushort4*)out)[i] = o;
  }
}

__global__ void k_convert_win(const float* __restrict__ W, unsigned short* __restrict__ out) {
  const long n4 = (long)NPAD * D_MODEL / 4;
  const long valid4 = (long)D_IN_PROJ * D_MODEL / 4;
  long i = (long)blockIdx.x * blockDim.x + threadIdx.x;
  long stride = (long)gridDim.x * blockDim.x;
  for (; i < n4; i += stride) {
    ushort4 o = make_ushort4(0, 0, 0, 0);
    if (i < valid4) {
      float4 v = ((const float4*)W)[i];
      o = make_ushort4(f2bf(v.x), f2bf(v.y), f2bf(v.z), f2bf(v.w));
    }
    ((ushort4*)out)[i] = o;
  }
}

// ---------------- GEMM (A[M][K] @ B[N][K]^T -> C[M][N]), bf16 MFMA ----------------
template <int BF16OUT>
__global__ __launch_bounds__(256) void k_gemm_bt(const unsigned short* __restrict__ A,
                                                 const unsigned short* __restrict__ B,
                                                 void* __restrict__ Cv, int M, int N, int K) {
  __shared__ short As[128 * 32];
  __shared__ short Bs[128 * 32];
  const int t = threadIdx.x;
  const int lane = t & 63;
  const int wr = (t >> 7) & 1;
  const int wc = (t >> 6) & 1;
  const int m0 = blockIdx.y * 128;
  const int n0 = blockIdx.x * 128;

  f32x4 acc[4][4];
#pragma unroll
  for (int i = 0; i < 4; ++i)
#pragma unroll
    for (int j = 0; j < 4; ++j) { f32x4 z = {0.f, 0.f, 0.f, 0.f}; acc[i][j] = z; }

  const unsigned short* gA0 = A + (size_t)(m0 + (t >> 2)) * K + (t & 3) * 8;
  const unsigned short* gA1 = gA0 + (size_t)64 * K;
  const unsigned short* gB0 = B + (size_t)(n0 + (t >> 2)) * K + (t & 3) * 8;
  const unsigned short* gB1 = gB0 + (size_t)64 * K;
  char* lA0 = (char*)As + t * 16;
  char* lA1 = lA0 + 4096;
  char* lB0 = (char*)Bs + t * 16;
  char* lB1 = lB0 + 4096;

  const int kofs = (lane >> 4) * 8;
  const int ra = wr * 64 + (lane & 15);
  const int rb = wc * 64 + (lane & 15);

  for (int kt = 0; kt < K; kt += 32) {
    __syncthreads();
    __builtin_amdgcn_global_load_lds((const AS1 void*)(gA0 + kt), (AS3 void*)lA0, 16, 0, 0);
    __builtin_amdgcn_global_load_lds((const AS1 void*)(gA1 + kt), (AS3 void*)lA1, 16, 0, 0);
    __builtin_amdgcn_global_load_lds((const AS1 void*)(gB0 + kt), (AS3 void*)lB0, 16, 0, 0);
    __builtin_amdgcn_global_load_lds((const AS1 void*)(gB1 + kt), (AS3 void*)lB1, 16, 0, 0);
    asm volatile("s_waitcnt vmcnt(0)" ::: "memory");
    __syncthreads();

    bf16x8 af[4], bfr[4];
#pragma unroll
    for (int i = 0; i < 4; ++i) af[i] = *(const bf16x8*)(As + (ra + i * 16) * 32 + kofs);
#pragma unroll
    for (int j = 0; j < 4; ++j) bfr[j] = *(const bf16x8*)(Bs + (rb + j * 16) * 32 + kofs);
#pragma unroll
    for (int i = 0; i < 4; ++i)
#pragma unroll
      for (int j = 0; j < 4; ++j)
        acc[i][j] = __builtin_amdgcn_mfma_f32_16x16x32_bf16(af[i], bfr[j], acc[i][j], 0, 0, 0);
  }

  const int crow = (lane >> 4) * 4;
  const int ccol = lane & 15;
#pragma unroll
  for (int i = 0; i < 4; ++i)
#pragma unroll
    for (int j = 0; j < 4; ++j) {
      size_t base = (size_t)(m0 + wr * 64 + i * 16 + crow) * N + (n0 + wc * 64 + j * 16 + ccol);
      if (BF16OUT) {
        unsigned short* C = (unsigned short*)Cv;
#pragma unroll
        for (int r = 0; r < 4; ++r) C[base + (size_t)r * N] = f2bf(acc[i][j][r]);
      } else {
        float* C = (float*)Cv;
#pragma unroll
        for (int r = 0; r < 4; ++r) C[base + (size_t)r * N] = acc[i][j][r];
      }
    }
}

// ---------------- dt: exact f32 skinny GEMM + softplus ----------------
__global__ __launch_bounds__(256) void k_dt(const float* __restrict__ u, const float* __restrict__ W_in,
                                            const float* __restrict__ dt_bias, float* __restrict__ dt_t) {
  __shared__ float Wl[64][129];
  __shared__ float ul[4][128];
  const int t = threadIdx.x;
  const int r = t >> 6, h = t & 63;
  const int row0 = blockIdx.x * 4;
  float acc = 0.f;
  for (int k0 = 0; k0 < D_MODEL; k0 += 128) {
    __syncthreads();
    for (int i = t; i < 64 * 128; i += 256) { int rr = i >> 7, kk = i & 127; Wl[rr][kk] = W_in[(size_t)(8448 + rr) * D_MODEL + k0 + kk]; }
    for (int i = t; i < 4 * 128; i += 256) { int rr = i >> 7, kk = i & 127; ul[rr][kk] = u[(size_t)(row0 + rr) * D_MODEL + k0 + kk]; }
    __syncthreads();
#pragma unroll 8
    for (int kk = 0; kk < 128; ++kk) acc += ul[r][kk] * Wl[h][kk];
  }
  float x = acc + dt_bias[h];
  float dtv = (x > 20.f) ? x : log1pf(expf(x));
  int row = row0 + r; int b = row >> 11; int l = row & 2047;
  dt_t[((size_t)(b * NHEADS + h)) * SEQ + l] = dtv;
}

// ---------------- conv1d + silu (bf16 in/out, 8 channels/thread) ----------------
__global__ void k_conv_silu(const unsigned short* __restrict__ xb, const float* __restrict__ conv_w,
                            const float* __restrict__ conv_b, unsigned short* __restrict__ out) {
  long idx = (long)blockIdx.x * blockDim.x + threadIdx.x;   // over NROWS*CONV_DIM/8
  if (idx >= (long)NROWS * CONV_DIM / 8) return;
  int c8 = (int)(idx % (CONV_DIM / 8));
  long bl = idx / (CONV_DIM / 8);
  int l = (int)(bl & (SEQ - 1));
  long brow = bl - l;
  int ch0 = c8 * 8;
  float acc[8];
#pragma unroll
  for (int e = 0; e < 8; ++e) acc[e] = conv_b[ch0 + e];
#pragma unroll
  for (int w = 0; w < 4; ++w) {
    int ls = l + w - 3;
    if (ls >= 0) {
      u16x8 xv = *(const u16x8*)(xb + (brow + ls) * (long)NX + ch0);
#pragma unroll
      for (int e = 0; e < 8; ++e) acc[e] += bf2f(xv[e]) * conv_w[(ch0 + e) * 4 + w];
    }
  }
  u16x8 o;
#pragma unroll
  for (int e = 0; e < 8; ++e) o[e] = f2bf(acc[e] / (1.f + expf(-acc[e])));
  *(u16x8*)(out + bl * (long)CONV_DIM + ch0) = o;
}

// ---------------- per-chunk cumsum of dA ----------------
__global__ __launch_bounds__(256) void k_cumsum(const float* __restrict__ dt_t, const float* __restrict__ A_log,
                                                float* __restrict__ A_cum) {
  const int bid = blockIdx.x;           // (b*NHEADS+h)*NCHUNK + c
  const int c = bid & 7;
  const int bh = bid >> 3;
  const int h = bh & 63;
  const int l = threadIdx.x;
  float A = -expf(A_log[h]);
  __shared__ float s[256];
  s[l] = dt_t[(size_t)bh * SEQ + c * CHUNK + l] * A;
  __syncthreads();
  for (int off = 1; off < 256; off <<= 1) {
    float x = (l >= off) ? s[l - off] : 0.f;
    __syncthreads();
    s[l] += x;
    __syncthreads();
  }
  A_cum[(size_t)bid * CHUNK + l] = s[l];
}

// ---------------- CBT^T[l][s] = C_l . B_s  (bf16 out), MFMA ----------------
__global__ __launch_bounds__(256) void k_cbtt(const unsigned short* __restrict__ xbc, unsigned short* __restrict__ cbt_t) {
  const int bid = blockIdx.x;           // bc*4 + sp
  const int sp = bid & 3;
  const int bc = bid >> 2;
  const int b = bc >> 3, c = bc & 7;
  const int t = threadIdx.x;
  const int lane = t & 63;
  const int w = t >> 6;
  const int g = lane >> 4;
  __shared__ unsigned short Cs[256][72];   // A operand: C rows, n-panel 64
  __shared__ unsigned short Bs2[64][72];   // B operand: B rows (s-panel)
  const long rowbase = (long)b * SEQ + c * CHUNK;
  f32x4 acc[4][4];
#pragma unroll
  for (int i = 0; i < 4; ++i)
#pragma unroll
    for (int j = 0; j < 4; ++j) { f32x4 z = {0.f, 0.f, 0.f, 0.f}; acc[i][j] = z; }

  for (int np = 0; np < 2; ++np) {
    __syncthreads();
    for (int i = t; i < 256 * 16; i += 256) {   // C: cols D_INNER+D_STATE + np*64 + ...
      int row = i >> 4, c4 = (i & 15) * 4;
      ushort4 v = *(const ushort4*)(xbc + (rowbase + row) * (long)CONV_DIM + D_INNER + D_STATE + np * 64 + c4);
      *(ushort4*)&Cs[row][c4] = v;
    }
    for (int i = t; i < 64 * 16; i += 256) {    // B: rows sp*64+..., cols D_INNER + np*64 + ...
      int row = i >> 4, c4 = (i & 15) * 4;
      ushort4 v = *(const ushort4*)(xbc + (rowbase + sp * 64 + row) * (long)CONV_DIM + D_INNER + np * 64 + c4);
      *(ushort4*)&Bs2[row][c4] = v;
    }
    __syncthreads();
#pragma unroll
    for (int ks = 0; ks < 2; ++ks) {
      const int kofs = ks * 32 + g * 8;
      bf16x8 af[4], bfr[4];
#pragma unroll
      for (int i = 0; i < 4; ++i) af[i] = *(const bf16x8*)&Cs[w * 64 + i * 16 + (lane & 15)][kofs];
#pragma unroll
      for (int j = 0; j < 4; ++j) bfr[j] = *(const bf16x8*)&Bs2[j * 16 + (lane & 15)][kofs];
#pragma unroll
      for (int i = 0; i < 4; ++i)
#pragma unroll
        for (int j = 0; j < 4; ++j)
          acc[i][j] = __builtin_amdgcn_mfma_f32_16x16x32_bf16(af[i], bfr[j], acc[i][j], 0, 0, 0);
    }
  }
  // store CBT^T[l][s] bf16; row l = w*64+i*16+(lane>>4)*4+r, col s = sp*64+j*16+(lane&15)
  unsigned short* ob = cbt_t + (long)bc * CHUNK * CHUNK;
#pragma unroll
  for (int i = 0; i < 4; ++i)
#pragma unroll
    for (int j = 0; j < 4; ++j) {
      int l0 = w * 64 + i * 16 + g * 4;
      int s = sp * 64 + j * 16 + (lane & 15);
#pragma unroll
      for (int r = 0; r < 4; ++r) ob[(long)(l0 + r) * CHUNK + s] = f2bf(acc[i][j][r]);
    }
}

// ---------------- states[n][p] = sum_l B[l][n]*w_l*x[l][p], MFMA ----------------
__global__ __launch_bounds__(256) void k_states(const unsigned short* __restrict__ xbc, const float* __restrict__ dt_t,
                                                const float* __restrict__ A_cum, float* __restrict__ states) {
  const int bid = blockIdx.x;           // bc*NHEADS + h
  const int h = bid & 63;
  const int bc = bid >> 6;
  const int b = bc >> 3, c = bc & 7;
  const int t = threadIdx.x;
  const int lane = t & 63;
  const int w = t >> 6;
  const int g = lane >> 4;
  __shared__ unsigned short BT[128][72];   // B^T (n rows, l cols)
  __shared__ unsigned short WXT[64][72];   // (w.x)^T (p rows, l cols)
  __shared__ float csL[256], dtL[256];
  const long rowbase = (long)b * SEQ + c * CHUNK;
  const long bh8 = ((long)(b * NHEADS + h)) * NCHUNK + c;
  const float* acum = A_cum + bh8 * CHUNK;
  if (t < 256) { csL[t] = acum[t]; dtL[t] = dt_t[((size_t)(b * NHEADS + h)) * SEQ + c * CHUNK + t]; }
  float cs_last = acum[255];
  f32x4 acc[2][4];
#pragma unroll
  for (int i = 0; i < 2; ++i)
#pragma unroll
    for (int j = 0; j < 4; ++j) { f32x4 z = {0.f, 0.f, 0.f, 0.f}; acc[i][j] = z; }

  for (int lp = 0; lp < 4; ++lp) {
    __syncthreads();
    for (int i = t; i < 64 * 32; i += 256) {   // B^T staging
      int l = i >> 5, n4 = (i & 31) * 4;
      ushort4 v = *(const ushort4*)(xbc + (rowbase + lp * 64 + l) * (long)CONV_DIM + D_INNER + n4);
      BT[n4 + 0][l] = v.x; BT[n4 + 1][l] = v.y; BT[n4 + 2][l] = v.z; BT[n4 + 3][l] = v.w;
    }
    for (int i = t; i < 64 * 16; i += 256) {   // (w*x)^T staging
      int l = i >> 4, p4 = (i & 15) * 4;
      int lg = lp * 64 + l;
      float wgt = expf(cs_last - csL[lg]) * dtL[lg];
      ushort4 v = *(const ushort4*)(xbc + (rowbase + lg) * (long)CONV_DIM + h * HEADDIM + p4);
      WXT[p4 + 0][l] = f2bf(bf2f(v.x) * wgt);
      WXT[p4 + 1][l] = f2bf(bf2f(v.y) * wgt);
      WXT[p4 + 2][l] = f2bf(bf2f(v.z) * wgt);
      WXT[p4 + 3][l] = f2bf(bf2f(v.w) * wgt);
    }
    __syncthreads();
#pragma unroll
    for (int ks = 0; ks < 2; ++ks) {
      const int kofs = ks * 32 + g * 8;
      bf16x8 am[2], bp[4];
#pragma unroll
      for (int i = 0; i < 2; ++i) am[i] = *(const bf16x8*)&BT[w * 32 + i * 16 + (lane & 15)][kofs];
#pragma unroll
      for (int j = 0; j < 4; ++j) bp[j] = *(const bf16x8*)&WXT[j * 16 + (lane & 15)][kofs];
#pragma unroll
      for (int i = 0; i < 2; ++i)
#pragma unroll
        for (int j = 0; j < 4; ++j)
          acc[i][j] = __builtin_amdgcn_mfma_f32_16x16x32_bf16(am[i], bp[j], acc[i][j], 0, 0, 0);
    }
  }
  float* sp = states + ((long)bc * NHEADS + h) * (D_STATE * HEADDIM);
#pragma unroll
  for (int i = 0; i < 2; ++i)
#pragma unroll
    for (int j = 0; j < 4; ++j) {
      int n0 = w * 32 + i * 16 + g * 4;
      int p = j * 16 + (lane & 15);
#pragma unroll
      for (int r = 0; r < 4; ++r) sp[(long)(n0 + r) * HEADDIM + p] = acc[i][j][r];
    }
}

// ---------------- inter-chunk scan -> prev_states (bf16, [n][p]) ----------------
__global__ void k_scan(const float* __restrict__ states, const float* __restrict__ A_cum, unsigned short* __restrict__ psb) {
  long idx = (long)blockIdx.x * blockDim.x + threadIdx.x;   // ((b*64+h)*128+n)*64+p
  if (idx >= (long)BATCH * NHEADS * D_STATE * HEADDIM) return;
  int p = idx & 63;
  int n = (int)((idx >> 6) & 127);
  long bh = idx >> 13;
  int h = (int)(bh & 63);
  int b = (int)(bh >> 6);
  float S = 0.f;
  for (int c = 0; c < NCHUNK; ++c) {
    long soff = (((long)(b * NCHUNK + c) * NHEADS + h) * (D_STATE * HEADDIM)) + (long)n * HEADDIM + p;
    psb[soff] = f2bf(S);
    float decay = expf(A_cum[(bh * NCHUNK + c) * CHUNK + 255]);
    S = S * decay + states[soff];
  }
}

// ---------------- Y = Y_diag + Y_off + x*D (bf16 out), MFMA ----------------
__global__ __launch_bounds__(256) void k_y(const unsigned short* __restrict__ xbc, const float* __restrict__ dt_t,
                                           const float* __restrict__ A_cum, const unsigned short* __restrict__ cbt_t,
                                           const unsigned short* __restrict__ psb, const float* __restrict__ Dp,
                                           unsigned short* __restrict__ y) {
  const int bid = blockIdx.x;           // bc*NHEADS + h
  const int h = bid & 63;
  const int bc = bid >> 6;
  const int b = bc >> 3, c = bc & 7;
  const int t = threadIdx.x;
  const int lane = t & 63;
  const int w = t >> 6;
  const int g = lane >> 4;
  __shared__ unsigned short Abuf[256][72];   // C' (Y_off A operand)
  __shared__ unsigned short Bbuf[64][72];    // PS panel (Y_off) / x^T panel (diag)
  __shared__ float csL[256], dtL[256], expL[256];
  const long rowbase = (long)b * SEQ + c * CHUNK;
  const long bh8 = ((long)(b * NHEADS + h)) * NCHUNK + c;
  const float* acum = A_cum + bh8 * CHUNK;
  if (t < 256) {
    float cv = acum[t];
    csL[t] = cv;
    expL[t] = expf(cv);
    dtL[t] = dt_t[((size_t)(b * NHEADS + h)) * SEQ + c * CHUNK + t];
  }
  f32x4 acc[4][4];
#pragma unroll
  for (int i = 0; i < 4; ++i)
#pragma unroll
    for (int j = 0; j < 4; ++j) { f32x4 z = {0.f, 0.f, 0.f, 0.f}; acc[i][j] = z; }

  // ---- phase 1: Y_off = (C .* exp(cs_l)) @ PS^T, K = 128 in 2 panels ----
  const unsigned short* psbase = psb + ((long)bc * NHEADS + h) * (D_STATE * HEADDIM);
  for (int np = 0; np < 2; ++np) {
    __syncthreads();
    for (int i = t; i < 256 * 16; i += 256) {
      int row = i >> 4, c4 = (i & 15) * 4;
      float el = expL[row];
      ushort4 v = *(const ushort4*)(xbc + (rowbase + row) * (long)CONV_DIM + D_INNER + D_STATE + np * 64 + c4);
      ushort4 o = make_ushort4(f2bf(bf2f(v.x) * el), f2bf(bf2f(v.y) * el), f2bf(bf2f(v.z) * el), f2bf(bf2f(v.w) * el));
      *(ushort4*)&Abuf[row][c4] = o;
    }
    for (int i = t; i < 64 * 16; i += 256) {   // PS^T staging: read [n][p], write [p][n]
      int n = i >> 4, p4 = (i & 15) * 4;
      ushort4 v = *(const ushort4*)(psbase + (long)(np * 64 + n) * HEADDIM + p4);
      Bbuf[p4 + 0][n] = v.x; Bbuf[p4 + 1][n] = v.y; Bbuf[p4 + 2][n] = v.z; Bbuf[p4 + 3][n] = v.w;
    }
    __syncthreads();
#pragma unroll
    for (int ks = 0; ks < 2; ++ks) {
      const int kofs = ks * 32 + g * 8;
      bf16x8 af[4], bfr[4];
#pragma unroll
      for (int i = 0; i < 4; ++i) af[i] = *(const bf16x8*)&Abuf[w * 64 + i * 16 + (lane & 15)][kofs];
#pragma unroll
      for (int j = 0; j < 4; ++j) bfr[j] = *(const bf16x8*)&Bbuf[j * 16 + (lane & 15)][kofs];
#pragma unroll
      for (int i = 0; i < 4; ++i)
#pragma unroll
        for (int j = 0; j < 4; ++j)
          acc[i][j] = __builtin_amdgcn_mfma_f32_16x16x32_bf16(af[i], bfr[j], acc[i][j], 0, 0, 0);
    }
  }

  // ---- phase 2: Y_diag, scores in-register, K = 256 in 4 panels ----
  const unsigned short* cbtb = cbt_t + (long)bc * CHUNK * CHUNK;
  for (int sp = 0; sp < 4; ++sp) {
    __syncthreads();
    for (int i = t; i < 64 * 8; i += 256) {    // x^T staging: read x[s][p], write [p][s]
      int s = i >> 3, p0 = (i & 7) * 8;
      u16x8 v = *(const u16x8*)(xbc + (rowbase + sp * 64 + s) * (long)CONV_DIM + h * HEADDIM + p0);
#pragma unroll
      for (int e = 0; e < 8; ++e) Bbuf[p0 + e][s] = v[e];
    }
    __syncthreads();
    if (sp > w) continue;                      // wave's l-range entirely above panel
#pragma unroll
    for (int ks = 0; ks < 2; ++ks) {
      const int kofs = ks * 32 + g * 8;
      bf16x8 bfr[4];
#pragma unroll
      for (int j = 0; j < 4; ++j) bfr[j] = *(const bf16x8*)&Bbuf[j * 16 + (lane & 15)][kofs];
      const int sbase = sp * 64 + ks * 32 + g * 8;
#pragma unroll
      for (int i = 0; i < 4; ++i) {
        if (sp == w && ks * 32 > i * 16 + 15) continue;   // fully-masked fragment
        const int l = w * 64 + i * 16 + (lane & 15);
        u16x8 cv = *(const u16x8*)(cbtb + (long)l * CHUNK + sbase);
        const float cl = csL[l];
        bf16x8 af;
#pragma unroll
        for (int e = 0; e < 8; ++e) {
          int s = sbase + e;
          float val = (s <= l) ? bf2f(cv[e]) * expf(cl - csL[s]) * dtL[s] : 0.f;
          af[e] = (short)f2bf(val);
        }
#pragma unroll
        for (int j = 0; j < 4; ++j)
          acc[i][j] = __builtin_amdgcn_mfma_f32_16x16x32_bf16(af, bfr[j], acc[i][j], 0, 0, 0);
      }
    }
  }

  // ---- epilogue: skip connection + bf16 store ----
  const float Dh = Dp[h];
#pragma unroll
  for (int i = 0; i < 4; ++i) {
    int l0 = w * 64 + i * 16 + g * 4;
#pragma unroll
    for (int r = 0; r < 4; ++r) {
      long grow = rowbase + l0 + r;
      const unsigned short* xrow = xbc + grow * (long)CONV_DIM + h * HEADDIM;
      unsigned short* yrow = y + grow * (long)D_INNER + h * HEADDIM;
#pragma unroll
      for (int j = 0; j < 4; ++j) {
        int p = j * 16 + (lane & 15);
        yrow[p] = f2bf(acc[i][j][r] + bf2f(xrow[p]) * Dh);
      }
    }
  }
}

// ---------------- gated RMSNorm (bf16 y,z in; bf16 out, in-place over y ok) ----------------
__global__ __launch_bounds__(256) void k_norm(unsigned short* yz, const unsigned short* __restrict__ zb,
                                              const float* __restrict__ norm_w, unsigned short* out) {
  const int row = blockIdx.x;
  const int t = threadIdx.x;
  const unsigned short* yr = yz + (size_t)row * D_INNER;
  const unsigned short* zr = zb + (size_t)row * D_INNER;
  float yv[16];
  float ss = 0.f;
#pragma unroll
  for (int j = 0; j < 4; ++j) {
    int e = (t + j * 256) * 4;
    ushort4 yy = *(const ushort4*)(yr + e);
    ushort4 zz = *(const ushort4*)(zr + e);
    float z0 = bf2f(zz.x), z1 = bf2f(zz.y), z2 = bf2f(zz.z), z3 = bf2f(zz.w);
    float g0 = bf2f(yy.x) * z0 / (1.f + expf(-z0));
    float g1 = bf2f(yy.y) * z1 / (1.f + expf(-z1));
    float g2 = bf2f(yy.z) * z2 / (1.f + expf(-z2));
    float g3 = bf2f(yy.w) * z3 / (1.f + expf(-z3));
    ss += g0 * g0 + g1 * g1 + g2 * g2 + g3 * g3;
    yv[j * 4 + 0] = g0; yv[j * 4 + 1] = g1; yv[j * 4 + 2] = g2; yv[j * 4 + 3] = g3;
  }
#pragma unroll
  for (int off = 32; off > 0; off >>= 1) ss += __shfl_xor(ss, off);
  __shared__ float red[4];
  if ((t & 63) == 0) red[t >> 6] = ss;
  __syncthreads();
  float tot = red[0] + red[1] + red[2] + red[3];
  float scale = rsqrtf(tot / (float)D_INNER + EPSV);
  unsigned short* orow = out + (size_t)row * D_INNER;
#pragma unroll
  for (int j = 0; j < 4; ++j) {
    int e = (t + j * 256) * 4;
    float4 w = *(const float4*)(norm_w + e);
    ushort4 o = make_ushort4(f2bf(yv[j * 4 + 0] * scale * w.x), f2bf(yv[j * 4 + 1] * scale * w.y),
                             f2bf(yv[j * 4 + 2] * scale * w.z), f2bf(yv[j * 4 + 3] * scale * w.w));
    *(ushort4*)(orow + e) = o;
  }
}

extern "C" void kernel_launch(void* const* d_in, const int* in_sizes, int n_in,
                              void* d_out, int out_size, void* d_ws, size_t ws_size,
                              hipStream_t stream) {
  const float* u       = (const float*)d_in[0];
  const float* W_in    = (const float*)d_in[1];
  const float* conv_w  = (const float*)d_in[2];
  const float* conv_b  = (const float*)d_in[3];
  const float* dt_bias = (const float*)d_in[4];
  const float* A_log   = (const float*)d_in[5];
  const float* Dp      = (const float*)d_in[6];
  const float* norm_w  = (const float*)d_in[7];
  const float* W_out   = (const float*)d_in[8];
  float* out = (float*)d_out;

  char* ws = (char*)d_ws;
  size_t off = 0;
  auto alloc = [&](size_t bytes) { char* p = ws + off; off += (bytes + 255) & ~(size_t)255; return p; };
  unsigned short* ub   = (unsigned short*)alloc((size_t)NROWS * D_MODEL * 2);       // -> wob later
  unsigned short* winb = (unsigned short*)alloc((size_t)NPAD * D_MODEL * 2);        // -> cbt_t + psb later
  unsigned short* zb   = (unsigned short*)alloc((size_t)NROWS * D_INNER * 2);
  unsigned short* xb   = (unsigned short*)alloc((size_t)NROWS * NX * 2);            // -> yb later
  unsigned short* xbcb = (unsigned short*)alloc((size_t)NROWS * CONV_DIM * 2);
  float* dtt  = (float*)alloc((size_t)BATCH * NHEADS * SEQ * 4);
  float* acum = (float*)alloc((size_t)BATCH * NHEADS * NCHUNK * CHUNK * 4);
  unsigned short* wob = ub;                        // W_out bf16, after GEMM1s
  unsigned short* cbt = winb;                      // CBT^T bf16 (2.1 MB), after GEMM1s
  unsigned short* psb = winb + (size_t)BATCH * NCHUNK * CHUNK * CHUNK + 1024;  // prev_states bf16 (2.1 MB)
  unsigned short* yb = xb;                         // y bf16, after conv
  float* states = (float*)d_out;                   // 33.6 MB scratch == out_size; overwritten by GEMM2

  if (off > ws_size) {
    k_sentinel<<<1, 64, 0, stream>>>(out);
    return;
  }

  k_f32_to_bf16_v4<<<2048, 256, 0, stream>>>(u, ub, (long)NROWS * D_MODEL / 4);
  k_convert_win<<<4096, 256, 0, stream>>>(W_in, winb);
  k_gemm_bt<1><<<dim3(D_INNER / 128, NROWS / 128), 256, 0, stream>>>(ub, winb, zb, NROWS, D_INNER, D_MODEL);
  k_gemm_bt<1><<<dim3(NX / 128, NROWS / 128), 256, 0, stream>>>(ub, winb + (size_t)D_INNER * D_MODEL, xb, NROWS, NX, D_MODEL);
  k_dt<<<NROWS / 4, 256, 0, stream>>>(u, W_in, dt_bias, dtt);
  k_conv_silu<<<(NROWS * (CONV_DIM / 8) + 255) / 256, 256, 0, stream>>>(xb, conv_w, conv_b, xbcb);
  k_cumsum<<<BATCH * NHEADS * NCHUNK, 256, 0, stream>>>(dtt, A_log, acum);
  k_cbtt<<<BATCH * NCHUNK * 4, 256, 0, stream>>>(xbcb, cbt);
  k_states<<<BATCH * NCHUNK * NHEADS, 256, 0, stream>>>(xbcb, dtt, acum, states);
  k_scan<<<(BATCH * NHEADS * D_STATE * HEADDIM + 255) / 256, 256, 0, stream>>>(states, acum, psb);
  k_y<<<BATCH * NCHUNK * NHEADS, 256, 0, stream>>>(xbcb, dtt, acum, cbt, psb, Dp, yb);
  k_norm<<<NROWS, 256, 0, stream>>>(yb, zb, norm_w, yb);
  k_f32_to_bf16_v4<<<2048, 256, 0, stream>>>(W_out, wob, (long)D_MODEL * D_INNER / 4);
  k_gemm_bt<0><<<dim3(D_MODEL / 128, NROWS / 128), 256, 0, stream>>>(yb, wob, out, NROWS, D_MODEL, D_INNER);
}

// Round 4
// 650.657 us; speedup vs baseline: 1.6859x; 1.1606x over previous
//
#include <hip/hip_runtime.h>

#define D_MODEL   2048
#define D_INNER   4096
#define HEADDIM   64
#define NHEADS    64
#define D_STATE   128
#define CHUNK     256
#define CONV_DIM  4352
#define D_IN_PROJ 8512
#define NPAD      8576
#define NX        4480      // xBC + dt + pad columns (35*128)
#define BATCH     2
#define SEQ       2048
#define NCHUNK    8
#define NROWS     4096
#define EPSV      1e-5f
#define CG        (CONV_DIM / 8)   // 544

typedef __attribute__((ext_vector_type(8))) short bf16x8;
typedef __attribute__((ext_vector_type(8))) unsigned short u16x8;
typedef __attribute__((ext_vector_type(4))) float f32x4;

#define AS1 __attribute__((address_space(1)))
#define AS3 __attribute__((address_space(3)))

__device__ __forceinline__ unsigned short f2bf(float f) {
  unsigned int x = __float_as_uint(f);
  unsigned int r = (x + 0x7fffu + ((x >> 16) & 1u)) >> 16;
  return (unsigned short)r;
}
__device__ __forceinline__ float bf2f(unsigned short u) {
  return __uint_as_float((unsigned int)u << 16);
}

__global__ void k_sentinel(float* out) { if (threadIdx.x == 0) out[0] = 1.0e6f; }

// ---------------- converts ----------------
__global__ void k_f32_to_bf16_v4(const float* __restrict__ in, unsigned short* __restrict__ out, long n4) {
  long i = (long)blockIdx.x * blockDim.x + threadIdx.x;
  long stride = (long)gridDim.x * blockDim.x;
  for (; i < n4; i += stride) {
    float4 v = ((const float4*)in)[i];
    ushort4 o = make_ushort4(f2bf(v.x), f2bf(v.y), f2bf(v.z), f2bf(v.w));
    ((ushort4*)out)[i] = o;
  }
}

__global__ void k_convert_win(const float* __restrict__ W, unsigned short* __restrict__ out) {
  const long n4 = (long)NPAD * D_MODEL / 4;
  const long valid4 = (long)D_IN_PROJ * D_MODEL / 4;
  long i = (long)blockIdx.x * blockDim.x + threadIdx.x;
  long stride = (long)gridDim.x * blockDim.x;
  for (; i < n4; i += stride) {
    ushort4 o = make_ushort4(0, 0, 0, 0);
    if (i < valid4) {
      float4 v = ((const float4*)W)[i];
      o = make_ushort4(f2bf(v.x), f2bf(v.y), f2bf(v.z), f2bf(v.w));
    }
    ((ushort4*)out)[i] = o;
  }
}

// ---------------- GEMM (A[M][K] @ B[N][K]^T -> C[M][N]), bf16 MFMA ----------------
template <int BF16OUT>
__global__ __launch_bounds__(256) void k_gemm_bt(const unsigned short* __restrict__ A,
                                                 const unsigned short* __restrict__ B,
                                                 void* __restrict__ Cv, int M, int N, int K) {
  __shared__ short As[128 * 32];
  __shared__ short Bs[128 * 32];
  const int t = threadIdx.x;
  const int lane = t & 63;
  const int wr = (t >> 7) & 1;
  const int wc = (t >> 6) & 1;
  const int m0 = blockIdx.y * 128;
  const int n0 = blockIdx.x * 128;

  f32x4 acc[4][4];
#pragma unroll
  for (int i = 0; i < 4; ++i)
#pragma unroll
    for (int j = 0; j < 4; ++j) { f32x4 z = {0.f, 0.f, 0.f, 0.f}; acc[i][j] = z; }

  const unsigned short* gA0 = A + (size_t)(m0 + (t >> 2)) * K + (t & 3) * 8;
  const unsigned short* gA1 = gA0 + (size_t)64 * K;
  const unsigned short* gB0 = B + (size_t)(n0 + (t >> 2)) * K + (t & 3) * 8;
  const unsigned short* gB1 = gB0 + (size_t)64 * K;
  char* lA0 = (char*)As + t * 16;
  char* lA1 = lA0 + 4096;
  char* lB0 = (char*)Bs + t * 16;
  char* lB1 = lB0 + 4096;

  const int kofs = (lane >> 4) * 8;
  const int ra = wr * 64 + (lane & 15);
  const int rb = wc * 64 + (lane & 15);

  for (int kt = 0; kt < K; kt += 32) {
    __syncthreads();
    __builtin_amdgcn_global_load_lds((const AS1 void*)(gA0 + kt), (AS3 void*)lA0, 16, 0, 0);
    __builtin_amdgcn_global_load_lds((const AS1 void*)(gA1 + kt), (AS3 void*)lA1, 16, 0, 0);
    __builtin_amdgcn_global_load_lds((const AS1 void*)(gB0 + kt), (AS3 void*)lB0, 16, 0, 0);
    __builtin_amdgcn_global_load_lds((const AS1 void*)(gB1 + kt), (AS3 void*)lB1, 16, 0, 0);
    asm volatile("s_waitcnt vmcnt(0)" ::: "memory");
    __syncthreads();

    bf16x8 af[4], bfr[4];
#pragma unroll
    for (int i = 0; i < 4; ++i) af[i] = *(const bf16x8*)(As + (ra + i * 16) * 32 + kofs);
#pragma unroll
    for (int j = 0; j < 4; ++j) bfr[j] = *(const bf16x8*)(Bs + (rb + j * 16) * 32 + kofs);
#pragma unroll
    for (int i = 0; i < 4; ++i)
#pragma unroll
      for (int j = 0; j < 4; ++j)
        acc[i][j] = __builtin_amdgcn_mfma_f32_16x16x32_bf16(af[i], bfr[j], acc[i][j], 0, 0, 0);
  }

  const int crow = (lane >> 4) * 4;
  const int ccol = lane & 15;
#pragma unroll
  for (int i = 0; i < 4; ++i)
#pragma unroll
    for (int j = 0; j < 4; ++j) {
      size_t base = (size_t)(m0 + wr * 64 + i * 16 + crow) * N + (n0 + wc * 64 + j * 16 + ccol);
      if (BF16OUT) {
        unsigned short* C = (unsigned short*)Cv;
#pragma unroll
        for (int r = 0; r < 4; ++r) C[base + (size_t)r * N] = f2bf(acc[i][j][r]);
      } else {
        float* C = (float*)Cv;
#pragma unroll
        for (int r = 0; r < 4; ++r) C[base + (size_t)r * N] = acc[i][j][r];
      }
    }
}

// ---------------- dt: exact f32 skinny GEMM + softplus (16 rows/block) ----------------
__global__ __launch_bounds__(256) void k_dt(const float* __restrict__ u, const float* __restrict__ W_in,
                                            const float* __restrict__ dt_bias, float* __restrict__ dt_t) {
  __shared__ float Wl[64][132];
  __shared__ float ul[16][132];
  const int t = threadIdx.x;
  const int h = t & 63, rg = t >> 6;     // 4 rows per thread
  const int row0 = blockIdx.x * 16;
  float acc[4] = {0.f, 0.f, 0.f, 0.f};
  for (int k0 = 0; k0 < D_MODEL; k0 += 128) {
    __syncthreads();
    for (int i = t; i < 64 * 32; i += 256) {
      int rr = i >> 5, k4 = (i & 31) * 4;
      float4 v = *(const float4*)(W_in + (size_t)(8448 + rr) * D_MODEL + k0 + k4);
      Wl[rr][k4] = v.x; Wl[rr][k4 + 1] = v.y; Wl[rr][k4 + 2] = v.z; Wl[rr][k4 + 3] = v.w;
    }
    for (int i = t; i < 16 * 32; i += 256) {
      int rr = i >> 5, k4 = (i & 31) * 4;
      float4 v = *(const float4*)(u + (size_t)(row0 + rr) * D_MODEL + k0 + k4);
      ul[rr][k4] = v.x; ul[rr][k4 + 1] = v.y; ul[rr][k4 + 2] = v.z; ul[rr][k4 + 3] = v.w;
    }
    __syncthreads();
#pragma unroll 4
    for (int kk = 0; kk < 128; ++kk) {
      float wv = Wl[h][kk];
#pragma unroll
      for (int r = 0; r < 4; ++r) acc[r] += ul[rg * 4 + r][kk] * wv;
    }
  }
#pragma unroll
  for (int r = 0; r < 4; ++r) {
    float x = acc[r] + dt_bias[h];
    float dtv = (x > 20.f) ? x : log1pf(expf(x));
    int row = row0 + rg * 4 + r; int b = row >> 11; int l = row & 2047;
    dt_t[((size_t)(b * NHEADS + h)) * SEQ + l] = dtv;
  }
}

// ---------------- conv weight/bias pack: f32 -> bf16 transposed ----------------
__global__ void k_conv_pack(const float* __restrict__ cw, const float* __restrict__ cb,
                            unsigned short* __restrict__ wT, unsigned short* __restrict__ bT) {
  int i = blockIdx.x * blockDim.x + threadIdx.x;
  if (i < CONV_DIM) {
#pragma unroll
    for (int w = 0; w < 4; ++w) wT[w * CONV_DIM + i] = f2bf(cw[i * 4 + w]);
    bT[i] = f2bf(cb[i]);
  }
}

// ---------------- conv1d + silu: 8 channels x 4 rows per thread ----------------
__global__ __launch_bounds__(256) void k_conv_silu(const unsigned short* __restrict__ xb,
                                                   const unsigned short* __restrict__ wT,
                                                   const unsigned short* __restrict__ bT,
                                                   unsigned short* __restrict__ out) {
  long idx = (long)blockIdx.x * blockDim.x + threadIdx.x;   // over (NROWS/4)*CG
  if (idx >= (long)(NROWS / 4) * CG) return;
  int c8 = (int)(idx % CG);
  long rq = idx / CG;                      // row-quad id; 512 per batch
  int l0 = (int)((rq & (SEQ / 4 - 1)) * 4);
  long brow = (rq >> 9) * (long)SEQ;       // batch base row
  int ch0 = c8 * 8;

  u16x8 wv[4];
#pragma unroll
  for (int w = 0; w < 4; ++w) wv[w] = *(const u16x8*)(wT + w * CONV_DIM + ch0);
  u16x8 bv = *(const u16x8*)(bT + ch0);

  u16x8 xr[7];
#pragma unroll
  for (int i = 0; i < 7; ++i) {
    int ls = l0 - 3 + i;
    if (ls >= 0) xr[i] = *(const u16x8*)(xb + (brow + ls) * (long)NX + ch0);
    else { u16x8 z = {0, 0, 0, 0, 0, 0, 0, 0}; xr[i] = z; }
  }

#pragma unroll
  for (int r = 0; r < 4; ++r) {
    float acc[8];
#pragma unroll
    for (int e = 0; e < 8; ++e) acc[e] = bf2f(bv[e]);
#pragma unroll
    for (int w = 0; w < 4; ++w)
#pragma unroll
      for (int e = 0; e < 8; ++e) acc[e] += bf2f(xr[r + w][e]) * bf2f(wv[w][e]);
    u16x8 o;
#pragma unroll
    for (int e = 0; e < 8; ++e) o[e] = f2bf(acc[e] / (1.f + expf(-acc[e])));
    *(u16x8*)(out + (brow + l0 + r) * (long)CONV_DIM + ch0) = o;
  }
}

// ---------------- per-chunk cumsum of dA ----------------
__global__ __launch_bounds__(256) void k_cumsum(const float* __restrict__ dt_t, const float* __restrict__ A_log,
                                                float* __restrict__ A_cum) {
  const int bid = blockIdx.x;           // (b*NHEADS+h)*NCHUNK + c
  const int c = bid & 7;
  const int bh = bid >> 3;
  const int h = bh & 63;
  const int l = threadIdx.x;
  float A = -expf(A_log[h]);
  __shared__ float s[256];
  s[l] = dt_t[(size_t)bh * SEQ + c * CHUNK + l] * A;
  __syncthreads();
  for (int off = 1; off < 256; off <<= 1) {
    float x = (l >= off) ? s[l - off] : 0.f;
    __syncthreads();
    s[l] += x;
    __syncthreads();
  }
  A_cum[(size_t)bid * CHUNK + l] = s[l];
}

// ---------------- CBT^T[l][s] = C_l . B_s  (bf16 out), MFMA ----------------
__global__ __launch_bounds__(256) void k_cbtt(const unsigned short* __restrict__ xbc, unsigned short* __restrict__ cbt_t) {
  const int bid = blockIdx.x;           // bc*4 + sp
  const int sp = bid & 3;
  const int bc = bid >> 2;
  const int b = bc >> 3, c = bc & 7;
  const int t = threadIdx.x;
  const int lane = t & 63;
  const int w = t >> 6;
  const int g = lane >> 4;
  __shared__ unsigned short Cs[256][72];
  __shared__ unsigned short Bs2[64][72];
  const long rowbase = (long)b * SEQ + c * CHUNK;
  f32x4 acc[4][4];
#pragma unroll
  for (int i = 0; i < 4; ++i)
#pragma unroll
    for (int j = 0; j < 4; ++j) { f32x4 z = {0.f, 0.f, 0.f, 0.f}; acc[i][j] = z; }

  for (int np = 0; np < 2; ++np) {
    __syncthreads();
    for (int i = t; i < 256 * 16; i += 256) {
      int row = i >> 4, c4 = (i & 15) * 4;
      ushort4 v = *(const ushort4*)(xbc + (rowbase + row) * (long)CONV_DIM + D_INNER + D_STATE + np * 64 + c4);
      *(ushort4*)&Cs[row][c4] = v;
    }
    for (int i = t; i < 64 * 16; i += 256) {
      int row = i >> 4, c4 = (i & 15) * 4;
      ushort4 v = *(const ushort4*)(xbc + (rowbase + sp * 64 + row) * (long)CONV_DIM + D_INNER + np * 64 + c4);
      *(ushort4*)&Bs2[row][c4] = v;
    }
    __syncthreads();
#pragma unroll
    for (int ks = 0; ks < 2; ++ks) {
      const int kofs = ks * 32 + g * 8;
      bf16x8 af[4], bfr[4];
#pragma unroll
      for (int i = 0; i < 4; ++i) af[i] = *(const bf16x8*)&Cs[w * 64 + i * 16 + (lane & 15)][kofs];
#pragma unroll
      for (int j = 0; j < 4; ++j) bfr[j] = *(const bf16x8*)&Bs2[j * 16 + (lane & 15)][kofs];
#pragma unroll
      for (int i = 0; i < 4; ++i)
#pragma unroll
        for (int j = 0; j < 4; ++j)
          acc[i][j] = __builtin_amdgcn_mfma_f32_16x16x32_bf16(af[i], bfr[j], acc[i][j], 0, 0, 0);
    }
  }
  unsigned short* ob = cbt_t + (long)bc * CHUNK * CHUNK;
#pragma unroll
  for (int i = 0; i < 4; ++i)
#pragma unroll
    for (int j = 0; j < 4; ++j) {
      int l0 = w * 64 + i * 16 + g * 4;
      int s = sp * 64 + j * 16 + (lane & 15);
#pragma unroll
      for (int r = 0; r < 4; ++r) ob[(long)(l0 + r) * CHUNK + s] = f2bf(acc[i][j][r]);
    }
}

// ---------------- states[n][p] = sum_l B[l][n]*w_l*x[l][p], MFMA ----------------
__global__ __launch_bounds__(256) void k_states(const unsigned short* __restrict__ xbc, const float* __restrict__ dt_t,
                                                const float* __restrict__ A_cum, float* __restrict__ states) {
  const int bid = blockIdx.x;           // bc*NHEADS + h
  const int h = bid & 63;
  const int bc = bid >> 6;
  const int b = bc >> 3, c = bc & 7;
  const int t = threadIdx.x;
  const int lane = t & 63;
  const int w = t >> 6;
  const int g = lane >> 4;
  __shared__ unsigned short BT[128][72];
  __shared__ unsigned short WXT[64][72];
  __shared__ float csL[256], dtL[256];
  const long rowbase = (long)b * SEQ + c * CHUNK;
  const long bh8 = ((long)(b * NHEADS + h)) * NCHUNK + c;
  const float* acum = A_cum + bh8 * CHUNK;
  if (t < 256) { csL[t] = acum[t]; dtL[t] = dt_t[((size_t)(b * NHEADS + h)) * SEQ + c * CHUNK + t]; }
  float cs_last = acum[255];
  f32x4 acc[2][4];
#pragma unroll
  for (int i = 0; i < 2; ++i)
#pragma unroll
    for (int j = 0; j < 4; ++j) { f32x4 z = {0.f, 0.f, 0.f, 0.f}; acc[i][j] = z; }

  for (int lp = 0; lp < 4; ++lp) {
    __syncthreads();
    for (int i = t; i < 64 * 32; i += 256) {
      int l = i >> 5, n4 = (i & 31) * 4;
      ushort4 v = *(const ushort4*)(xbc + (rowbase + lp * 64 + l) * (long)CONV_DIM + D_INNER + n4);
      BT[n4 + 0][l] = v.x; BT[n4 + 1][l] = v.y; BT[n4 + 2][l] = v.z; BT[n4 + 3][l] = v.w;
    }
    for (int i = t; i < 64 * 16; i += 256) {
      int l = i >> 4, p4 = (i & 15) * 4;
      int lg = lp * 64 + l;
      float wgt = expf(cs_last - csL[lg]) * dtL[lg];
      ushort4 v = *(const ushort4*)(xbc + (rowbase + lg) * (long)CONV_DIM + h * HEADDIM + p4);
      WXT[p4 + 0][l] = f2bf(bf2f(v.x) * wgt);
      WXT[p4 + 1][l] = f2bf(bf2f(v.y) * wgt);
      WXT[p4 + 2][l] = f2bf(bf2f(v.z) * wgt);
      WXT[p4 + 3][l] = f2bf(bf2f(v.w) * wgt);
    }
    __syncthreads();
#pragma unroll
    for (int ks = 0; ks < 2; ++ks) {
      const int kofs = ks * 32 + g * 8;
      bf16x8 am[2], bp[4];
#pragma unroll
      for (int i = 0; i < 2; ++i) am[i] = *(const bf16x8*)&BT[w * 32 + i * 16 + (lane & 15)][kofs];
#pragma unroll
      for (int j = 0; j < 4; ++j) bp[j] = *(const bf16x8*)&WXT[j * 16 + (lane & 15)][kofs];
#pragma unroll
      for (int i = 0; i < 2; ++i)
#pragma unroll
        for (int j = 0; j < 4; ++j)
          acc[i][j] = __builtin_amdgcn_mfma_f32_16x16x32_bf16(am[i], bp[j], acc[i][j], 0, 0, 0);
    }
  }
  float* sp = states + ((long)bc * NHEADS + h) * (D_STATE * HEADDIM);
#pragma unroll
  for (int i = 0; i < 2; ++i)
#pragma unroll
    for (int j = 0; j < 4; ++j) {
      int n0 = w * 32 + i * 16 + g * 4;
      int p = j * 16 + (lane & 15);
#pragma unroll
      for (int r = 0; r < 4; ++r) sp[(long)(n0 + r) * HEADDIM + p] = acc[i][j][r];
    }
}

// ---------------- inter-chunk scan -> prev_states (bf16, [n][p]) ----------------
__global__ void k_scan(const float* __restrict__ states, const float* __restrict__ A_cum, unsigned short* __restrict__ psb) {
  long idx = (long)blockIdx.x * blockDim.x + threadIdx.x;   // ((b*64+h)*128+n)*64+p
  if (idx >= (long)BATCH * NHEADS * D_STATE * HEADDIM) return;
  int p = idx & 63;
  int n = (int)((idx >> 6) & 127);
  long bh = idx >> 13;
  int h = (int)(bh & 63);
  int b = (int)(bh >> 6);
  float S = 0.f;
  for (int c = 0; c < NCHUNK; ++c) {
    long soff = (((long)(b * NCHUNK + c) * NHEADS + h) * (D_STATE * HEADDIM)) + (long)n * HEADDIM + p;
    psb[soff] = f2bf(S);
    float decay = expf(A_cum[(bh * NCHUNK + c) * CHUNK + 255]);
    S = S * decay + states[soff];
  }
}

// ---------------- Y = Y_diag + Y_off + x*D (bf16 out), MFMA ----------------
__global__ __launch_bounds__(256) void k_y(const unsigned short* __restrict__ xbc, const float* __restrict__ dt_t,
                                           const float* __restrict__ A_cum, const unsigned short* __restrict__ cbt_t,
                                           const unsigned short* __restrict__ psb, const float* __restrict__ Dp,
                                           unsigned short* __restrict__ y) {
  const int bid = blockIdx.x;           // bc*NHEADS + h
  const int h = bid & 63;
  const int bc = bid >> 6;
  const int b = bc >> 3, c = bc & 7;
  const int t = threadIdx.x;
  const int lane = t & 63;
  const int w = t >> 6;
  const int g = lane >> 4;
  __shared__ unsigned short Abuf[256][72];
  __shared__ unsigned short Bbuf[64][72];
  __shared__ float csL[256], dtL[256], expL[256];
  const long rowbase = (long)b * SEQ + c * CHUNK;
  const long bh8 = ((long)(b * NHEADS + h)) * NCHUNK + c;
  const float* acum = A_cum + bh8 * CHUNK;
  if (t < 256) {
    float cv = acum[t];
    csL[t] = cv;
    expL[t] = expf(cv);
    dtL[t] = dt_t[((size_t)(b * NHEADS + h)) * SEQ + c * CHUNK + t];
  }
  f32x4 acc[4][4];
#pragma unroll
  for (int i = 0; i < 4; ++i)
#pragma unroll
    for (int j = 0; j < 4; ++j) { f32x4 z = {0.f, 0.f, 0.f, 0.f}; acc[i][j] = z; }

  // ---- phase 1: Y_off = (C .* exp(cs_l)) @ PS^T ----
  const unsigned short* psbase = psb + ((long)bc * NHEADS + h) * (D_STATE * HEADDIM);
  for (int np = 0; np < 2; ++np) {
    __syncthreads();
    for (int i = t; i < 256 * 16; i += 256) {
      int row = i >> 4, c4 = (i & 15) * 4;
      float el = expL[row];
      ushort4 v = *(const ushort4*)(xbc + (rowbase + row) * (long)CONV_DIM + D_INNER + D_STATE + np * 64 + c4);
      ushort4 o = make_ushort4(f2bf(bf2f(v.x) * el), f2bf(bf2f(v.y) * el), f2bf(bf2f(v.z) * el), f2bf(bf2f(v.w) * el));
      *(ushort4*)&Abuf[row][c4] = o;
    }
    for (int i = t; i < 64 * 16; i += 256) {
      int n = i >> 4, p4 = (i & 15) * 4;
      ushort4 v = *(const ushort4*)(psbase + (long)(np * 64 + n) * HEADDIM + p4);
      Bbuf[p4 + 0][n] = v.x; Bbuf[p4 + 1][n] = v.y; Bbuf[p4 + 2][n] = v.z; Bbuf[p4 + 3][n] = v.w;
    }
    __syncthreads();
#pragma unroll
    for (int ks = 0; ks < 2; ++ks) {
      const int kofs = ks * 32 + g * 8;
      bf16x8 af[4], bfr[4];
#pragma unroll
      for (int i = 0; i < 4; ++i) af[i] = *(const bf16x8*)&Abuf[w * 64 + i * 16 + (lane & 15)][kofs];
#pragma unroll
      for (int j = 0; j < 4; ++j) bfr[j] = *(const bf16x8*)&Bbuf[j * 16 + (lane & 15)][kofs];
#pragma unroll
      for (int i = 0; i < 4; ++i)
#pragma unroll
        for (int j = 0; j < 4; ++j)
          acc[i][j] = __builtin_amdgcn_mfma_f32_16x16x32_bf16(af[i], bfr[j], acc[i][j], 0, 0, 0);
    }
  }

  // ---- phase 2: Y_diag, scores in-register ----
  const unsigned short* cbtb = cbt_t + (long)bc * CHUNK * CHUNK;
  for (int sp = 0; sp < 4; ++sp) {
    __syncthreads();
    for (int i = t; i < 64 * 8; i += 256) {
      int s = i >> 3, p0 = (i & 7) * 8;
      u16x8 v = *(const u16x8*)(xbc + (rowbase + sp * 64 + s) * (long)CONV_DIM + h * HEADDIM + p0);
#pragma unroll
      for (int e = 0; e < 8; ++e) Bbuf[p0 + e][s] = v[e];
    }
    __syncthreads();
    if (sp > w) continue;
#pragma unroll
    for (int ks = 0; ks < 2; ++ks) {
      const int kofs = ks * 32 + g * 8;
      bf16x8 bfr[4];
#pragma unroll
      for (int j = 0; j < 4; ++j) bfr[j] = *(const bf16x8*)&Bbuf[j * 16 + (lane & 15)][kofs];
      const int sbase = sp * 64 + ks * 32 + g * 8;
#pragma unroll
      for (int i = 0; i < 4; ++i) {
        if (sp == w && ks * 32 > i * 16 + 15) continue;
        const int l = w * 64 + i * 16 + (lane & 15);
        u16x8 cv = *(const u16x8*)(cbtb + (long)l * CHUNK + sbase);
        const float cl = csL[l];
        bf16x8 af;
#pragma unroll
        for (int e = 0; e < 8; ++e) {
          int s = sbase + e;
          float val = (s <= l) ? bf2f(cv[e]) * expf(cl - csL[s]) * dtL[s] : 0.f;
          af[e] = (short)f2bf(val);
        }
#pragma unroll
        for (int j = 0; j < 4; ++j)
          acc[i][j] = __builtin_amdgcn_mfma_f32_16x16x32_bf16(af, bfr[j], acc[i][j], 0, 0, 0);
      }
    }
  }

  // ---- epilogue: skip connection + bf16 store ----
  const float Dh = Dp[h];
#pragma unroll
  for (int i = 0; i < 4; ++i) {
    int l0 = w * 64 + i * 16 + g * 4;
#pragma unroll
    for (int r = 0; r < 4; ++r) {
      long grow = rowbase + l0 + r;
      const unsigned short* xrow = xbc + grow * (long)CONV_DIM + h * HEADDIM;
      unsigned short* yrow = y + grow * (long)D_INNER + h * HEADDIM;
#pragma unroll
      for (int j = 0; j < 4; ++j) {
        int p = j * 16 + (lane & 15);
        yrow[p] = f2bf(acc[i][j][r] + bf2f(xrow[p]) * Dh);
      }
    }
  }
}

// ---------------- gated RMSNorm (bf16 y,z in; bf16 out, in-place over y ok) ----------------
__global__ __launch_bounds__(256) void k_norm(unsigned short* yz, const unsigned short* __restrict__ zb,
                                              const float* __restrict__ norm_w, unsigned short* out) {
  const int row = blockIdx.x;
  const int t = threadIdx.x;
  const unsigned short* yr = yz + (size_t)row * D_INNER;
  const unsigned short* zr = zb + (size_t)row * D_INNER;
  float yv[16];
  float ss = 0.f;
#pragma unroll
  for (int j = 0; j < 4; ++j) {
    int e = (t + j * 256) * 4;
    ushort4 yy = *(const ushort4*)(yr + e);
    ushort4 zz = *(const ushort4*)(zr + e);
    float z0 = bf2f(zz.x), z1 = bf2f(zz.y), z2 = bf2f(zz.z), z3 = bf2f(zz.w);
    float g0 = bf2f(yy.x) * z0 / (1.f + expf(-z0));
    float g1 = bf2f(yy.y) * z1 / (1.f + expf(-z1));
    float g2 = bf2f(yy.z) * z2 / (1.f + expf(-z2));
    float g3 = bf2f(yy.w) * z3 / (1.f + expf(-z3));
    ss += g0 * g0 + g1 * g1 + g2 * g2 + g3 * g3;
    yv[j * 4 + 0] = g0; yv[j * 4 + 1] = g1; yv[j * 4 + 2] = g2; yv[j * 4 + 3] = g3;
  }
#pragma unroll
  for (int off = 32; off > 0; off >>= 1) ss += __shfl_xor(ss, off);
  __shared__ float red[4];
  if ((t & 63) == 0) red[t >> 6] = ss;
  __syncthreads();
  float tot = red[0] + red[1] + red[2] + red[3];
  float scale = rsqrtf(tot / (float)D_INNER + EPSV);
  unsigned short* orow = out + (size_t)row * D_INNER;
#pragma unroll
  for (int j = 0; j < 4; ++j) {
    int e = (t + j * 256) * 4;
    float4 w = *(const float4*)(norm_w + e);
    ushort4 o = make_ushort4(f2bf(yv[j * 4 + 0] * scale * w.x), f2bf(yv[j * 4 + 1] * scale * w.y),
                             f2bf(yv[j * 4 + 2] * scale * w.z), f2bf(yv[j * 4 + 3] * scale * w.w));
    *(ushort4*)(orow + e) = o;
  }
}

extern "C" void kernel_launch(void* const* d_in, const int* in_sizes, int n_in,
                              void* d_out, int out_size, void* d_ws, size_t ws_size,
                              hipStream_t stream) {
  const float* u       = (const float*)d_in[0];
  const float* W_in    = (const float*)d_in[1];
  const float* conv_w  = (const float*)d_in[2];
  const float* conv_b  = (const float*)d_in[3];
  const float* dt_bias = (const float*)d_in[4];
  const float* A_log   = (const float*)d_in[5];
  const float* Dp      = (const float*)d_in[6];
  const float* norm_w  = (const float*)d_in[7];
  const float* W_out   = (const float*)d_in[8];
  float* out = (float*)d_out;

  char* ws = (char*)d_ws;
  size_t off = 0;
  auto alloc = [&](size_t bytes) { char* p = ws + off; off += (bytes + 255) & ~(size_t)255; return p; };
  unsigned short* ub   = (unsigned short*)alloc((size_t)NROWS * D_MODEL * 2);       // -> wob later
  unsigned short* winb = (unsigned short*)alloc((size_t)NPAD * D_MODEL * 2);        // -> cbt_t + psb later
  unsigned short* zb   = (unsigned short*)alloc((size_t)NROWS * D_INNER * 2);
  unsigned short* xb   = (unsigned short*)alloc((size_t)NROWS * NX * 2);            // -> yb later
  unsigned short* xbcb = (unsigned short*)alloc((size_t)NROWS * CONV_DIM * 2);
  float* dtt  = (float*)alloc((size_t)BATCH * NHEADS * SEQ * 4);
  float* acum = (float*)alloc((size_t)BATCH * NHEADS * NCHUNK * CHUNK * 4);
  unsigned short* cwT = (unsigned short*)alloc((size_t)4 * CONV_DIM * 2);
  unsigned short* cbT = (unsigned short*)alloc((size_t)CONV_DIM * 2);
  unsigned short* wob = ub;                        // W_out bf16, after GEMM1s
  unsigned short* cbt = winb;                      // CBT^T bf16, after GEMM1s
  unsigned short* psb = winb + (size_t)BATCH * NCHUNK * CHUNK * CHUNK + 1024;  // prev_states bf16
  unsigned short* yb = xb;                         // y bf16, after conv
  float* states = (float*)d_out;                   // scratch == out_size; overwritten by GEMM2

  if (off > ws_size) {
    k_sentinel<<<1, 64, 0, stream>>>(out);
    return;
  }

  k_f32_to_bf16_v4<<<2048, 256, 0, stream>>>(u, ub, (long)NROWS * D_MODEL / 4);
  k_convert_win<<<4096, 256, 0, stream>>>(W_in, winb);
  k_conv_pack<<<(CONV_DIM + 255) / 256, 256, 0, stream>>>(conv_w, conv_b, cwT, cbT);
  k_gemm_bt<1><<<dim3(D_INNER / 128, NROWS / 128), 256, 0, stream>>>(ub, winb, zb, NROWS, D_INNER, D_MODEL);
  k_gemm_bt<1><<<dim3(NX / 128, NROWS / 128), 256, 0, stream>>>(ub, winb + (size_t)D_INNER * D_MODEL, xb, NROWS, NX, D_MODEL);
  k_dt<<<NROWS / 16, 256, 0, stream>>>(u, W_in, dt_bias, dtt);
  k_conv_silu<<<(int)(((long)(NROWS / 4) * CG + 255) / 256), 256, 0, stream>>>(xb, cwT, cbT, xbcb);
  k_cumsum<<<BATCH * NHEADS * NCHUNK, 256, 0, stream>>>(dtt, A_log, acum);
  k_cbtt<<<BATCH * NCHUNK * 4, 256, 0, stream>>>(xbcb, cbt);
  k_states<<<BATCH * NCHUNK * NHEADS, 256, 0, stream>>>(xbcb, dtt, acum, states);
  k_scan<<<(BATCH * NHEADS * D_STATE * HEADDIM + 255) / 256, 256, 0, stream>>>(states, acum, psb);
  k_y<<<BATCH * NCHUNK * NHEADS, 256, 0, stream>>>(xbcb, dtt, acum, cbt, psb, Dp, yb);
  k_norm<<<NROWS, 256, 0, stream>>>(yb, zb, norm_w, yb);
  k_f32_to_bf16_v4<<<2048, 256, 0, stream>>>(W_out, wob, (long)D_MODEL * D_INNER / 4);
  k_gemm_bt<0><<<dim3(D_MODEL / 128, NROWS / 128), 256, 0, stream>>>(yb, wob, out, NROWS, D_MODEL, D_INNER);
}

// Round 5
// 606.360 us; speedup vs baseline: 1.8090x; 1.0731x over previous
//
#include <hip/hip_runtime.h>

#define D_MODEL   2048
#define D_INNER   4096
#define HEADDIM   64
#define NHEADS    64
#define D_STATE   128
#define CHUNK     256
#define CONV_DIM  4352
#define D_IN_PROJ 8512
#define NPAD      8704
#define NX        4608      // xBC + dt + pad columns (18*256)
#define BATCH     2
#define SEQ       2048
#define NCHUNK    8
#define NROWS     4096
#define EPSV      1e-5f
#define CG        (CONV_DIM / 8)   // 544

typedef __attribute__((ext_vector_type(8))) short bf16x8;
typedef __attribute__((ext_vector_type(8))) unsigned short u16x8;
typedef __attribute__((ext_vector_type(4))) float f32x4;

#define AS1 __attribute__((address_space(1)))
#define AS3 __attribute__((address_space(3)))

__device__ __forceinline__ unsigned short f2bf(float f) {
  unsigned int x = __float_as_uint(f);
  unsigned int r = (x + 0x7fffu + ((x >> 16) & 1u)) >> 16;
  return (unsigned short)r;
}
__device__ __forceinline__ float bf2f(unsigned short u) {
  return __uint_as_float((unsigned int)u << 16);
}

__global__ void k_sentinel(float* out) { if (threadIdx.x == 0) out[0] = 1.0e6f; }

// ---------------- converts ----------------
__global__ void k_f32_to_bf16_v4(const float* __restrict__ in, unsigned short* __restrict__ out, long n4) {
  long i = (long)blockIdx.x * blockDim.x + threadIdx.x;
  long stride = (long)gridDim.x * blockDim.x;
  for (; i < n4; i += stride) {
    float4 v = ((const float4*)in)[i];
    ushort4 o = make_ushort4(f2bf(v.x), f2bf(v.y), f2bf(v.z), f2bf(v.w));
    ((ushort4*)out)[i] = o;
  }
}

__global__ void k_convert_win(const float* __restrict__ W, unsigned short* __restrict__ out) {
  const long n4 = (long)NPAD * D_MODEL / 4;
  const long valid4 = (long)D_IN_PROJ * D_MODEL / 4;
  long i = (long)blockIdx.x * blockDim.x + threadIdx.x;
  long stride = (long)gridDim.x * blockDim.x;
  for (; i < n4; i += stride) {
    ushort4 o = make_ushort4(0, 0, 0, 0);
    if (i < valid4) {
      float4 v = ((const float4*)W)[i];
      o = make_ushort4(f2bf(v.x), f2bf(v.y), f2bf(v.z), f2bf(v.w));
    }
    ((ushort4*)out)[i] = o;
  }
}

// ---------------- 2-phase double-buffered GEMM (A[M][K] @ B[N][K]^T -> C[M][N]) ----------------
// 8 waves (2Mx4N), BK=64, early-stage + one vmcnt(0)+barrier per K-tile, XCD swizzle (nwg%8==0).
template <int BM, int BN, int BF16OUT>
__global__ __launch_bounds__(512, 2) void k_gemm2p(const unsigned short* __restrict__ A,
                                                   const unsigned short* __restrict__ B,
                                                   void* __restrict__ Cv, int M, int N, int K) {
  constexpr int BK = 64;
  constexpr int MSUB = BM / 2;
  constexpr int NSUB = BN / 4;
  constexpr int MR = MSUB / 16;
  constexpr int NR = NSUB / 16;
  constexpr int AI = BM / 64;   // 8KB global_load_lds insts per A K-tile
  constexpr int BI = BN / 64;
  __shared__ short lds[2][(BM + BN) * BK];
  const int t = threadIdx.x;
  const int lane = t & 63;
  const int wid = t >> 6;
  const int wr = wid >> 2;
  const int wc = wid & 3;
  const int ntx = N / BN;
  const int nwg = (int)gridDim.x;
  const int bid = (int)blockIdx.x;
  const int swz = (bid & 7) * (nwg >> 3) + (bid >> 3);   // bijective: nwg % 8 == 0
  const int m0 = (swz / ntx) * BM;
  const int n0 = (swz % ntx) * BN;

  f32x4 acc[MR][NR];
#pragma unroll
  for (int i = 0; i < MR; ++i)
#pragma unroll
    for (int j = 0; j < NR; ++j) { f32x4 z = {0.f, 0.f, 0.f, 0.f}; acc[i][j] = z; }

  const int srow = t >> 3;
  const int scol = (t & 7) * 8;
  const unsigned short* gA = A + (size_t)(m0 + srow) * K + scol;
  const unsigned short* gB = B + (size_t)(n0 + srow) * K + scol;

  auto STAGE = [&](int buf, int kt) {
    char* dA = (char*)&lds[buf][0] + t * 16;
    char* dB = (char*)&lds[buf][BM * BK] + t * 16;
#pragma unroll
    for (int ii = 0; ii < AI; ++ii)
      __builtin_amdgcn_global_load_lds((const AS1 void*)(gA + (size_t)ii * 64 * K + kt * BK),
                                       (AS3 void*)(dA + ii * 8192), 16, 0, 0);
#pragma unroll
    for (int ii = 0; ii < BI; ++ii)
      __builtin_amdgcn_global_load_lds((const AS1 void*)(gB + (size_t)ii * 64 * K + kt * BK),
                                       (AS3 void*)(dB + ii * 8192), 16, 0, 0);
  };

  STAGE(0, 0);
  asm volatile("s_waitcnt vmcnt(0)" ::: "memory");
  __syncthreads();

  const int NT = K / BK;
  const int ar = wr * MSUB + (lane & 15);
  const int br = wc * NSUB + (lane & 15);
  const int kof = (lane >> 4) * 8;
  for (int kt = 0; kt < NT; ++kt) {
    const int cur = kt & 1;
    if (kt + 1 < NT) STAGE(cur ^ 1, kt + 1);       // issue next-tile loads BEFORE compute
    const short* As = &lds[cur][0];
    const short* Bs = &lds[cur][BM * BK];
#pragma unroll
    for (int kk = 0; kk < 2; ++kk) {
      bf16x8 bfr[NR];
#pragma unroll
      for (int j = 0; j < NR; ++j) bfr[j] = *(const bf16x8*)(Bs + (br + j * 16) * BK + kk * 32 + kof);
#pragma unroll
      for (int i = 0; i < MR; ++i) {
        bf16x8 af = *(const bf16x8*)(As + (ar + i * 16) * BK + kk * 32 + kof);
#pragma unroll
        for (int j = 0; j < NR; ++j)
          acc[i][j] = __builtin_amdgcn_mfma_f32_16x16x32_bf16(af, bfr[j], acc[i][j], 0, 0, 0);
      }
    }
    asm volatile("s_waitcnt vmcnt(0)" ::: "memory");  // next-tile stores landed (latency hidden by MFMA above)
    __syncthreads();
  }

  const int crow = (lane >> 4) * 4;
  const int ccol = lane & 15;
#pragma unroll
  for (int i = 0; i < MR; ++i)
#pragma unroll
    for (int j = 0; j < NR; ++j) {
      size_t base = (size_t)(m0 + wr * MSUB + i * 16 + crow) * N + (n0 + wc * NSUB + j * 16 + ccol);
      if (BF16OUT) {
        unsigned short* C = (unsigned short*)Cv;
#pragma unroll
        for (int r = 0; r < 4; ++r) C[base + (size_t)r * N] = f2bf(acc[i][j][r]);
      } else {
        float* C = (float*)Cv;
#pragma unroll
        for (int r = 0; r < 4; ++r) C[base + (size_t)r * N] = acc[i][j][r];
      }
    }
}

// ---------------- dt: exact f32 skinny GEMM + softplus (16 rows/block) ----------------
__global__ __launch_bounds__(256) void k_dt(const float* __restrict__ u, const float* __restrict__ W_in,
                                            const float* __restrict__ dt_bias, float* __restrict__ dt_t) {
  __shared__ float Wl[64][132];
  __shared__ float ul[16][132];
  const int t = threadIdx.x;
  const int h = t & 63, rg = t >> 6;     // 4 rows per thread
  const int row0 = blockIdx.x * 16;
  float acc[4] = {0.f, 0.f, 0.f, 0.f};
  for (int k0 = 0; k0 < D_MODEL; k0 += 128) {
    __syncthreads();
    for (int i = t; i < 64 * 32; i += 256) {
      int rr = i >> 5, k4 = (i & 31) * 4;
      float4 v = *(const float4*)(W_in + (size_t)(8448 + rr) * D_MODEL + k0 + k4);
      Wl[rr][k4] = v.x; Wl[rr][k4 + 1] = v.y; Wl[rr][k4 + 2] = v.z; Wl[rr][k4 + 3] = v.w;
    }
    for (int i = t; i < 16 * 32; i += 256) {
      int rr = i >> 5, k4 = (i & 31) * 4;
      float4 v = *(const float4*)(u + (size_t)(row0 + rr) * D_MODEL + k0 + k4);
      ul[rr][k4] = v.x; ul[rr][k4 + 1] = v.y; ul[rr][k4 + 2] = v.z; ul[rr][k4 + 3] = v.w;
    }
    __syncthreads();
#pragma unroll 4
    for (int kk = 0; kk < 128; ++kk) {
      float wv = Wl[h][kk];
#pragma unroll
      for (int r = 0; r < 4; ++r) acc[r] += ul[rg * 4 + r][kk] * wv;
    }
  }
#pragma unroll
  for (int r = 0; r < 4; ++r) {
    float x = acc[r] + dt_bias[h];
    float dtv = (x > 20.f) ? x : log1pf(expf(x));
    int row = row0 + rg * 4 + r; int b = row >> 11; int l = row & 2047;
    dt_t[((size_t)(b * NHEADS + h)) * SEQ + l] = dtv;
  }
}

// ---------------- conv weight/bias pack: f32 -> bf16 transposed ----------------
__global__ void k_conv_pack(const float* __restrict__ cw, const float* __restrict__ cb,
                            unsigned short* __restrict__ wT, unsigned short* __restrict__ bT) {
  int i = blockIdx.x * blockDim.x + threadIdx.x;
  if (i < CONV_DIM) {
#pragma unroll
    for (int w = 0; w < 4; ++w) wT[w * CONV_DIM + i] = f2bf(cw[i * 4 + w]);
    bT[i] = f2bf(cb[i]);
  }
}

// ---------------- conv1d + silu: 8 channels x 4 rows per thread ----------------
__global__ __launch_bounds__(256) void k_conv_silu(const unsigned short* __restrict__ xb,
                                                   const unsigned short* __restrict__ wT,
                                                   const unsigned short* __restrict__ bT,
                                                   unsigned short* __restrict__ out) {
  long idx = (long)blockIdx.x * blockDim.x + threadIdx.x;   // over (NROWS/4)*CG
  if (idx >= (long)(NROWS / 4) * CG) return;
  int c8 = (int)(idx % CG);
  long rq = idx / CG;                      // row-quad id; 512 per batch
  int l0 = (int)((rq & (SEQ / 4 - 1)) * 4);
  long brow = (rq >> 9) * (long)SEQ;       // batch base row
  int ch0 = c8 * 8;

  u16x8 wv[4];
#pragma unroll
  for (int w = 0; w < 4; ++w) wv[w] = *(const u16x8*)(wT + w * CONV_DIM + ch0);
  u16x8 bv = *(const u16x8*)(bT + ch0);

  u16x8 xr[7];
#pragma unroll
  for (int i = 0; i < 7; ++i) {
    int ls = l0 - 3 + i;
    if (ls >= 0) xr[i] = *(const u16x8*)(xb + (brow + ls) * (long)NX + ch0);
    else { u16x8 z = {0, 0, 0, 0, 0, 0, 0, 0}; xr[i] = z; }
  }

#pragma unroll
  for (int r = 0; r < 4; ++r) {
    float acc[8];
#pragma unroll
    for (int e = 0; e < 8; ++e) acc[e] = bf2f(bv[e]);
#pragma unroll
    for (int w = 0; w < 4; ++w)
#pragma unroll
      for (int e = 0; e < 8; ++e) acc[e] += bf2f(xr[r + w][e]) * bf2f(wv[w][e]);
    u16x8 o;
#pragma unroll
    for (int e = 0; e < 8; ++e) o[e] = f2bf(acc[e] / (1.f + expf(-acc[e])));
    *(u16x8*)(out + (brow + l0 + r) * (long)CONV_DIM + ch0) = o;
  }
}

// ---------------- per-chunk cumsum of dA ----------------
__global__ __launch_bounds__(256) void k_cumsum(const float* __restrict__ dt_t, const float* __restrict__ A_log,
                                                float* __restrict__ A_cum) {
  const int bid = blockIdx.x;           // (b*NHEADS+h)*NCHUNK + c
  const int c = bid & 7;
  const int bh = bid >> 3;
  const int h = bh & 63;
  const int l = threadIdx.x;
  float A = -expf(A_log[h]);
  __shared__ float s[256];
  s[l] = dt_t[(size_t)bh * SEQ + c * CHUNK + l] * A;
  __syncthreads();
  for (int off = 1; off < 256; off <<= 1) {
    float x = (l >= off) ? s[l - off] : 0.f;
    __syncthreads();
    s[l] += x;
    __syncthreads();
  }
  A_cum[(size_t)bid * CHUNK + l] = s[l];
}

// ---------------- CBT^T[l][s] = C_l . B_s  (bf16 out), MFMA ----------------
__global__ __launch_bounds__(256) void k_cbtt(const unsigned short* __restrict__ xbc, unsigned short* __restrict__ cbt_t) {
  const int bid = blockIdx.x;           // bc*4 + sp
  const int sp = bid & 3;
  const int bc = bid >> 2;
  const int b = bc >> 3, c = bc & 7;
  const int t = threadIdx.x;
  const int lane = t & 63;
  const int w = t >> 6;
  const int g = lane >> 4;
  __shared__ unsigned short Cs[256][72];
  __shared__ unsigned short Bs2[64][72];
  const long rowbase = (long)b * SEQ + c * CHUNK;
  f32x4 acc[4][4];
#pragma unroll
  for (int i = 0; i < 4; ++i)
#pragma unroll
    for (int j = 0; j < 4; ++j) { f32x4 z = {0.f, 0.f, 0.f, 0.f}; acc[i][j] = z; }

  for (int np = 0; np < 2; ++np) {
    __syncthreads();
    for (int i = t; i < 256 * 16; i += 256) {
      int row = i >> 4, c4 = (i & 15) * 4;
      ushort4 v = *(const ushort4*)(xbc + (rowbase + row) * (long)CONV_DIM + D_INNER + D_STATE + np * 64 + c4);
      *(ushort4*)&Cs[row][c4] = v;
    }
    for (int i = t; i < 64 * 16; i += 256) {
      int row = i >> 4, c4 = (i & 15) * 4;
      ushort4 v = *(const ushort4*)(xbc + (rowbase + sp * 64 + row) * (long)CONV_DIM + D_INNER + np * 64 + c4);
      *(ushort4*)&Bs2[row][c4] = v;
    }
    __syncthreads();
#pragma unroll
    for (int ks = 0; ks < 2; ++ks) {
      const int kofs = ks * 32 + g * 8;
      bf16x8 af[4], bfr[4];
#pragma unroll
      for (int i = 0; i < 4; ++i) af[i] = *(const bf16x8*)&Cs[w * 64 + i * 16 + (lane & 15)][kofs];
#pragma unroll
      for (int j = 0; j < 4; ++j) bfr[j] = *(const bf16x8*)&Bs2[j * 16 + (lane & 15)][kofs];
#pragma unroll
      for (int i = 0; i < 4; ++i)
#pragma unroll
        for (int j = 0; j < 4; ++j)
          acc[i][j] = __builtin_amdgcn_mfma_f32_16x16x32_bf16(af[i], bfr[j], acc[i][j], 0, 0, 0);
    }
  }
  unsigned short* ob = cbt_t + (long)bc * CHUNK * CHUNK;
#pragma unroll
  for (int i = 0; i < 4; ++i)
#pragma unroll
    for (int j = 0; j < 4; ++j) {
      int l0 = w * 64 + i * 16 + g * 4;
      int s = sp * 64 + j * 16 + (lane & 15);
#pragma unroll
      for (int r = 0; r < 4; ++r) ob[(long)(l0 + r) * CHUNK + s] = f2bf(acc[i][j][r]);
    }
}

// ---------------- states[n][p] = sum_l B[l][n]*w_l*x[l][p], MFMA ----------------
__global__ __launch_bounds__(256) void k_states(const unsigned short* __restrict__ xbc, const float* __restrict__ dt_t,
                                                const float* __restrict__ A_cum, float* __restrict__ states) {
  const int bid = blockIdx.x;           // bc*NHEADS + h
  const int h = bid & 63;
  const int bc = bid >> 6;
  const int b = bc >> 3, c = bc & 7;
  const int t = threadIdx.x;
  const int lane = t & 63;
  const int w = t >> 6;
  const int g = lane >> 4;
  __shared__ unsigned short BT[128][72];
  __shared__ unsigned short WXT[64][72];
  __shared__ float csL[256], dtL[256];
  const long rowbase = (long)b * SEQ + c * CHUNK;
  const long bh8 = ((long)(b * NHEADS + h)) * NCHUNK + c;
  const float* acum = A_cum + bh8 * CHUNK;
  if (t < 256) { csL[t] = acum[t]; dtL[t] = dt_t[((size_t)(b * NHEADS + h)) * SEQ + c * CHUNK + t]; }
  float cs_last = acum[255];
  f32x4 acc[2][4];
#pragma unroll
  for (int i = 0; i < 2; ++i)
#pragma unroll
    for (int j = 0; j < 4; ++j) { f32x4 z = {0.f, 0.f, 0.f, 0.f}; acc[i][j] = z; }

  for (int lp = 0; lp < 4; ++lp) {
    __syncthreads();
    for (int i = t; i < 64 * 32; i += 256) {
      int l = i >> 5, n4 = (i & 31) * 4;
      ushort4 v = *(const ushort4*)(xbc + (rowbase + lp * 64 + l) * (long)CONV_DIM + D_INNER + n4);
      BT[n4 + 0][l] = v.x; BT[n4 + 1][l] = v.y; BT[n4 + 2][l] = v.z; BT[n4 + 3][l] = v.w;
    }
    for (int i = t; i < 64 * 16; i += 256) {
      int l = i >> 4, p4 = (i & 15) * 4;
      int lg = lp * 64 + l;
      float wgt = expf(cs_last - csL[lg]) * dtL[lg];
      ushort4 v = *(const ushort4*)(xbc + (rowbase + lg) * (long)CONV_DIM + h * HEADDIM + p4);
      WXT[p4 + 0][l] = f2bf(bf2f(v.x) * wgt);
      WXT[p4 + 1][l] = f2bf(bf2f(v.y) * wgt);
      WXT[p4 + 2][l] = f2bf(bf2f(v.z) * wgt);
      WXT[p4 + 3][l] = f2bf(bf2f(v.w) * wgt);
    }
    __syncthreads();
#pragma unroll
    for (int ks = 0; ks < 2; ++ks) {
      const int kofs = ks * 32 + g * 8;
      bf16x8 am[2], bp[4];
#pragma unroll
      for (int i = 0; i < 2; ++i) am[i] = *(const bf16x8*)&BT[w * 32 + i * 16 + (lane & 15)][kofs];
#pragma unroll
      for (int j = 0; j < 4; ++j) bp[j] = *(const bf16x8*)&WXT[j * 16 + (lane & 15)][kofs];
#pragma unroll
      for (int i = 0; i < 2; ++i)
#pragma unroll
        for (int j = 0; j < 4; ++j)
          acc[i][j] = __builtin_amdgcn_mfma_f32_16x16x32_bf16(am[i], bp[j], acc[i][j], 0, 0, 0);
    }
  }
  float* sp = states + ((long)bc * NHEADS + h) * (D_STATE * HEADDIM);
#pragma unroll
  for (int i = 0; i < 2; ++i)
#pragma unroll
    for (int j = 0; j < 4; ++j) {
      int n0 = w * 32 + i * 16 + g * 4;
      int p = j * 16 + (lane & 15);
#pragma unroll
      for (int r = 0; r < 4; ++r) sp[(long)(n0 + r) * HEADDIM + p] = acc[i][j][r];
    }
}

// ---------------- inter-chunk scan -> prev_states (bf16, [n][p]) ----------------
__global__ void k_scan(const float* __restrict__ states, const float* __restrict__ A_cum, unsigned short* __restrict__ psb) {
  long idx = (long)blockIdx.x * blockDim.x + threadIdx.x;   // ((b*64+h)*128+n)*64+p
  if (idx >= (long)BATCH * NHEADS * D_STATE * HEADDIM) return;
  int p = idx & 63;
  int n = (int)((idx >> 6) & 127);
  long bh = idx >> 13;
  int h = (int)(bh & 63);
  int b = (int)(bh >> 6);
  float S = 0.f;
  for (int c = 0; c < NCHUNK; ++c) {
    long soff = (((long)(b * NCHUNK + c) * NHEADS + h) * (D_STATE * HEADDIM)) + (long)n * HEADDIM + p;
    psb[soff] = f2bf(S);
    float decay = expf(A_cum[(bh * NCHUNK + c) * CHUNK + 255]);
    S = S * decay + states[soff];
  }
}

// ---------------- Y = Y_diag + Y_off + x*D (bf16 out), MFMA ----------------
__global__ __launch_bounds__(256) void k_y(const unsigned short* __restrict__ xbc, const float* __restrict__ dt_t,
                                           const float* __restrict__ A_cum, const unsigned short* __restrict__ cbt_t,
                                           const unsigned short* __restrict__ psb, const float* __restrict__ Dp,
                                           unsigned short* __restrict__ y) {
  const int bid = blockIdx.x;           // bc*NHEADS + h
  const int h = bid & 63;
  const int bc = bid >> 6;
  const int b = bc >> 3, c = bc & 7;
  const int t = threadIdx.x;
  const int lane = t & 63;
  const int w = t >> 6;
  const int g = lane >> 4;
  __shared__ unsigned short Abuf[256][72];
  __shared__ unsigned short Bbuf[64][72];
  __shared__ float csL[256], dtL[256], expL[256];
  const long rowbase = (long)b * SEQ + c * CHUNK;
  const long bh8 = ((long)(b * NHEADS + h)) * NCHUNK + c;
  const float* acum = A_cum + bh8 * CHUNK;
  if (t < 256) {
    float cv = acum[t];
    csL[t] = cv;
    expL[t] = expf(cv);
    dtL[t] = dt_t[((size_t)(b * NHEADS + h)) * SEQ + c * CHUNK + t];
  }
  f32x4 acc[4][4];
#pragma unroll
  for (int i = 0; i < 4; ++i)
#pragma unroll
    for (int j = 0; j < 4; ++j) { f32x4 z = {0.f, 0.f, 0.f, 0.f}; acc[i][j] = z; }

  // ---- phase 1: Y_off = (C .* exp(cs_l)) @ PS^T ----
  const unsigned short* psbase = psb + ((long)bc * NHEADS + h) * (D_STATE * HEADDIM);
  for (int np = 0; np < 2; ++np) {
    __syncthreads();
    for (int i = t; i < 256 * 16; i += 256) {
      int row = i >> 4, c4 = (i & 15) * 4;
      float el = expL[row];
      ushort4 v = *(const ushort4*)(xbc + (rowbase + row) * (long)CONV_DIM + D_INNER + D_STATE + np * 64 + c4);
      ushort4 o = make_ushort4(f2bf(bf2f(v.x) * el), f2bf(bf2f(v.y) * el), f2bf(bf2f(v.z) * el), f2bf(bf2f(v.w) * el));
      *(ushort4*)&Abuf[row][c4] = o;
    }
    for (int i = t; i < 64 * 16; i += 256) {
      int n = i >> 4, p4 = (i & 15) * 4;
      ushort4 v = *(const ushort4*)(psbase + (long)(np * 64 + n) * HEADDIM + p4);
      Bbuf[p4 + 0][n] = v.x; Bbuf[p4 + 1][n] = v.y; Bbuf[p4 + 2][n] = v.z; Bbuf[p4 + 3][n] = v.w;
    }
    __syncthreads();
#pragma unroll
    for (int ks = 0; ks < 2; ++ks) {
      const int kofs = ks * 32 + g * 8;
      bf16x8 af[4], bfr[4];
#pragma unroll
      for (int i = 0; i < 4; ++i) af[i] = *(const bf16x8*)&Abuf[w * 64 + i * 16 + (lane & 15)][kofs];
#pragma unroll
      for (int j = 0; j < 4; ++j) bfr[j] = *(const bf16x8*)&Bbuf[j * 16 + (lane & 15)][kofs];
#pragma unroll
      for (int i = 0; i < 4; ++i)
#pragma unroll
        for (int j = 0; j < 4; ++j)
          acc[i][j] = __builtin_amdgcn_mfma_f32_16x16x32_bf16(af[i], bfr[j], acc[i][j], 0, 0, 0);
    }
  }

  // ---- phase 2: Y_diag, scores in-register ----
  const unsigned short* cbtb = cbt_t + (long)bc * CHUNK * CHUNK;
  for (int sp = 0; sp < 4; ++sp) {
    __syncthreads();
    for (int i = t; i < 64 * 8; i += 256) {
      int s = i >> 3, p0 = (i & 7) * 8;
      u16x8 v = *(const u16x8*)(xbc + (rowbase + sp * 64 + s) * (long)CONV_DIM + h * HEADDIM + p0);
#pragma unroll
      for (int e = 0; e < 8; ++e) Bbuf[p0 + e][s] = v[e];
    }
    __syncthreads();
    if (sp > w) continue;
#pragma unroll
    for (int ks = 0; ks < 2; ++ks) {
      const int kofs = ks * 32 + g * 8;
      bf16x8 bfr[4];
#pragma unroll
      for (int j = 0; j < 4; ++j) bfr[j] = *(const bf16x8*)&Bbuf[j * 16 + (lane & 15)][kofs];
      const int sbase = sp * 64 + ks * 32 + g * 8;
#pragma unroll
      for (int i = 0; i < 4; ++i) {
        if (sp == w && ks * 32 > i * 16 + 15) continue;
        const int l = w * 64 + i * 16 + (lane & 15);
        u16x8 cv = *(const u16x8*)(cbtb + (long)l * CHUNK + sbase);
        const float cl = csL[l];
        bf16x8 af;
#pragma unroll
        for (int e = 0; e < 8; ++e) {
          int s = sbase + e;
          float val = (s <= l) ? bf2f(cv[e]) * expf(cl - csL[s]) * dtL[s] : 0.f;
          af[e] = (short)f2bf(val);
        }
#pragma unroll
        for (int j = 0; j < 4; ++j)
          acc[i][j] = __builtin_amdgcn_mfma_f32_16x16x32_bf16(af, bfr[j], acc[i][j], 0, 0, 0);
      }
    }
  }

  // ---- epilogue: skip connection + bf16 store ----
  const float Dh = Dp[h];
#pragma unroll
  for (int i = 0; i < 4; ++i) {
    int l0 = w * 64 + i * 16 + g * 4;
#pragma unroll
    for (int r = 0; r < 4; ++r) {
      long grow = rowbase + l0 + r;
      const unsigned short* xrow = xbc + grow * (long)CONV_DIM + h * HEADDIM;
      unsigned short* yrow = y + grow * (long)D_INNER + h * HEADDIM;
#pragma unroll
      for (int j = 0; j < 4; ++j) {
        int p = j * 16 + (lane & 15);
        yrow[p] = f2bf(acc[i][j][r] + bf2f(xrow[p]) * Dh);
      }
    }
  }
}

// ---------------- gated RMSNorm (bf16 y,z in; bf16 out, in-place over y ok) ----------------
__global__ __launch_bounds__(256) void k_norm(unsigned short* yz, const unsigned short* __restrict__ zb,
                                              const float* __restrict__ norm_w, unsigned short* out) {
  const int row = blockIdx.x;
  const int t = threadIdx.x;
  const unsigned short* yr = yz + (size_t)row * D_INNER;
  const unsigned short* zr = zb + (size_t)row * D_INNER;
  float yv[16];
  float ss = 0.f;
#pragma unroll
  for (int j = 0; j < 4; ++j) {
    int e = (t + j * 256) * 4;
    ushort4 yy = *(const ushort4*)(yr + e);
    ushort4 zz = *(const ushort4*)(zr + e);
    float z0 = bf2f(zz.x), z1 = bf2f(zz.y), z2 = bf2f(zz.z), z3 = bf2f(zz.w);
    float g0 = bf2f(yy.x) * z0 / (1.f + expf(-z0));
    float g1 = bf2f(yy.y) * z1 / (1.f + expf(-z1));
    float g2 = bf2f(yy.z) * z2 / (1.f + expf(-z2));
    float g3 = bf2f(yy.w) * z3 / (1.f + expf(-z3));
    ss += g0 * g0 + g1 * g1 + g2 * g2 + g3 * g3;
    yv[j * 4 + 0] = g0; yv[j * 4 + 1] = g1; yv[j * 4 + 2] = g2; yv[j * 4 + 3] = g3;
  }
#pragma unroll
  for (int off = 32; off > 0; off >>= 1) ss += __shfl_xor(ss, off);
  __shared__ float red[4];
  if ((t & 63) == 0) red[t >> 6] = ss;
  __syncthreads();
  float tot = red[0] + red[1] + red[2] + red[3];
  float scale = rsqrtf(tot / (float)D_INNER + EPSV);
  unsigned short* orow = out + (size_t)row * D_INNER;
#pragma unroll
  for (int j = 0; j < 4; ++j) {
    int e = (t + j * 256) * 4;
    float4 w = *(const float4*)(norm_w + e);
    ushort4 o = make_ushort4(f2bf(yv[j * 4 + 0] * scale * w.x), f2bf(yv[j * 4 + 1] * scale * w.y),
                             f2bf(yv[j * 4 + 2] * scale * w.z), f2bf(yv[j * 4 + 3] * scale * w.w));
    *(ushort4*)(orow + e) = o;
  }
}

extern "C" void kernel_launch(void* const* d_in, const int* in_sizes, int n_in,
                              void* d_out, int out_size, void* d_ws, size_t ws_size,
                              hipStream_t stream) {
  const float* u       = (const float*)d_in[0];
  const float* W_in    = (const float*)d_in[1];
  const float* conv_w  = (const float*)d_in[2];
  const float* conv_b  = (const float*)d_in[3];
  const float* dt_bias = (const float*)d_in[4];
  const float* A_log   = (const float*)d_in[5];
  const float* Dp      = (const float*)d_in[6];
  const float* norm_w  = (const float*)d_in[7];
  const float* W_out   = (const float*)d_in[8];
  float* out = (float*)d_out;

  char* ws = (char*)d_ws;
  size_t off = 0;
  auto alloc = [&](size_t bytes) { char* p = ws + off; off += (bytes + 255) & ~(size_t)255; return p; };
  unsigned short* ub   = (unsigned short*)alloc((size_t)NROWS * D_MODEL * 2);       // -> wob later
  unsigned short* winb = (unsigned short*)alloc((size_t)NPAD * D_MODEL * 2);        // -> cbt_t + psb later
  unsigned short* zb   = (unsigned short*)alloc((size_t)NROWS * D_INNER * 2);
  unsigned short* xb   = (unsigned short*)alloc((size_t)NROWS * NX * 2);            // -> yb later
  unsigned short* xbcb = (unsigned short*)alloc((size_t)NROWS * CONV_DIM * 2);
  float* dtt  = (float*)alloc((size_t)BATCH * NHEADS * SEQ * 4);
  float* acum = (float*)alloc((size_t)BATCH * NHEADS * NCHUNK * CHUNK * 4);
  unsigned short* cwT = (unsigned short*)alloc((size_t)4 * CONV_DIM * 2);
  unsigned short* cbT = (unsigned short*)alloc((size_t)CONV_DIM * 2);
  unsigned short* wob = ub;                        // W_out bf16, after GEMM1s
  unsigned short* cbt = winb;                      // CBT^T bf16, after GEMM1s
  unsigned short* psb = winb + (size_t)BATCH * NCHUNK * CHUNK * CHUNK + 1024;  // prev_states bf16
  unsigned short* yb = xb;                         // y bf16, after conv
  float* states = (float*)d_out;                   // scratch == out_size; overwritten by GEMM2

  if (off > ws_size) {
    k_sentinel<<<1, 64, 0, stream>>>(out);
    return;
  }

  k_f32_to_bf16_v4<<<2048, 256, 0, stream>>>(u, ub, (long)NROWS * D_MODEL / 4);
  k_convert_win<<<4096, 256, 0, stream>>>(W_in, winb);
  k_conv_pack<<<(CONV_DIM + 255) / 256, 256, 0, stream>>>(conv_w, conv_b, cwT, cbT);
  k_gemm2p<256, 256, 1><<<(NROWS / 256) * (D_INNER / 256), 512, 0, stream>>>(ub, winb, zb, NROWS, D_INNER, D_MODEL);
  k_gemm2p<256, 256, 1><<<(NROWS / 256) * (NX / 256), 512, 0, stream>>>(ub, winb + (size_t)D_INNER * D_MODEL, xb, NROWS, NX, D_MODEL);
  k_dt<<<NROWS / 16, 256, 0, stream>>>(u, W_in, dt_bias, dtt);
  k_conv_silu<<<(int)(((long)(NROWS / 4) * CG + 255) / 256), 256, 0, stream>>>(xb, cwT, cbT, xbcb);
  k_cumsum<<<BATCH * NHEADS * NCHUNK, 256, 0, stream>>>(dtt, A_log, acum);
  k_cbtt<<<BATCH * NCHUNK * 4, 256, 0, stream>>>(xbcb, cbt);
  k_states<<<BATCH * NCHUNK * NHEADS, 256, 0, stream>>>(xbcb, dtt, acum, states);
  k_scan<<<(BATCH * NHEADS * D_STATE * HEADDIM + 255) / 256, 256, 0, stream>>>(states, acum, psb);
  k_y<<<BATCH * NCHUNK * NHEADS, 256, 0, stream>>>(xbcb, dtt, acum, cbt, psb, Dp, yb);
  k_norm<<<NROWS, 256, 0, stream>>>(yb, zb, norm_w, yb);
  k_f32_to_bf16_v4<<<2048, 256, 0, stream>>>(W_out, wob, (long)D_MODEL * D_INNER / 4);
  k_gemm2p<128, 256, 0><<<(NROWS / 128) * (D_MODEL / 256), 512, 0, stream>>>(yb, wob, out, NROWS, D_MODEL, D_INNER);
}

// Round 6
// 575.181 us; speedup vs baseline: 1.9071x; 1.0542x over previous
//
#include <hip/hip_runtime.h>

#define D_MODEL   2048
#define D_INNER   4096
#define HEADDIM   64
#define NHEADS    64
#define D_STATE   128
#define CHUNK     256
#define CONV_DIM  4352
#define D_IN_PROJ 8512
#define BATCH     2
#define SEQ       2048
#define NCHUNK    8
#define NROWS     4096
#define EPSV      1e-5f
#define CG        (CONV_DIM / 8)   // 544

typedef __attribute__((ext_vector_type(8))) short bf16x8;
typedef __attribute__((ext_vector_type(8))) unsigned short u16x8;
typedef __attribute__((ext_vector_type(4))) float f32x4;

#define AS1 __attribute__((address_space(1)))
#define AS3 __attribute__((address_space(3)))

__device__ __forceinline__ unsigned short f2bf(float f) {
  unsigned int x = __float_as_uint(f);
  unsigned int r = (x + 0x7fffu + ((x >> 16) & 1u)) >> 16;
  return (unsigned short)r;
}
__device__ __forceinline__ float bf2f(unsigned short u) {
  return __uint_as_float((unsigned int)u << 16);
}

__global__ void k_sentinel(float* out) { if (threadIdx.x == 0) out[0] = 1.0e6f; }

// ---------------- converts ----------------
__global__ void k_f32_to_bf16_v4(const float* __restrict__ in, unsigned short* __restrict__ out, long n4) {
  long i = (long)blockIdx.x * blockDim.x + threadIdx.x;
  long stride = (long)gridDim.x * blockDim.x;
  for (; i < n4; i += stride) {
    float4 v = ((const float4*)in)[i];
    ushort4 o = make_ushort4(f2bf(v.x), f2bf(v.y), f2bf(v.z), f2bf(v.w));
    ((ushort4*)out)[i] = o;
  }
}

// ---- 128x128 BK=64 double-buffered GEMM, counted vmcnt + raw barriers + T2 swizzle + XCD swizzle ----
// A[M][K] @ B[N][K]^T -> C[M][N].  256 threads, 4 waves (2Mx2N). grid must be %8==0.
template <int BF16OUT>
__global__ __launch_bounds__(256, 2) void k_gemm128(const unsigned short* __restrict__ A,
                                                    const unsigned short* __restrict__ B,
                                                    void* __restrict__ Cv, int M, int N, int K) {
  constexpr int BK = 64;
  __shared__ __align__(16) short lds[2][256 * BK];   // A tile [128][64] then B tile [128][64]
  const int t = threadIdx.x;
  const int lane = t & 63;
  const int wid = t >> 6;
  const int wr = wid >> 1;
  const int wc = wid & 1;
  const int ntx = N / 128;
  const int nwg = (int)gridDim.x;
  const int bid = (int)blockIdx.x;
  const int swzb = (bid & 7) * (nwg >> 3) + (bid >> 3);   // bijective XCD swizzle (nwg%8==0)
  const int m0 = (swzb / ntx) * 128;
  const int n0 = (swzb % ntx) * 128;

  f32x4 acc[4][4];
#pragma unroll
  for (int i = 0; i < 4; ++i)
#pragma unroll
    for (int j = 0; j < 4; ++j) { f32x4 z = {0.f, 0.f, 0.f, 0.f}; acc[i][j] = z; }

  // staging: thread t covers row (ii*32 + t>>3), 16B chunk ((t&7) ^ ((t>>3)&7))  [T2 inverse pre-swizzle]
  const int srow = t >> 3;
  const int schunk = (t & 7) ^ (srow & 7);
  const unsigned short* gA = A + (size_t)(m0 + srow) * K + schunk * 8;
  const unsigned short* gB = B + (size_t)(n0 + srow) * K + schunk * 8;

  auto STAGE = [&](int buf, int kt) {
    char* dA = (char*)&lds[buf][0] + t * 16;
    char* dB = (char*)&lds[buf][128 * BK] + t * 16;
#pragma unroll
    for (int ii = 0; ii < 4; ++ii)
      __builtin_amdgcn_global_load_lds((const AS1 void*)(gA + (size_t)ii * 32 * K + kt * BK),
                                       (AS3 void*)(dA + ii * 4096), 16, 0, 0);
#pragma unroll
    for (int ii = 0; ii < 4; ++ii)
      __builtin_amdgcn_global_load_lds((const AS1 void*)(gB + (size_t)ii * 32 * K + kt * BK),
                                       (AS3 void*)(dB + ii * 4096), 16, 0, 0);
  };

  STAGE(0, 0);

  const int NT = K / BK;
  const int ar = wr * 64 + (lane & 15);
  const int br = wc * 64 + (lane & 15);
  const int kof = (lane >> 4) * 8;
  const int rsw = (lane & 7) * 8;        // T2 read swizzle: col ^= (row&7)*8
  int cur = 0;
  for (int kt = 0; kt < NT; ++kt) {
    if (kt + 1 < NT) {
      STAGE(cur ^ 1, kt + 1);
      asm volatile("s_waitcnt vmcnt(8)" ::: "memory");   // this tile's 8 loads landed (ours)
    } else {
      asm volatile("s_waitcnt vmcnt(0)" ::: "memory");
    }
    __builtin_amdgcn_s_barrier();                        // all waves' loads landed
    asm volatile("" ::: "memory");
    const short* As = &lds[cur][0];
    const short* Bs = &lds[cur][128 * BK];
#pragma unroll
    for (int kk = 0; kk < 2; ++kk) {
      bf16x8 bfr[4];
#pragma unroll
      for (int j = 0; j < 4; ++j)
        bfr[j] = *(const bf16x8*)(Bs + (br + j * 16) * BK + ((kk * 32 + kof) ^ rsw));
#pragma unroll
      for (int i = 0; i < 4; ++i) {
        bf16x8 af = *(const bf16x8*)(As + (ar + i * 16) * BK + ((kk * 32 + kof) ^ rsw));
#pragma unroll
        for (int j = 0; j < 4; ++j)
          acc[i][j] = __builtin_amdgcn_mfma_f32_16x16x32_bf16(af, bfr[j], acc[i][j], 0, 0, 0);
      }
    }
    asm volatile("" ::: "memory");
    __builtin_amdgcn_s_barrier();                        // all waves done reading -> next STAGE may overwrite
    asm volatile("" ::: "memory");
    cur ^= 1;
  }

  const int crow = (lane >> 4) * 4;
  const int ccol = lane & 15;
#pragma unroll
  for (int i = 0; i < 4; ++i)
#pragma unroll
    for (int j = 0; j < 4; ++j) {
      size_t base = (size_t)(m0 + wr * 64 + i * 16 + crow) * N + (n0 + wc * 64 + j * 16 + ccol);
      if (BF16OUT) {
        unsigned short* C = (unsigned short*)Cv;
#pragma unroll
        for (int r = 0; r < 4; ++r) C[base + (size_t)r * N] = f2bf(acc[i][j][r]);
      } else {
        float* C = (float*)Cv;
#pragma unroll
        for (int r = 0; r < 4; ++r) C[base + (size_t)r * N] = acc[i][j][r];
      }
    }
}

// ---------------- dt: exact f32 skinny GEMM + softplus (16 rows/block) ----------------
__global__ __launch_bounds__(256) void k_dt(const float* __restrict__ u, const float* __restrict__ W_in,
                                            const float* __restrict__ dt_bias, float* __restrict__ dt_t) {
  __shared__ float Wl[64][132];
  __shared__ float ul[16][132];
  const int t = threadIdx.x;
  const int h = t & 63, rg = t >> 6;     // 4 rows per thread
  const int row0 = blockIdx.x * 16;
  float acc[4] = {0.f, 0.f, 0.f, 0.f};
  for (int k0 = 0; k0 < D_MODEL; k0 += 128) {
    __syncthreads();
    for (int i = t; i < 64 * 32; i += 256) {
      int rr = i >> 5, k4 = (i & 31) * 4;
      float4 v = *(const float4*)(W_in + (size_t)(8448 + rr) * D_MODEL + k0 + k4);
      Wl[rr][k4] = v.x; Wl[rr][k4 + 1] = v.y; Wl[rr][k4 + 2] = v.z; Wl[rr][k4 + 3] = v.w;
    }
    for (int i = t; i < 16 * 32; i += 256) {
      int rr = i >> 5, k4 = (i & 31) * 4;
      float4 v = *(const float4*)(u + (size_t)(row0 + rr) * D_MODEL + k0 + k4);
      ul[rr][k4] = v.x; ul[rr][k4 + 1] = v.y; ul[rr][k4 + 2] = v.z; ul[rr][k4 + 3] = v.w;
    }
    __syncthreads();
#pragma unroll 4
    for (int kk = 0; kk < 128; ++kk) {
      float wv = Wl[h][kk];
#pragma unroll
      for (int r = 0; r < 4; ++r) acc[r] += ul[rg * 4 + r][kk] * wv;
    }
  }
#pragma unroll
  for (int r = 0; r < 4; ++r) {
    float x = acc[r] + dt_bias[h];
    float dtv = (x > 20.f) ? x : log1pf(expf(x));
    int row = row0 + rg * 4 + r; int b = row >> 11; int l = row & 2047;
    dt_t[((size_t)(b * NHEADS + h)) * SEQ + l] = dtv;
  }
}

// ---------------- conv weight/bias pack: f32 -> bf16 transposed ----------------
__global__ void k_conv_pack(const float* __restrict__ cw, const float* __restrict__ cb,
                            unsigned short* __restrict__ wT, unsigned short* __restrict__ bT) {
  int i = blockIdx.x * blockDim.x + threadIdx.x;
  if (i < CONV_DIM) {
#pragma unroll
    for (int w = 0; w < 4; ++w) wT[w * CONV_DIM + i] = f2bf(cw[i * 4 + w]);
    bT[i] = f2bf(cb[i]);
  }
}

// ---------------- conv1d + silu: 8 channels x 4 rows per thread ----------------
__global__ __launch_bounds__(256) void k_conv_silu(const unsigned short* __restrict__ xb,
                                                   const unsigned short* __restrict__ wT,
                                                   const unsigned short* __restrict__ bT,
                                                   unsigned short* __restrict__ out) {
  long idx = (long)blockIdx.x * blockDim.x + threadIdx.x;   // over (NROWS/4)*CG
  if (idx >= (long)(NROWS / 4) * CG) return;
  int c8 = (int)(idx % CG);
  long rq = idx / CG;                      // row-quad id; 512 per batch
  int l0 = (int)((rq & (SEQ / 4 - 1)) * 4);
  long brow = (rq >> 9) * (long)SEQ;       // batch base row
  int ch0 = c8 * 8;

  u16x8 wv[4];
#pragma unroll
  for (int w = 0; w < 4; ++w) wv[w] = *(const u16x8*)(wT + w * CONV_DIM + ch0);
  u16x8 bv = *(const u16x8*)(bT + ch0);

  u16x8 xr[7];
#pragma unroll
  for (int i = 0; i < 7; ++i) {
    int ls = l0 - 3 + i;
    if (ls >= 0) xr[i] = *(const u16x8*)(xb + (brow + ls) * (long)CONV_DIM + ch0);
    else { u16x8 z = {0, 0, 0, 0, 0, 0, 0, 0}; xr[i] = z; }
  }

#pragma unroll
  for (int r = 0; r < 4; ++r) {
    float acc[8];
#pragma unroll
    for (int e = 0; e < 8; ++e) acc[e] = bf2f(bv[e]);
#pragma unroll
    for (int w = 0; w < 4; ++w)
#pragma unroll
      for (int e = 0; e < 8; ++e) acc[e] += bf2f(xr[r + w][e]) * bf2f(wv[w][e]);
    u16x8 o;
#pragma unroll
    for (int e = 0; e < 8; ++e) o[e] = f2bf(acc[e] / (1.f + expf(-acc[e])));
    *(u16x8*)(out + (brow + l0 + r) * (long)CONV_DIM + ch0) = o;
  }
}

// ---------------- per-chunk cumsum of dA ----------------
__global__ __launch_bounds__(256) void k_cumsum(const float* __restrict__ dt_t, const float* __restrict__ A_log,
                                                float* __restrict__ A_cum) {
  const int bid = blockIdx.x;           // (b*NHEADS+h)*NCHUNK + c
  const int c = bid & 7;
  const int bh = bid >> 3;
  const int h = bh & 63;
  const int l = threadIdx.x;
  float A = -expf(A_log[h]);
  __shared__ float s[256];
  s[l] = dt_t[(size_t)bh * SEQ + c * CHUNK + l] * A;
  __syncthreads();
  for (int off = 1; off < 256; off <<= 1) {
    float x = (l >= off) ? s[l - off] : 0.f;
    __syncthreads();
    s[l] += x;
    __syncthreads();
  }
  A_cum[(size_t)bid * CHUNK + l] = s[l];
}

// ---------------- CBT^T[l][s] = C_l . B_s  (bf16 out), MFMA ----------------
__global__ __launch_bounds__(256) void k_cbtt(const unsigned short* __restrict__ xbc, unsigned short* __restrict__ cbt_t) {
  const int bid = blockIdx.x;           // bc*4 + sp
  const int sp = bid & 3;
  const int bc = bid >> 2;
  const int b = bc >> 3, c = bc & 7;
  const int t = threadIdx.x;
  const int lane = t & 63;
  const int w = t >> 6;
  const int g = lane >> 4;
  __shared__ unsigned short Cs[256][72];
  __shared__ unsigned short Bs2[64][72];
  const long rowbase = (long)b * SEQ + c * CHUNK;
  f32x4 acc[4][4];
#pragma unroll
  for (int i = 0; i < 4; ++i)
#pragma unroll
    for (int j = 0; j < 4; ++j) { f32x4 z = {0.f, 0.f, 0.f, 0.f}; acc[i][j] = z; }

  for (int np = 0; np < 2; ++np) {
    __syncthreads();
    for (int i = t; i < 256 * 16; i += 256) {
      int row = i >> 4, c4 = (i & 15) * 4;
      ushort4 v = *(const ushort4*)(xbc + (rowbase + row) * (long)CONV_DIM + D_INNER + D_STATE + np * 64 + c4);
      *(ushort4*)&Cs[row][c4] = v;
    }
    for (int i = t; i < 64 * 16; i += 256) {
      int row = i >> 4, c4 = (i & 15) * 4;
      ushort4 v = *(const ushort4*)(xbc + (rowbase + sp * 64 + row) * (long)CONV_DIM + D_INNER + np * 64 + c4);
      *(ushort4*)&Bs2[row][c4] = v;
    }
    __syncthreads();
#pragma unroll
    for (int ks = 0; ks < 2; ++ks) {
      const int kofs = ks * 32 + g * 8;
      bf16x8 af[4], bfr[4];
#pragma unroll
      for (int i = 0; i < 4; ++i) af[i] = *(const bf16x8*)&Cs[w * 64 + i * 16 + (lane & 15)][kofs];
#pragma unroll
      for (int j = 0; j < 4; ++j) bfr[j] = *(const bf16x8*)&Bs2[j * 16 + (lane & 15)][kofs];
#pragma unroll
      for (int i = 0; i < 4; ++i)
#pragma unroll
        for (int j = 0; j < 4; ++j)
          acc[i][j] = __builtin_amdgcn_mfma_f32_16x16x32_bf16(af[i], bfr[j], acc[i][j], 0, 0, 0);
    }
  }
  unsigned short* ob = cbt_t + (long)bc * CHUNK * CHUNK;
#pragma unroll
  for (int i = 0; i < 4; ++i)
#pragma unroll
    for (int j = 0; j < 4; ++j) {
      int l0 = w * 64 + i * 16 + g * 4;
      int s = sp * 64 + j * 16 + (lane & 15);
#pragma unroll
      for (int r = 0; r < 4; ++r) ob[(long)(l0 + r) * CHUNK + s] = f2bf(acc[i][j][r]);
    }
}

// ---------------- states[n][p] = sum_l B[l][n]*w_l*x[l][p], MFMA ----------------
__global__ __launch_bounds__(256) void k_states(const unsigned short* __restrict__ xbc, const float* __restrict__ dt_t,
                                                const float* __restrict__ A_cum, float* __restrict__ states) {
  const int bid = blockIdx.x;           // bc*NHEADS + h
  const int h = bid & 63;
  const int bc = bid >> 6;
  const int b = bc >> 3, c = bc & 7;
  const int t = threadIdx.x;
  const int lane = t & 63;
  const int w = t >> 6;
  const int g = lane >> 4;
  __shared__ unsigned short BT[128][72];
  __shared__ unsigned short WXT[64][72];
  __shared__ float csL[256], dtL[256];
  const long rowbase = (long)b * SEQ + c * CHUNK;
  const long bh8 = ((long)(b * NHEADS + h)) * NCHUNK + c;
  const float* acum = A_cum + bh8 * CHUNK;
  if (t < 256) { csL[t] = acum[t]; dtL[t] = dt_t[((size_t)(b * NHEADS + h)) * SEQ + c * CHUNK + t]; }
  float cs_last = acum[255];
  f32x4 acc[2][4];
#pragma unroll
  for (int i = 0; i < 2; ++i)
#pragma unroll
    for (int j = 0; j < 4; ++j) { f32x4 z = {0.f, 0.f, 0.f, 0.f}; acc[i][j] = z; }

  for (int lp = 0; lp < 4; ++lp) {
    __syncthreads();
    for (int i = t; i < 64 * 32; i += 256) {
      int l = i >> 5, n4 = (i & 31) * 4;
      ushort4 v = *(const ushort4*)(xbc + (rowbase + lp * 64 + l) * (long)CONV_DIM + D_INNER + n4);
      BT[n4 + 0][l] = v.x; BT[n4 + 1][l] = v.y; BT[n4 + 2][l] = v.z; BT[n4 + 3][l] = v.w;
    }
    for (int i = t; i < 64 * 16; i += 256) {
      int l = i >> 4, p4 = (i & 15) * 4;
      int lg = lp * 64 + l;
      float wgt = expf(cs_last - csL[lg]) * dtL[lg];
      ushort4 v = *(const ushort4*)(xbc + (rowbase + lg) * (long)CONV_DIM + h * HEADDIM + p4);
      WXT[p4 + 0][l] = f2bf(bf2f(v.x) * wgt);
      WXT[p4 + 1][l] = f2bf(bf2f(v.y) * wgt);
      WXT[p4 + 2][l] = f2bf(bf2f(v.z) * wgt);
      WXT[p4 + 3][l] = f2bf(bf2f(v.w) * wgt);
    }
    __syncthreads();
#pragma unroll
    for (int ks = 0; ks < 2; ++ks) {
      const int kofs = ks * 32 + g * 8;
      bf16x8 am[2], bp[4];
#pragma unroll
      for (int i = 0; i < 2; ++i) am[i] = *(const bf16x8*)&BT[w * 32 + i * 16 + (lane & 15)][kofs];
#pragma unroll
      for (int j = 0; j < 4; ++j) bp[j] = *(const bf16x8*)&WXT[j * 16 + (lane & 15)][kofs];
#pragma unroll
      for (int i = 0; i < 2; ++i)
#pragma unroll
        for (int j = 0; j < 4; ++j)
          acc[i][j] = __builtin_amdgcn_mfma_f32_16x16x32_bf16(am[i], bp[j], acc[i][j], 0, 0, 0);
    }
  }
  float* sp = states + ((long)bc * NHEADS + h) * (D_STATE * HEADDIM);
#pragma unroll
  for (int i = 0; i < 2; ++i)
#pragma unroll
    for (int j = 0; j < 4; ++j) {
      int n0 = w * 32 + i * 16 + g * 4;
      int p = j * 16 + (lane & 15);
#pragma unroll
      for (int r = 0; r < 4; ++r) sp[(long)(n0 + r) * HEADDIM + p] = acc[i][j][r];
    }
}

// ---------------- inter-chunk scan -> prev_states (bf16, [n][p]) ----------------
__global__ void k_scan(const float* __restrict__ states, const float* __restrict__ A_cum, unsigned short* __restrict__ psb) {
  long idx = (long)blockIdx.x * blockDim.x + threadIdx.x;   // ((b*64+h)*128+n)*64+p
  if (idx >= (long)BATCH * NHEADS * D_STATE * HEADDIM) return;
  int p = idx & 63;
  int n = (int)((idx >> 6) & 127);
  long bh = idx >> 13;
  int h = (int)(bh & 63);
  int b = (int)(bh >> 6);
  float S = 0.f;
  for (int c = 0; c < NCHUNK; ++c) {
    long soff = (((long)(b * NCHUNK + c) * NHEADS + h) * (D_STATE * HEADDIM)) + (long)n * HEADDIM + p;
    psb[soff] = f2bf(S);
    float decay = expf(A_cum[(bh * NCHUNK + c) * CHUNK + 255]);
    S = S * decay + states[soff];
  }
}

// ---------------- Y = Y_diag + Y_off + x*D (bf16 out), MFMA ----------------
__global__ __launch_bounds__(256) void k_y(const unsigned short* __restrict__ xbc, const float* __restrict__ dt_t,
                                           const float* __restrict__ A_cum, const unsigned short* __restrict__ cbt_t,
                                           const unsigned short* __restrict__ psb, const float* __restrict__ Dp,
                                           unsigned short* __restrict__ y) {
  const int bid = blockIdx.x;           // bc*NHEADS + h
  const int h = bid & 63;
  const int bc = bid >> 6;
  const int b = bc >> 3, c = bc & 7;
  const int t = threadIdx.x;
  const int lane = t & 63;
  const int w = t >> 6;
  const int g = lane >> 4;
  __shared__ unsigned short Abuf[256][72];
  __shared__ unsigned short Bbuf[64][72];
  __shared__ float csL[256], dtL[256], expL[256];
  const long rowbase = (long)b * SEQ + c * CHUNK;
  const long bh8 = ((long)(b * NHEADS + h)) * NCHUNK + c;
  const float* acum = A_cum + bh8 * CHUNK;
  if (t < 256) {
    float cv = acum[t];
    csL[t] = cv;
    expL[t] = expf(cv);
    dtL[t] = dt_t[((size_t)(b * NHEADS + h)) * SEQ + c * CHUNK + t];
  }
  f32x4 acc[4][4];
#pragma unroll
  for (int i = 0; i < 4; ++i)
#pragma unroll
    for (int j = 0; j < 4; ++j) { f32x4 z = {0.f, 0.f, 0.f, 0.f}; acc[i][j] = z; }

  // ---- phase 1: Y_off = (C .* exp(cs_l)) @ PS^T ----
  const unsigned short* psbase = psb + ((long)bc * NHEADS + h) * (D_STATE * HEADDIM);
  for (int np = 0; np < 2; ++np) {
    __syncthreads();
    for (int i = t; i < 256 * 16; i += 256) {
      int row = i >> 4, c4 = (i & 15) * 4;
      float el = expL[row];
      ushort4 v = *(const ushort4*)(xbc + (rowbase + row) * (long)CONV_DIM + D_INNER + D_STATE + np * 64 + c4);
      ushort4 o = make_ushort4(f2bf(bf2f(v.x) * el), f2bf(bf2f(v.y) * el), f2bf(bf2f(v.z) * el), f2bf(bf2f(v.w) * el));
      *(ushort4*)&Abuf[row][c4] = o;
    }
    for (int i = t; i < 64 * 16; i += 256) {
      int n = i >> 4, p4 = (i & 15) * 4;
      ushort4 v = *(const ushort4*)(psbase + (long)(np * 64 + n) * HEADDIM + p4);
      Bbuf[p4 + 0][n] = v.x; Bbuf[p4 + 1][n] = v.y; Bbuf[p4 + 2][n] = v.z; Bbuf[p4 + 3][n] = v.w;
    }
    __syncthreads();
#pragma unroll
    for (int ks = 0; ks < 2; ++ks) {
      const int kofs = ks * 32 + g * 8;
      bf16x8 af[4], bfr[4];
#pragma unroll
      for (int i = 0; i < 4; ++i) af[i] = *(const bf16x8*)&Abuf[w * 64 + i * 16 + (lane & 15)][kofs];
#pragma unroll
      for (int j = 0; j < 4; ++j) bfr[j] = *(const bf16x8*)&Bbuf[j * 16 + (lane & 15)][kofs];
#pragma unroll
      for (int i = 0; i < 4; ++i)
#pragma unroll
        for (int j = 0; j < 4; ++j)
          acc[i][j] = __builtin_amdgcn_mfma_f32_16x16x32_bf16(af[i], bfr[j], acc[i][j], 0, 0, 0);
    }
  }

  // ---- phase 2: Y_diag, scores in-register ----
  const unsigned short* cbtb = cbt_t + (long)bc * CHUNK * CHUNK;
  for (int sp = 0; sp < 4; ++sp) {
    __syncthreads();
    for (int i = t; i < 64 * 8; i += 256) {
      int s = i >> 3, p0 = (i & 7) * 8;
      u16x8 v = *(const u16x8*)(xbc + (rowbase + sp * 64 + s) * (long)CONV_DIM + h * HEADDIM + p0);
#pragma unroll
      for (int e = 0; e < 8; ++e) Bbuf[p0 + e][s] = v[e];
    }
    __syncthreads();
    if (sp > w) continue;
#pragma unroll
    for (int ks = 0; ks < 2; ++ks) {
      const int kofs = ks * 32 + g * 8;
      bf16x8 bfr[4];
#pragma unroll
      for (int j = 0; j < 4; ++j) bfr[j] = *(const bf16x8*)&Bbuf[j * 16 + (lane & 15)][kofs];
      const int sbase = sp * 64 + ks * 32 + g * 8;
#pragma unroll
      for (int i = 0; i < 4; ++i) {
        if (sp == w && ks * 32 > i * 16 + 15) continue;
        const int l = w * 64 + i * 16 + (lane & 15);
        u16x8 cv = *(const u16x8*)(cbtb + (long)l * CHUNK + sbase);
        const float cl = csL[l];
        bf16x8 af;
#pragma unroll
        for (int e = 0; e < 8; ++e) {
          int s = sbase + e;
          float val = (s <= l) ? bf2f(cv[e]) * expf(cl - csL[s]) * dtL[s] : 0.f;
          af[e] = (short)f2bf(val);
        }
#pragma unroll
        for (int j = 0; j < 4; ++j)
          acc[i][j] = __builtin_amdgcn_mfma_f32_16x16x32_bf16(af, bfr[j], acc[i][j], 0, 0, 0);
      }
    }
  }

  // ---- epilogue: skip connection + bf16 store ----
  const float Dh = Dp[h];
#pragma unroll
  for (int i = 0; i < 4; ++i) {
    int l0 = w * 64 + i * 16 + g * 4;
#pragma unroll
    for (int r = 0; r < 4; ++r) {
      long grow = rowbase + l0 + r;
      const unsigned short* xrow = xbc + grow * (long)CONV_DIM + h * HEADDIM;
      unsigned short* yrow = y + grow * (long)D_INNER + h * HEADDIM;
#pragma unroll
      for (int j = 0; j < 4; ++j) {
        int p = j * 16 + (lane & 15);
        yrow[p] = f2bf(acc[i][j][r] + bf2f(xrow[p]) * Dh);
      }
    }
  }
}

// ---------------- gated RMSNorm (bf16 y,z in; bf16 out, in-place over y ok) ----------------
__global__ __launch_bounds__(256) void k_norm(unsigned short* yz, const unsigned short* __restrict__ zb,
                                              const float* __restrict__ norm_w, unsigned short* out) {
  const int row = blockIdx.x;
  const int t = threadIdx.x;
  const unsigned short* yr = yz + (size_t)row * D_INNER;
  const unsigned short* zr = zb + (size_t)row * D_INNER;
  float yv[16];
  float ss = 0.f;
#pragma unroll
  for (int j = 0; j < 4; ++j) {
    int e = (t + j * 256) * 4;
    ushort4 yy = *(const ushort4*)(yr + e);
    ushort4 zz = *(const ushort4*)(zr + e);
    float z0 = bf2f(zz.x), z1 = bf2f(zz.y), z2 = bf2f(zz.z), z3 = bf2f(zz.w);
    float g0 = bf2f(yy.x) * z0 / (1.f + expf(-z0));
    float g1 = bf2f(yy.y) * z1 / (1.f + expf(-z1));
    float g2 = bf2f(yy.z) * z2 / (1.f + expf(-z2));
    float g3 = bf2f(yy.w) * z3 / (1.f + expf(-z3));
    ss += g0 * g0 + g1 * g1 + g2 * g2 + g3 * g3;
    yv[j * 4 + 0] = g0; yv[j * 4 + 1] = g1; yv[j * 4 + 2] = g2; yv[j * 4 + 3] = g3;
  }
#pragma unroll
  for (int off = 32; off > 0; off >>= 1) ss += __shfl_xor(ss, off);
  __shared__ float red[4];
  if ((t & 63) == 0) red[t >> 6] = ss;
  __syncthreads();
  float tot = red[0] + red[1] + red[2] + red[3];
  float scale = rsqrtf(tot / (float)D_INNER + EPSV);
  unsigned short* orow = out + (size_t)row * D_INNER;
#pragma unroll
  for (int j = 0; j < 4; ++j) {
    int e = (t + j * 256) * 4;
    float4 w = *(const float4*)(norm_w + e);
    ushort4 o = make_ushort4(f2bf(yv[j * 4 + 0] * scale * w.x), f2bf(yv[j * 4 + 1] * scale * w.y),
                             f2bf(yv[j * 4 + 2] * scale * w.z), f2bf(yv[j * 4 + 3] * scale * w.w));
    *(ushort4*)(orow + e) = o;
  }
}

extern "C" void kernel_launch(void* const* d_in, const int* in_sizes, int n_in,
                              void* d_out, int out_size, void* d_ws, size_t ws_size,
                              hipStream_t stream) {
  const float* u       = (const float*)d_in[0];
  const float* W_in    = (const float*)d_in[1];
  const float* conv_w  = (const float*)d_in[2];
  const float* conv_b  = (const float*)d_in[3];
  const float* dt_bias = (const float*)d_in[4];
  const float* A_log   = (const float*)d_in[5];
  const float* Dp      = (const float*)d_in[6];
  const float* norm_w  = (const float*)d_in[7];
  const float* W_out   = (const float*)d_in[8];
  float* out = (float*)d_out;

  char* ws = (char*)d_ws;
  size_t off = 0;
  auto alloc = [&](size_t bytes) { char* p = ws + off; off += (bytes + 255) & ~(size_t)255; return p; };
  unsigned short* ub   = (unsigned short*)alloc((size_t)NROWS * D_MODEL * 2);        // -> wob later
  unsigned short* winb = (unsigned short*)alloc((size_t)D_IN_PROJ * D_MODEL * 2);    // -> cbt_t + psb later
  unsigned short* zb   = (unsigned short*)alloc((size_t)NROWS * D_INNER * 2);
  unsigned short* xb   = (unsigned short*)alloc((size_t)NROWS * CONV_DIM * 2);       // -> yb later
  unsigned short* xbcb = (unsigned short*)alloc((size_t)NROWS * CONV_DIM * 2);
  float* dtt  = (float*)alloc((size_t)BATCH * NHEADS * SEQ * 4);
  float* acum = (float*)alloc((size_t)BATCH * NHEADS * NCHUNK * CHUNK * 4);
  unsigned short* cwT = (unsigned short*)alloc((size_t)4 * CONV_DIM * 2);
  unsigned short* cbT = (unsigned short*)alloc((size_t)CONV_DIM * 2);
  unsigned short* wob = ub;                        // W_out bf16, after GEMM1s
  unsigned short* cbt = winb;                      // CBT^T bf16, after GEMM1s
  unsigned short* psb = winb + (size_t)BATCH * NCHUNK * CHUNK * CHUNK + 1024;  // prev_states bf16
  unsigned short* yb = xb;                         // y bf16, after conv
  float* states = (float*)d_out;                   // scratch == out_size; overwritten by GEMM2

  if (off > ws_size) {
    k_sentinel<<<1, 64, 0, stream>>>(out);
    return;
  }

  k_f32_to_bf16_v4<<<2048, 256, 0, stream>>>(u, ub, (long)NROWS * D_MODEL / 4);
  k_f32_to_bf16_v4<<<2048, 256, 0, stream>>>(W_in, winb, (long)D_IN_PROJ * D_MODEL / 4);
  k_conv_pack<<<(CONV_DIM + 255) / 256, 256, 0, stream>>>(conv_w, conv_b, cwT, cbT);
  k_gemm128<1><<<(NROWS / 128) * (D_INNER / 128), 256, 0, stream>>>(ub, winb, zb, NROWS, D_INNER, D_MODEL);
  k_gemm128<1><<<(NROWS / 128) * (CONV_DIM / 128), 256, 0, stream>>>(ub, winb + (size_t)D_INNER * D_MODEL, xb, NROWS, CONV_DIM, D_MODEL);
  k_dt<<<NROWS / 16, 256, 0, stream>>>(u, W_in, dt_bias, dtt);
  k_conv_silu<<<(int)(((long)(NROWS / 4) * CG + 255) / 256), 256, 0, stream>>>(xb, cwT, cbT, xbcb);
  k_cumsum<<<BATCH * NHEADS * NCHUNK, 256, 0, stream>>>(dtt, A_log, acum);
  k_cbtt<<<BATCH * NCHUNK * 4, 256, 0, stream>>>(xbcb, cbt);
  k_states<<<BATCH * NCHUNK * NHEADS, 256, 0, stream>>>(xbcb, dtt, acum, states);
  k_scan<<<(BATCH * NHEADS * D_STATE * HEADDIM + 255) / 256, 256, 0, stream>>>(states, acum, psb);
  k_y<<<BATCH * NCHUNK * NHEADS, 256, 0, stream>>>(xbcb, dtt, acum, cbt, psb, Dp, yb);
  k_norm<<<NROWS, 256, 0, stream>>>(yb, zb, norm_w, yb);
  k_f32_to_bf16_v4<<<2048, 256, 0, stream>>>(W_out, wob, (long)D_MODEL * D_INNER / 4);
  k_gemm128<0><<<(NROWS / 128) * (D_MODEL / 128), 256, 0, stream>>>(yb, wob, out, NROWS, D_MODEL, D_INNER);
}

// Round 7
// 565.052 us; speedup vs baseline: 1.9413x; 1.0179x over previous
//
#include <hip/hip_runtime.h>

#define D_MODEL   2048
#define D_INNER   4096
#define HEADDIM   64
#define NHEADS    64
#define D_STATE   128
#define CHUNK     256
#define CONV_DIM  4352
#define D_IN_PROJ 8512
#define BATCH     2
#define SEQ       2048
#define NCHUNK    8
#define NROWS     4096
#define EPSV      1e-5f
#define CG        (CONV_DIM / 8)   // 544

typedef __attribute__((ext_vector_type(8))) short bf16x8;
typedef __attribute__((ext_vector_type(8))) unsigned short u16x8;
typedef __attribute__((ext_vector_type(4))) float f32x4;

#define AS1 __attribute__((address_space(1)))
#define AS3 __attribute__((address_space(3)))

#define BAR() do { asm volatile("" ::: "memory"); __builtin_amdgcn_s_barrier(); asm volatile("" ::: "memory"); } while (0)

__device__ __forceinline__ unsigned short f2bf(float f) {
  unsigned int x = __float_as_uint(f);
  unsigned int r = (x + 0x7fffu + ((x >> 16) & 1u)) >> 16;
  return (unsigned short)r;
}
__device__ __forceinline__ float bf2f(unsigned short u) {
  return __uint_as_float((unsigned int)u << 16);
}

__global__ void k_sentinel(float* out) { if (threadIdx.x == 0) out[0] = 1.0e6f; }

// ---------------- converts ----------------
__global__ void k_f32_to_bf16_v4(const float* __restrict__ in, unsigned short* __restrict__ out, long n4) {
  long i = (long)blockIdx.x * blockDim.x + threadIdx.x;
  long stride = (long)gridDim.x * blockDim.x;
  for (; i < n4; i += stride) {
    float4 v = ((const float4*)in)[i];
    ushort4 o = make_ushort4(f2bf(v.x), f2bf(v.y), f2bf(v.z), f2bf(v.w));
    ((ushort4*)out)[i] = o;
  }
}

// ---- 256x256 BK=64 8-phase GEMM (T2+T3+T4+T5), 512 thr, 8 waves (2Mx4N), grid%8==0, 1 block/CU ----
// A[M][K] @ B[N][K]^T -> C[M][N] bf16.
__global__ __launch_bounds__(512, 2) void k_gemm8p(const unsigned short* __restrict__ A,
                                                   const unsigned short* __restrict__ B,
                                                   unsigned short* __restrict__ C, int M, int N, int K) {
  __shared__ __align__(16) short lds[2][32768];   // per buf: A [256][64] shorts 0..16383, B 16384..32767
  const int t = threadIdx.x;
  const int lane = t & 63;
  const int wid = t >> 6;
  const int wr = wid >> 2;        // 0..1 -> rows wr*128..+128
  const int wc = wid & 3;         // 0..3 -> cols wc*64..+64
  const int ntx = N / 256;
  const int nwg = (int)gridDim.x;
  const int bid = (int)blockIdx.x;
  const int swzb = (bid & 7) * (nwg >> 3) + (bid >> 3);
  const int m0 = (swzb / ntx) * 256;
  const int n0 = (swzb % ntx) * 256;

  f32x4 acc[8][4];
#pragma unroll
  for (int i = 0; i < 8; ++i)
#pragma unroll
    for (int j = 0; j < 4; ++j) { f32x4 z = {0.f, 0.f, 0.f, 0.f}; acc[i][j] = z; }

  // staging: thread t -> row (t>>3) within a 64-row group, source chunk inverse-swizzled
  const int srow = t >> 3;                       // 0..63
  const int schunk = (t & 7) ^ (srow & 7);
  const unsigned short* gA = A + (size_t)(m0 + srow) * K + schunk * 8;
  const unsigned short* gB = B + (size_t)(n0 + srow) * K + schunk * 8;

  // which: 0=A0(rows 0-127) 1=A1 2=B0 3=B1 ; half = 2 insts x 64 rows
  auto STAGE_HALF = [&](int buf, int kt, int which) {
    const unsigned short* g = (which < 2 ? gA : gB) + (size_t)(which & 1) * 128 * K + (size_t)kt * 64;
    char* d = (char*)lds + buf * 65536 + which * 16384 + t * 16;
    __builtin_amdgcn_global_load_lds((const AS1 void*)g, (AS3 void*)d, 16, 0, 0);
    __builtin_amdgcn_global_load_lds((const AS1 void*)(g + (size_t)64 * K), (AS3 void*)(d + 8192), 16, 0, 0);
  };

  const int NT = K / 64;
  // prologue: t0 all 4 halves + t1 {B0, A0, A1}; wait until only t1's 3 halves in flight
  STAGE_HALF(0, 0, 0); STAGE_HALF(0, 0, 1); STAGE_HALF(0, 0, 2); STAGE_HALF(0, 0, 3);
  STAGE_HALF(1, 1, 2); STAGE_HALF(1, 1, 0); STAGE_HALF(1, 1, 1);
  asm volatile("s_waitcnt vmcnt(6)" ::: "memory");
  BAR();

  const int ar = wr * 128 + (lane & 15);
  const int br = wc * 64 + (lane & 15);
  const int kof = (lane >> 4) * 8;
  const int rsw = (lane & 7) * 8;

  for (int kt = 0; kt < NT; ++kt) {
    const int buf = kt & 1;
    const short* As = &lds[buf][0];
    const short* Bs = &lds[buf][16384];
    const bool s1 = (kt + 1 < NT);
    const bool s2 = (kt + 2 < NT);
    bf16x8 aLo[4][2], aHi[4][2], bLo[2][2], bHi[2][2];

    // ---- phase 1: read A(i0-3) + B(j0-1); stage (t+1, B1); MFMA i0-3 x j0-1 ----
#pragma unroll
    for (int i = 0; i < 4; ++i)
#pragma unroll
      for (int k = 0; k < 2; ++k) aLo[i][k] = *(const bf16x8*)(As + (ar + i * 16) * 64 + ((k * 32 + kof) ^ rsw));
#pragma unroll
    for (int j = 0; j < 2; ++j)
#pragma unroll
      for (int k = 0; k < 2; ++k) bLo[j][k] = *(const bf16x8*)(Bs + (br + j * 16) * 64 + ((k * 32 + kof) ^ rsw));
    if (s1) STAGE_HALF(buf ^ 1, kt + 1, 3);
    BAR();
    __builtin_amdgcn_s_setprio(1);
#pragma unroll
    for (int k = 0; k < 2; ++k)
#pragma unroll
      for (int i = 0; i < 4; ++i)
#pragma unroll
        for (int j = 0; j < 2; ++j)
          acc[i][j] = __builtin_amdgcn_mfma_f32_16x16x32_bf16(aLo[i][k], bLo[j][k], acc[i][j], 0, 0, 0);
    __builtin_amdgcn_s_setprio(0);
    BAR();

    // ---- phase 2: read B(j2-3); MFMA i0-3 x j2-3 ----
#pragma unroll
    for (int j = 0; j < 2; ++j)
#pragma unroll
      for (int k = 0; k < 2; ++k) bHi[j][k] = *(const bf16x8*)(Bs + (br + (j + 2) * 16) * 64 + ((k * 32 + kof) ^ rsw));
    BAR();
    __builtin_amdgcn_s_setprio(1);
#pragma unroll
    for (int k = 0; k < 2; ++k)
#pragma unroll
      for (int i = 0; i < 4; ++i)
#pragma unroll
        for (int j = 0; j < 2; ++j)
          acc[i][j + 2] = __builtin_amdgcn_mfma_f32_16x16x32_bf16(aLo[i][k], bHi[j][k], acc[i][j + 2], 0, 0, 0);
    __builtin_amdgcn_s_setprio(0);
    BAR();

    // ---- phase 3: read A(i4-7); stage (t+2, B0) [B-reads of t ended ph1]; MFMA i4-7 x j0-1 ----
#pragma unroll
    for (int i = 0; i < 4; ++i)
#pragma unroll
      for (int k = 0; k < 2; ++k) aHi[i][k] = *(const bf16x8*)(As + (ar + (i + 4) * 16) * 64 + ((k * 32 + kof) ^ rsw));
    if (s2) STAGE_HALF(buf, kt + 2, 2);
    BAR();
    __builtin_amdgcn_s_setprio(1);
#pragma unroll
    for (int k = 0; k < 2; ++k)
#pragma unroll
      for (int i = 0; i < 4; ++i)
#pragma unroll
        for (int j = 0; j < 2; ++j)
          acc[i + 4][j] = __builtin_amdgcn_mfma_f32_16x16x32_bf16(aHi[i][k], bLo[j][k], acc[i + 4][j], 0, 0, 0);
    __builtin_amdgcn_s_setprio(0);
    BAR();

    // ---- phase 4: stage (t+2, A0),(t+2, A1) [A-reads of t ended ph3]; counted vmcnt; MFMA i4-7 x j2-3 ----
    if (s2) { STAGE_HALF(buf, kt + 2, 0); STAGE_HALF(buf, kt + 2, 1); }
    if (s2) { asm volatile("s_waitcnt vmcnt(6)" ::: "memory"); }
    else    { asm volatile("s_waitcnt vmcnt(0)" ::: "memory"); }
    BAR();
    __builtin_amdgcn_s_setprio(1);
#pragma unroll
    for (int k = 0; k < 2; ++k)
#pragma unroll
      for (int i = 0; i < 4; ++i)
#pragma unroll
        for (int j = 0; j < 2; ++j)
          acc[i + 4][j + 2] = __builtin_amdgcn_mfma_f32_16x16x32_bf16(aHi[i][k], bHi[j][k], acc[i + 4][j + 2], 0, 0, 0);
    __builtin_amdgcn_s_setprio(0);
    BAR();
  }

  const int crow = (lane >> 4) * 4;
  const int ccol = lane & 15;
#pragma unroll
  for (int i = 0; i < 8; ++i)
#pragma unroll
    for (int j = 0; j < 4; ++j) {
      size_t base = (size_t)(m0 + wr * 128 + i * 16 + crow) * N + (n0 + wc * 64 + j * 16 + ccol);
#pragma unroll
      for (int r = 0; r < 4; ++r) C[base + (size_t)r * N] = f2bf(acc[i][j][r]);
    }
}

// ---- 128x128 BK=64 double-buffered GEMM, counted vmcnt + raw barriers + T2 swizzle + XCD swizzle ----
template <int BF16OUT>
__global__ __launch_bounds__(256, 2) void k_gemm128(const unsigned short* __restrict__ A,
                                                    const unsigned short* __restrict__ B,
                                                    void* __restrict__ Cv, int M, int N, int K) {
  constexpr int BK = 64;
  __shared__ __align__(16) short lds[2][256 * BK];
  const int t = threadIdx.x;
  const int lane = t & 63;
  const int wid = t >> 6;
  const int wr = wid >> 1;
  const int wc = wid & 1;
  const int ntx = N / 128;
  const int nwg = (int)gridDim.x;
  const int bid = (int)blockIdx.x;
  const int swzb = (bid & 7) * (nwg >> 3) + (bid >> 3);
  const int m0 = (swzb / ntx) * 128;
  const int n0 = (swzb % ntx) * 128;

  f32x4 acc[4][4];
#pragma unroll
  for (int i = 0; i < 4; ++i)
#pragma unroll
    for (int j = 0; j < 4; ++j) { f32x4 z = {0.f, 0.f, 0.f, 0.f}; acc[i][j] = z; }

  const int srow = t >> 3;
  const int schunk = (t & 7) ^ (srow & 7);
  const unsigned short* gA = A + (size_t)(m0 + srow) * K + schunk * 8;
  const unsigned short* gB = B + (size_t)(n0 + srow) * K + schunk * 8;

  auto STAGE = [&](int buf, int kt) {
    char* dA = (char*)&lds[buf][0] + t * 16;
    char* dB = (char*)&lds[buf][128 * BK] + t * 16;
#pragma unroll
    for (int ii = 0; ii < 4; ++ii)
      __builtin_amdgcn_global_load_lds((const AS1 void*)(gA + (size_t)ii * 32 * K + kt * BK),
                                       (AS3 void*)(dA + ii * 4096), 16, 0, 0);
#pragma unroll
    for (int ii = 0; ii < 4; ++ii)
      __builtin_amdgcn_global_load_lds((const AS1 void*)(gB + (size_t)ii * 32 * K + kt * BK),
                                       (AS3 void*)(dB + ii * 4096), 16, 0, 0);
  };

  STAGE(0, 0);

  const int NT = K / BK;
  const int ar = wr * 64 + (lane & 15);
  const int br = wc * 64 + (lane & 15);
  const int kof = (lane >> 4) * 8;
  const int rsw = (lane & 7) * 8;
  int cur = 0;
  for (int kt = 0; kt < NT; ++kt) {
    if (kt + 1 < NT) {
      STAGE(cur ^ 1, kt + 1);
      asm volatile("s_waitcnt vmcnt(8)" ::: "memory");
    } else {
      asm volatile("s_waitcnt vmcnt(0)" ::: "memory");
    }
    __builtin_amdgcn_s_barrier();
    asm volatile("" ::: "memory");
    const short* As = &lds[cur][0];
    const short* Bs = &lds[cur][128 * BK];
#pragma unroll
    for (int kk = 0; kk < 2; ++kk) {
      bf16x8 bfr[4];
#pragma unroll
      for (int j = 0; j < 4; ++j)
        bfr[j] = *(const bf16x8*)(Bs + (br + j * 16) * BK + ((kk * 32 + kof) ^ rsw));
#pragma unroll
      for (int i = 0; i < 4; ++i) {
        bf16x8 af = *(const bf16x8*)(As + (ar + i * 16) * BK + ((kk * 32 + kof) ^ rsw));
#pragma unroll
        for (int j = 0; j < 4; ++j)
          acc[i][j] = __builtin_amdgcn_mfma_f32_16x16x32_bf16(af, bfr[j], acc[i][j], 0, 0, 0);
      }
    }
    asm volatile("" ::: "memory");
    __builtin_amdgcn_s_barrier();
    asm volatile("" ::: "memory");
    cur ^= 1;
  }

  const int crow = (lane >> 4) * 4;
  const int ccol = lane & 15;
#pragma unroll
  for (int i = 0; i < 4; ++i)
#pragma unroll
    for (int j = 0; j < 4; ++j) {
      size_t base = (size_t)(m0 + wr * 64 + i * 16 + crow) * N + (n0 + wc * 64 + j * 16 + ccol);
      if (BF16OUT) {
        unsigned short* C = (unsigned short*)Cv;
#pragma unroll
        for (int r = 0; r < 4; ++r) C[base + (size_t)r * N] = f2bf(acc[i][j][r]);
      } else {
        float* C = (float*)Cv;
#pragma unroll
        for (int r = 0; r < 4; ++r) C[base + (size_t)r * N] = acc[i][j][r];
      }
    }
}

// ---------------- dt: exact f32 skinny GEMM + softplus (16 rows/block) ----------------
__global__ __launch_bounds__(256) void k_dt(const float* __restrict__ u, const float* __restrict__ W_in,
                                            const float* __restrict__ dt_bias, float* __restrict__ dt_t) {
  __shared__ float Wl[64][133];
  __shared__ float ul[16][133];
  const int t = threadIdx.x;
  const int h = t & 63, rg = t >> 6;
  const int row0 = blockIdx.x * 16;
  float acc[4] = {0.f, 0.f, 0.f, 0.f};
  for (int k0 = 0; k0 < D_MODEL; k0 += 128) {
    __syncthreads();
    for (int i = t; i < 64 * 32; i += 256) {
      int rr = i >> 5, k4 = (i & 31) * 4;
      float4 v = *(const float4*)(W_in + (size_t)(8448 + rr) * D_MODEL + k0 + k4);
      Wl[rr][k4] = v.x; Wl[rr][k4 + 1] = v.y; Wl[rr][k4 + 2] = v.z; Wl[rr][k4 + 3] = v.w;
    }
    for (int i = t; i < 16 * 32; i += 256) {
      int rr = i >> 5, k4 = (i & 31) * 4;
      float4 v = *(const float4*)(u + (size_t)(row0 + rr) * D_MODEL + k0 + k4);
      ul[rr][k4] = v.x; ul[rr][k4 + 1] = v.y; ul[rr][k4 + 2] = v.z; ul[rr][k4 + 3] = v.w;
    }
    __syncthreads();
#pragma unroll 4
    for (int kk = 0; kk < 128; ++kk) {
      float wv = Wl[h][kk];
#pragma unroll
      for (int r = 0; r < 4; ++r) acc[r] += ul[rg * 4 + r][kk] * wv;
    }
  }
#pragma unroll
  for (int r = 0; r < 4; ++r) {
    float x = acc[r] + dt_bias[h];
    float dtv = (x > 20.f) ? x : log1pf(expf(x));
    int row = row0 + rg * 4 + r; int b = row >> 11; int l = row & 2047;
    dt_t[((size_t)(b * NHEADS + h)) * SEQ + l] = dtv;
  }
}

// ---------------- conv weight/bias pack: f32 -> bf16 transposed ----------------
__global__ void k_conv_pack(const float* __restrict__ cw, const float* __restrict__ cb,
                            unsigned short* __restrict__ wT, unsigned short* __restrict__ bT) {
  int i = blockIdx.x * blockDim.x + threadIdx.x;
  if (i < CONV_DIM) {
#pragma unroll
    for (int w = 0; w < 4; ++w) wT[w * CONV_DIM + i] = f2bf(cw[i * 4 + w]);
    bT[i] = f2bf(cb[i]);
  }
}

// ---------------- conv1d + silu: 8 channels x 4 rows per thread ----------------
__global__ __launch_bounds__(256) void k_conv_silu(const unsigned short* __restrict__ xb,
                                                   const unsigned short* __restrict__ wT,
                                                   const unsigned short* __restrict__ bT,
                                                   unsigned short* __restrict__ out) {
  long idx = (long)blockIdx.x * blockDim.x + threadIdx.x;
  if (idx >= (long)(NROWS / 4) * CG) return;
  int c8 = (int)(idx % CG);
  long rq = idx / CG;
  int l0 = (int)((rq & (SEQ / 4 - 1)) * 4);
  long brow = (rq >> 9) * (long)SEQ;
  int ch0 = c8 * 8;

  u16x8 wv[4];
#pragma unroll
  for (int w = 0; w < 4; ++w) wv[w] = *(const u16x8*)(wT + w * CONV_DIM + ch0);
  u16x8 bv = *(const u16x8*)(bT + ch0);

  u16x8 xr[7];
#pragma unroll
  for (int i = 0; i < 7; ++i) {
    int ls = l0 - 3 + i;
    if (ls >= 0) xr[i] = *(const u16x8*)(xb + (brow + ls) * (long)CONV_DIM + ch0);
    else { u16x8 z = {0, 0, 0, 0, 0, 0, 0, 0}; xr[i] = z; }
  }

#pragma unroll
  for (int r = 0; r < 4; ++r) {
    float acc[8];
#pragma unroll
    for (int e = 0; e < 8; ++e) acc[e] = bf2f(bv[e]);
#pragma unroll
    for (int w = 0; w < 4; ++w)
#pragma unroll
      for (int e = 0; e < 8; ++e) acc[e] += bf2f(xr[r + w][e]) * bf2f(wv[w][e]);
    u16x8 o;
#pragma unroll
    for (int e = 0; e < 8; ++e) o[e] = f2bf(acc[e] / (1.f + expf(-acc[e])));
    *(u16x8*)(out + (brow + l0 + r) * (long)CONV_DIM + ch0) = o;
  }
}

// ---------------- per-chunk cumsum of dA ----------------
__global__ __launch_bounds__(256) void k_cumsum(const float* __restrict__ dt_t, const float* __restrict__ A_log,
                                                float* __restrict__ A_cum) {
  const int bid = blockIdx.x;
  const int c = bid & 7;
  const int bh = bid >> 3;
  const int h = bh & 63;
  const int l = threadIdx.x;
  float A = -expf(A_log[h]);
  __shared__ float s[256];
  s[l] = dt_t[(size_t)bh * SEQ + c * CHUNK + l] * A;
  __syncthreads();
  for (int off = 1; off < 256; off <<= 1) {
    float x = (l >= off) ? s[l - off] : 0.f;
    __syncthreads();
    s[l] += x;
    __syncthreads();
  }
  A_cum[(size_t)bid * CHUNK + l] = s[l];
}

// ---------------- CBT^T[l][s] = C_l . B_s  (bf16 out), MFMA ----------------
__global__ __launch_bounds__(256) void k_cbtt(const unsigned short* __restrict__ xbc, unsigned short* __restrict__ cbt_t) {
  const int bid = blockIdx.x;
  const int sp = bid & 3;
  const int bc = bid >> 2;
  const int b = bc >> 3, c = bc & 7;
  const int t = threadIdx.x;
  const int lane = t & 63;
  const int w = t >> 6;
  const int g = lane >> 4;
  __shared__ unsigned short Cs[256][72];
  __shared__ unsigned short Bs2[64][72];
  const long rowbase = (long)b * SEQ + c * CHUNK;
  f32x4 acc[4][4];
#pragma unroll
  for (int i = 0; i < 4; ++i)
#pragma unroll
    for (int j = 0; j < 4; ++j) { f32x4 z = {0.f, 0.f, 0.f, 0.f}; acc[i][j] = z; }

  for (int np = 0; np < 2; ++np) {
    __syncthreads();
    for (int i = t; i < 256 * 16; i += 256) {
      int row = i >> 4, c4 = (i & 15) * 4;
      ushort4 v = *(const ushort4*)(xbc + (rowbase + row) * (long)CONV_DIM + D_INNER + D_STATE + np * 64 + c4);
      *(ushort4*)&Cs[row][c4] = v;
    }
    for (int i = t; i < 64 * 16; i += 256) {
      int row = i >> 4, c4 = (i & 15) * 4;
      ushort4 v = *(const ushort4*)(xbc + (rowbase + sp * 64 + row) * (long)CONV_DIM + D_INNER + np * 64 + c4);
      *(ushort4*)&Bs2[row][c4] = v;
    }
    __syncthreads();
#pragma unroll
    for (int ks = 0; ks < 2; ++ks) {
      const int kofs = ks * 32 + g * 8;
      bf16x8 af[4], bfr[4];
#pragma unroll
      for (int i = 0; i < 4; ++i) af[i] = *(const bf16x8*)&Cs[w * 64 + i * 16 + (lane & 15)][kofs];
#pragma unroll
      for (int j = 0; j < 4; ++j) bfr[j] = *(const bf16x8*)&Bs2[j * 16 + (lane & 15)][kofs];
#pragma unroll
      for (int i = 0; i < 4; ++i)
#pragma unroll
        for (int j = 0; j < 4; ++j)
          acc[i][j] = __builtin_amdgcn_mfma_f32_16x16x32_bf16(af[i], bfr[j], acc[i][j], 0, 0, 0);
    }
  }
  unsigned short* ob = cbt_t + (long)bc * CHUNK * CHUNK;
#pragma unroll
  for (int i = 0; i < 4; ++i)
#pragma unroll
    for (int j = 0; j < 4; ++j) {
      int l0 = w * 64 + i * 16 + g * 4;
      int s = sp * 64 + j * 16 + (lane & 15);
#pragma unroll
      for (int r = 0; r < 4; ++r) ob[(long)(l0 + r) * CHUNK + s] = f2bf(acc[i][j][r]);
    }
}

// ---------------- states[n][p] = sum_l B[l][n]*w_l*x[l][p], MFMA ----------------
__global__ __launch_bounds__(256) void k_states(const unsigned short* __restrict__ xbc, const float* __restrict__ dt_t,
                                                const float* __restrict__ A_cum, float* __restrict__ states) {
  const int bid = blockIdx.x;
  const int h = bid & 63;
  const int bc = bid >> 6;
  const int b = bc >> 3, c = bc & 7;
  const int t = threadIdx.x;
  const int lane = t & 63;
  const int w = t >> 6;
  const int g = lane >> 4;
  __shared__ unsigned short BT[128][72];
  __shared__ unsigned short WXT[64][72];
  __shared__ float csL[256], dtL[256];
  const long rowbase = (long)b * SEQ + c * CHUNK;
  const long bh8 = ((long)(b * NHEADS + h)) * NCHUNK + c;
  const float* acum = A_cum + bh8 * CHUNK;
  if (t < 256) { csL[t] = acum[t]; dtL[t] = dt_t[((size_t)(b * NHEADS + h)) * SEQ + c * CHUNK + t]; }
  float cs_last = acum[255];
  f32x4 acc[2][4];
#pragma unroll
  for (int i = 0; i < 2; ++i)
#pragma unroll
    for (int j = 0; j < 4; ++j) { f32x4 z = {0.f, 0.f, 0.f, 0.f}; acc[i][j] = z; }

  for (int lp = 0; lp < 4; ++lp) {
    __syncthreads();
    for (int i = t; i < 64 * 32; i += 256) {
      int l = i >> 5, n4 = (i & 31) * 4;
      ushort4 v = *(const ushort4*)(xbc + (rowbase + lp * 64 + l) * (long)CONV_DIM + D_INNER + n4);
      BT[n4 + 0][l] = v.x; BT[n4 + 1][l] = v.y; BT[n4 + 2][l] = v.z; BT[n4 + 3][l] = v.w;
    }
    for (int i = t; i < 64 * 16; i += 256) {
      int l = i >> 4, p4 = (i & 15) * 4;
      int lg = lp * 64 + l;
      float wgt = expf(cs_last - csL[lg]) * dtL[lg];
      ushort4 v = *(const ushort4*)(xbc + (rowbase + lg) * (long)CONV_DIM + h * HEADDIM + p4);
      WXT[p4 + 0][l] = f2bf(bf2f(v.x) * wgt);
      WXT[p4 + 1][l] = f2bf(bf2f(v.y) * wgt);
      WXT[p4 + 2][l] = f2bf(bf2f(v.z) * wgt);
      WXT[p4 + 3][l] = f2bf(bf2f(v.w) * wgt);
    }
    __syncthreads();
#pragma unroll
    for (int ks = 0; ks < 2; ++ks) {
      const int kofs = ks * 32 + g * 8;
      bf16x8 am[2], bp[4];
#pragma unroll
      for (int i = 0; i < 2; ++i) am[i] = *(const bf16x8*)&BT[w * 32 + i * 16 + (lane & 15)][kofs];
#pragma unroll
      for (int j = 0; j < 4; ++j) bp[j] = *(const bf16x8*)&WXT[j * 16 + (lane & 15)][kofs];
#pragma unroll
      for (int i = 0; i < 2; ++i)
#pragma unroll
        for (int j = 0; j < 4; ++j)
          acc[i][j] = __builtin_amdgcn_mfma_f32_16x16x32_bf16(am[i], bp[j], acc[i][j], 0, 0, 0);
    }
  }
  float* sp = states + ((long)bc * NHEADS + h) * (D_STATE * HEADDIM);
#pragma unroll
  for (int i = 0; i < 2; ++i)
#pragma unroll
    for (int j = 0; j < 4; ++j) {
      int n0 = w * 32 + i * 16 + g * 4;
      int p = j * 16 + (lane & 15);
#pragma unroll
      for (int r = 0; r < 4; ++r) sp[(long)(n0 + r) * HEADDIM + p] = acc[i][j][r];
    }
}

// ---------------- inter-chunk scan -> prev_states (bf16, [n][p]) ----------------
__global__ void k_scan(const float* __restrict__ states, const float* __restrict__ A_cum, unsigned short* __restrict__ psb) {
  long idx = (long)blockIdx.x * blockDim.x + threadIdx.x;
  if (idx >= (long)BATCH * NHEADS * D_STATE * HEADDIM) return;
  int p = idx & 63;
  int n = (int)((idx >> 6) & 127);
  long bh = idx >> 13;
  int h = (int)(bh & 63);
  int b = (int)(bh >> 6);
  float S = 0.f;
  for (int c = 0; c < NCHUNK; ++c) {
    long soff = (((long)(b * NCHUNK + c) * NHEADS + h) * (D_STATE * HEADDIM)) + (long)n * HEADDIM + p;
    psb[soff] = f2bf(S);
    float decay = expf(A_cum[(bh * NCHUNK + c) * CHUNK + 255]);
    S = S * decay + states[soff];
  }
}

// ---------------- Y = Y_diag + Y_off + x*D (bf16 out), MFMA ----------------
__global__ __launch_bounds__(256) void k_y(const unsigned short* __restrict__ xbc, const float* __restrict__ dt_t,
                                           const float* __restrict__ A_cum, const unsigned short* __restrict__ cbt_t,
                                           const unsigned short* __restrict__ psb, const float* __restrict__ Dp,
                                           unsigned short* __restrict__ y) {
  const int bid = blockIdx.x;
  const int h = bid & 63;
  const int bc = bid >> 6;
  const int b = bc >> 3, c = bc & 7;
  const int t = threadIdx.x;
  const int lane = t & 63;
  const int w = t >> 6;
  const int g = lane >> 4;
  __shared__ unsigned short Abuf[256][72];
  __shared__ unsigned short Bbuf[64][72];
  __shared__ float csL[256], dtL[256], expL[256];
  const long rowbase = (long)b * SEQ + c * CHUNK;
  const long bh8 = ((long)(b * NHEADS + h)) * NCHUNK + c;
  const float* acum = A_cum + bh8 * CHUNK;
  if (t < 256) {
    float cv = acum[t];
    csL[t] = cv;
    expL[t] = expf(cv);
    dtL[t] = dt_t[((size_t)(b * NHEADS + h)) * SEQ + c * CHUNK + t];
  }
  f32x4 acc[4][4];
#pragma unroll
  for (int i = 0; i < 4; ++i)
#pragma unroll
    for (int j = 0; j < 4; ++j) { f32x4 z = {0.f, 0.f, 0.f, 0.f}; acc[i][j] = z; }

  const unsigned short* psbase = psb + ((long)bc * NHEADS + h) * (D_STATE * HEADDIM);
  for (int np = 0; np < 2; ++np) {
    __syncthreads();
    for (int i = t; i < 256 * 16; i += 256) {
      int row = i >> 4, c4 = (i & 15) * 4;
      float el = expL[row];
      ushort4 v = *(const ushort4*)(xbc + (rowbase + row) * (long)CONV_DIM + D_INNER + D_STATE + np * 64 + c4);
      ushort4 o = make_ushort4(f2bf(bf2f(v.x) * el), f2bf(bf2f(v.y) * el), f2bf(bf2f(v.z) * el), f2bf(bf2f(v.w) * el));
      *(ushort4*)&Abuf[row][c4] = o;
    }
    for (int i = t; i < 64 * 16; i += 256) {
      int n = i >> 4, p4 = (i & 15) * 4;
      ushort4 v = *(const ushort4*)(psbase + (long)(np * 64 + n) * HEADDIM + p4);
      Bbuf[p4 + 0][n] = v.x; Bbuf[p4 + 1][n] = v.y; Bbuf[p4 + 2][n] = v.z; Bbuf[p4 + 3][n] = v.w;
    }
    __syncthreads();
#pragma unroll
    for (int ks = 0; ks < 2; ++ks) {
      const int kofs = ks * 32 + g * 8;
      bf16x8 af[4], bfr[4];
#pragma unroll
      for (int i = 0; i < 4; ++i) af[i] = *(const bf16x8*)&Abuf[w * 64 + i * 16 + (lane & 15)][kofs];
#pragma unroll
      for (int j = 0; j < 4; ++j) bfr[j] = *(const bf16x8*)&Bbuf[j * 16 + (lane & 15)][kofs];
#pragma unroll
      for (int i = 0; i < 4; ++i)
#pragma unroll
        for (int j = 0; j < 4; ++j)
          acc[i][j] = __builtin_amdgcn_mfma_f32_16x16x32_bf16(af[i], bfr[j], acc[i][j], 0, 0, 0);
    }
  }

  const unsigned short* cbtb = cbt_t + (long)bc * CHUNK * CHUNK;
  for (int sp = 0; sp < 4; ++sp) {
    __syncthreads();
    for (int i = t; i < 64 * 8; i += 256) {
      int s = i >> 3, p0 = (i & 7) * 8;
      u16x8 v = *(const u16x8*)(xbc + (rowbase + sp * 64 + s) * (long)CONV_DIM + h * HEADDIM + p0);
#pragma unroll
      for (int e = 0; e < 8; ++e) Bbuf[p0 + e][s] = v[e];
    }
    __syncthreads();
    if (sp > w) continue;
#pragma unroll
    for (int ks = 0; ks < 2; ++ks) {
      const int kofs = ks * 32 + g * 8;
      bf16x8 bfr[4];
#pragma unroll
      for (int j = 0; j < 4; ++j) bfr[j] = *(const bf16x8*)&Bbuf[j * 16 + (lane & 15)][kofs];
      const int sbase = sp * 64 + ks * 32 + g * 8;
#pragma unroll
      for (int i = 0; i < 4; ++i) {
        if (sp == w && ks * 32 > i * 16 + 15) continue;
        const int l = w * 64 + i * 16 + (lane & 15);
        u16x8 cv = *(const u16x8*)(cbtb + (long)l * CHUNK + sbase);
        const float cl = csL[l];
        bf16x8 af;
#pragma unroll
        for (int e = 0; e < 8; ++e) {
          int s = sbase + e;
          float val = (s <= l) ? bf2f(cv[e]) * expf(cl - csL[s]) * dtL[s] : 0.f;
          af[e] = (short)f2bf(val);
        }
#pragma unroll
        for (int j = 0; j < 4; ++j)
          acc[i][j] = __builtin_amdgcn_mfma_f32_16x16x32_bf16(af, bfr[j], acc[i][j], 0, 0, 0);
      }
    }
  }

  const float Dh = Dp[h];
#pragma unroll
  for (int i = 0; i < 4; ++i) {
    int l0 = w * 64 + i * 16 + g * 4;
#pragma unroll
    for (int r = 0; r < 4; ++r) {
      long grow = rowbase + l0 + r;
      const unsigned short* xrow = xbc + grow * (long)CONV_DIM + h * HEADDIM;
      unsigned short* yrow = y + grow * (long)D_INNER + h * HEADDIM;
#pragma unroll
      for (int j = 0; j < 4; ++j) {
        int p = j * 16 + (lane & 15);
        yrow[p] = f2bf(acc[i][j][r] + bf2f(xrow[p]) * Dh);
      }
    }
  }
}

// ---------------- gated RMSNorm ----------------
__global__ __launch_bounds__(256) void k_norm(unsigned short* yz, const unsigned short* __restrict__ zb,
                                              const float* __restrict__ norm_w, unsigned short* out) {
  const int row = blockIdx.x;
  const int t = threadIdx.x;
  const unsigned short* yr = yz + (size_t)row * D_INNER;
  const unsigned short* zr = zb + (size_t)row * D_INNER;
  float yv[16];
  float ss = 0.f;
#pragma unroll
  for (int j = 0; j < 4; ++j) {
    int e = (t + j * 256) * 4;
    ushort4 yy = *(const ushort4*)(yr + e);
    ushort4 zz = *(const ushort4*)(zr + e);
    float z0 = bf2f(zz.x), z1 = bf2f(zz.y), z2 = bf2f(zz.z), z3 = bf2f(zz.w);
    float g0 = bf2f(yy.x) * z0 / (1.f + expf(-z0));
    float g1 = bf2f(yy.y) * z1 / (1.f + expf(-z1));
    float g2 = bf2f(yy.z) * z2 / (1.f + expf(-z2));
    float g3 = bf2f(yy.w) * z3 / (1.f + expf(-z3));
    ss += g0 * g0 + g1 * g1 + g2 * g2 + g3 * g3;
    yv[j * 4 + 0] = g0; yv[j * 4 + 1] = g1; yv[j * 4 + 2] = g2; yv[j * 4 + 3] = g3;
  }
#pragma unroll
  for (int off = 32; off > 0; off >>= 1) ss += __shfl_xor(ss, off);
  __shared__ float red[4];
  if ((t & 63) == 0) red[t >> 6] = ss;
  __syncthreads();
  float tot = red[0] + red[1] + red[2] + red[3];
  float scale = rsqrtf(tot / (float)D_INNER + EPSV);
  unsigned short* orow = out + (size_t)row * D_INNER;
#pragma unroll
  for (int j = 0; j < 4; ++j) {
    int e = (t + j * 256) * 4;
    float4 w = *(const float4*)(norm_w + e);
    ushort4 o = make_ushort4(f2bf(yv[j * 4 + 0] * scale * w.x), f2bf(yv[j * 4 + 1] * scale * w.y),
                             f2bf(yv[j * 4 + 2] * scale * w.z), f2bf(yv[j * 4 + 3] * scale * w.w));
    *(ushort4*)(orow + e) = o;
  }
}

extern "C" void kernel_launch(void* const* d_in, const int* in_sizes, int n_in,
                              void* d_out, int out_size, void* d_ws, size_t ws_size,
                              hipStream_t stream) {
  const float* u       = (const float*)d_in[0];
  const float* W_in    = (const float*)d_in[1];
  const float* conv_w  = (const float*)d_in[2];
  const float* conv_b  = (const float*)d_in[3];
  const float* dt_bias = (const float*)d_in[4];
  const float* A_log   = (const float*)d_in[5];
  const float* Dp      = (const float*)d_in[6];
  const float* norm_w  = (const float*)d_in[7];
  const float* W_out   = (const float*)d_in[8];
  float* out = (float*)d_out;

  char* ws = (char*)d_ws;
  size_t off = 0;
  auto alloc = [&](size_t bytes) { char* p = ws + off; off += (bytes + 255) & ~(size_t)255; return p; };
  unsigned short* ub   = (unsigned short*)alloc((size_t)NROWS * D_MODEL * 2);
  unsigned short* winb = (unsigned short*)alloc((size_t)D_IN_PROJ * D_MODEL * 2);
  unsigned short* zb   = (unsigned short*)alloc((size_t)NROWS * D_INNER * 2);
  unsigned short* xb   = (unsigned short*)alloc((size_t)NROWS * CONV_DIM * 2);
  unsigned short* xbcb = (unsigned short*)alloc((size_t)NROWS * CONV_DIM * 2);
  float* dtt  = (float*)alloc((size_t)BATCH * NHEADS * SEQ * 4);
  float* acum = (float*)alloc((size_t)BATCH * NHEADS * NCHUNK * CHUNK * 4);
  unsigned short* cwT = (unsigned short*)alloc((size_t)4 * CONV_DIM * 2);
  unsigned short* cbT = (unsigned short*)alloc((size_t)CONV_DIM * 2);
  unsigned short* wob = ub;
  unsigned short* cbt = winb;
  unsigned short* psb = winb + (size_t)BATCH * NCHUNK * CHUNK * CHUNK + 1024;
  unsigned short* yb = xb;
  float* states = (float*)d_out;

  if (off > ws_size) {
    k_sentinel<<<1, 64, 0, stream>>>(out);
    return;
  }

  k_f32_to_bf16_v4<<<2048, 256, 0, stream>>>(u, ub, (long)NROWS * D_MODEL / 4);
  k_f32_to_bf16_v4<<<2048, 256, 0, stream>>>(W_in, winb, (long)D_IN_PROJ * D_MODEL / 4);
  k_conv_pack<<<(CONV_DIM + 255) / 256, 256, 0, stream>>>(conv_w, conv_b, cwT, cbT);
  k_gemm8p<<<(NROWS / 256) * (D_INNER / 256), 512, 0, stream>>>(ub, winb, zb, NROWS, D_INNER, D_MODEL);
  k_gemm128<1><<<(NROWS / 128) * (CONV_DIM / 128), 256, 0, stream>>>(ub, winb + (size_t)D_INNER * D_MODEL, xb, NROWS, CONV_DIM, D_MODEL);
  k_dt<<<NROWS / 16, 256, 0, stream>>>(u, W_in, dt_bias, dtt);
  k_conv_silu<<<(int)(((long)(NROWS / 4) * CG + 255) / 256), 256, 0, stream>>>(xb, cwT, cbT, xbcb);
  k_cumsum<<<BATCH * NHEADS * NCHUNK, 256, 0, stream>>>(dtt, A_log, acum);
  k_cbtt<<<BATCH * NCHUNK * 4, 256, 0, stream>>>(xbcb, cbt);
  k_states<<<BATCH * NCHUNK * NHEADS, 256, 0, stream>>>(xbcb, dtt, acum, states);
  k_scan<<<(BATCH * NHEADS * D_STATE * HEADDIM + 255) / 256, 256, 0, stream>>>(states, acum, psb);
  k_y<<<BATCH * NCHUNK * NHEADS, 256, 0, stream>>>(xbcb, dtt, acum, cbt, psb, Dp, yb);
  k_norm<<<NROWS, 256, 0, stream>>>(yb, zb, norm_w, yb);
  k_f32_to_bf16_v4<<<2048, 256, 0, stream>>>(W_out, wob, (long)D_MODEL * D_INNER / 4);
  k_gemm128<0><<<(NROWS / 128) * (D_MODEL / 128), 256, 0, stream>>>(yb, wob, out, NROWS, D_MODEL, D_INNER);
}

// Round 8
// 506.994 us; speedup vs baseline: 2.1636x; 1.1145x over previous
//
#include <hip/hip_runtime.h>

#define D_MODEL   2048
#define D_INNER   4096
#define HEADDIM   64
#define NHEADS    64
#define D_STATE   128
#define CHUNK     256
#define CONV_DIM  4352
#define D_IN_PROJ 8512
#define BATCH     2
#define SEQ       2048
#define NCHUNK    8
#define NROWS     4096
#define EPSV      1e-5f
#define CG        (CONV_DIM / 8)   // 544

typedef __attribute__((ext_vector_type(8))) short bf16x8;
typedef __attribute__((ext_vector_type(8))) unsigned short u16x8;
typedef __attribute__((ext_vector_type(4))) float f32x4;

#define AS1 __attribute__((address_space(1)))
#define AS3 __attribute__((address_space(3)))

#define BAR() do { asm volatile("" ::: "memory"); __builtin_amdgcn_s_barrier(); asm volatile("" ::: "memory"); } while (0)

__device__ __forceinline__ unsigned short f2bf(float f) {
  unsigned int x = __float_as_uint(f);
  unsigned int r = (x + 0x7fffu + ((x >> 16) & 1u)) >> 16;
  return (unsigned short)r;
}
__device__ __forceinline__ float bf2f(unsigned short u) {
  return __uint_as_float((unsigned int)u << 16);
}

__global__ void k_sentinel(float* out) { if (threadIdx.x == 0) out[0] = 1.0e6f; }

// ---------------- converts ----------------
__global__ void k_f32_to_bf16_v4(const float* __restrict__ in, unsigned short* __restrict__ out, long n4) {
  long i = (long)blockIdx.x * blockDim.x + threadIdx.x;
  long stride = (long)gridDim.x * blockDim.x;
  for (; i < n4; i += stride) {
    float4 v = ((const float4*)in)[i];
    ushort4 o = make_ushort4(f2bf(v.x), f2bf(v.y), f2bf(v.z), f2bf(v.w));
    ((ushort4*)out)[i] = o;
  }
}

// u -> bf16 hi + bf16 residual lo (one pass)
__global__ void k_usplit(const float* __restrict__ in, unsigned short* __restrict__ hi,
                         unsigned short* __restrict__ lo, long n4) {
  long i = (long)blockIdx.x * blockDim.x + threadIdx.x;
  long stride = (long)gridDim.x * blockDim.x;
  for (; i < n4; i += stride) {
    float4 v = ((const float4*)in)[i];
    ushort4 h, l;
    h.x = f2bf(v.x); l.x = f2bf(v.x - bf2f(h.x));
    h.y = f2bf(v.y); l.y = f2bf(v.y - bf2f(h.y));
    h.z = f2bf(v.z); l.z = f2bf(v.z - bf2f(h.z));
    h.w = f2bf(v.w); l.w = f2bf(v.w - bf2f(h.w));
    ((ushort4*)hi)[i] = h;
    ((ushort4*)lo)[i] = l;
  }
}

// W_in dt rows (8448..8511) -> whl[0:64]=bf16 hi, whl[64:128]=bf16 residual
__global__ void k_wpack(const float* __restrict__ W, unsigned short* __restrict__ whl) {
  long i = (long)blockIdx.x * blockDim.x + threadIdx.x;
  if (i >= (long)64 * D_MODEL) return;
  float v = W[(size_t)8448 * D_MODEL + i];
  unsigned short h = f2bf(v);
  whl[i] = h;
  whl[(size_t)64 * D_MODEL + i] = f2bf(v - bf2f(h));
}

// ---- dt via split-bf16 MFMA: dt_raw = uhi@[Whi;Wlo]^T (+) ulo@Whi^T, softplus, transpose-store ----
// 64 rows/block, 4 waves (16 rows each), K=2048, BK=64. Same staging pattern as k_gemm128.
__global__ __launch_bounds__(256, 2) void k_dtm(const unsigned short* __restrict__ uhi,
                                                const unsigned short* __restrict__ ulo,
                                                const unsigned short* __restrict__ whl,
                                                const float* __restrict__ dt_bias,
                                                float* __restrict__ dt_t) {
  __shared__ __align__(16) short lds[2][256 * 64];   // rows 0-63 uhi, 64-127 ulo, 128-255 [Whi;Wlo]
  const int t = threadIdx.x;
  const int lane = t & 63;
  const int w = t >> 6;
  const int m0 = (int)blockIdx.x * 64;

  f32x4 acc1[8], acc2[4];
#pragma unroll
  for (int j = 0; j < 8; ++j) { f32x4 z = {0.f, 0.f, 0.f, 0.f}; acc1[j] = z; }
#pragma unroll
  for (int j = 0; j < 4; ++j) { f32x4 z = {0.f, 0.f, 0.f, 0.f}; acc2[j] = z; }

  const int srow = t >> 3;                 // 0..31
  const int schunk = (t & 7) ^ (srow & 7); // T2 inverse pre-swizzle
  const unsigned short* gU = uhi + (size_t)(m0 + srow) * D_MODEL + schunk * 8;
  const unsigned short* gL = ulo + (size_t)(m0 + srow) * D_MODEL + schunk * 8;
  const unsigned short* gW = whl + (size_t)srow * D_MODEL + schunk * 8;

  auto STAGE = [&](int buf, int kt) {      // 8 global_load_lds per thread
    char* d = (char*)&lds[buf][0] + t * 16;
#pragma unroll
    for (int ii = 0; ii < 2; ++ii)
      __builtin_amdgcn_global_load_lds((const AS1 void*)(gU + (size_t)ii * 32 * D_MODEL + (size_t)kt * 64),
                                       (AS3 void*)(d + ii * 4096), 16, 0, 0);
#pragma unroll
    for (int ii = 0; ii < 2; ++ii)
      __builtin_amdgcn_global_load_lds((const AS1 void*)(gL + (size_t)ii * 32 * D_MODEL + (size_t)kt * 64),
                                       (AS3 void*)(d + 8192 + ii * 4096), 16, 0, 0);
#pragma unroll
    for (int ii = 0; ii < 4; ++ii)
      __builtin_amdgcn_global_load_lds((const AS1 void*)(gW + (size_t)ii * 32 * D_MODEL + (size_t)kt * 64),
                                       (AS3 void*)(d + 16384 + ii * 4096), 16, 0, 0);
  };

  STAGE(0, 0);

  const int NT = D_MODEL / 64;
  const int ar = w * 16 + (lane & 15);
  const int kof = (lane >> 4) * 8;
  const int rsw = (lane & 7) * 8;
  int cur = 0;
  for (int kt = 0; kt < NT; ++kt) {
    if (kt + 1 < NT) {
      STAGE(cur ^ 1, kt + 1);
      asm volatile("s_waitcnt vmcnt(8)" ::: "memory");
    } else {
      asm volatile("s_waitcnt vmcnt(0)" ::: "memory");
    }
    __builtin_amdgcn_s_barrier();
    asm volatile("" ::: "memory");
    const short* L = &lds[cur][0];
#pragma unroll
    for (int kk = 0; kk < 2; ++kk) {
      const int off = (kk * 32 + kof) ^ rsw;
      bf16x8 ah = *(const bf16x8*)(L + ar * 64 + off);
      bf16x8 al = *(const bf16x8*)(L + (64 + ar) * 64 + off);
#pragma unroll
      for (int j = 0; j < 8; ++j) {
        bf16x8 bj = *(const bf16x8*)(L + (128 + j * 16 + (lane & 15)) * 64 + off);
        acc1[j] = __builtin_amdgcn_mfma_f32_16x16x32_bf16(ah, bj, acc1[j], 0, 0, 0);
        if (j < 4) acc2[j] = __builtin_amdgcn_mfma_f32_16x16x32_bf16(al, bj, acc2[j], 0, 0, 0);
      }
    }
    asm volatile("" ::: "memory");
    __builtin_amdgcn_s_barrier();
    asm volatile("" ::: "memory");
    cur ^= 1;
  }

  const int crow = (lane >> 4) * 4;
#pragma unroll
  for (int j = 0; j < 4; ++j) {
    int h = j * 16 + (lane & 15);
    float bias = dt_bias[h];
#pragma unroll
    for (int r = 0; r < 4; ++r) {
      int row = m0 + w * 16 + crow + r;
      float v = acc1[j][r] + acc1[j + 4][r] + acc2[j][r] + bias;
      float dtv = (v > 20.f) ? v : log1pf(expf(v));
      dt_t[(size_t)((row >> 11) * NHEADS + h) * SEQ + (row & 2047)] = dtv;
    }
  }
}

// ---- 256x256 BK=64 8-phase GEMM (T2+T3+T4+T5), 512 thr, 8 waves (2Mx4N), grid%8==0 ----
__global__ __launch_bounds__(512, 2) void k_gemm8p(const unsigned short* __restrict__ A,
                                                   const unsigned short* __restrict__ B,
                                                   unsigned short* __restrict__ C, int M, int N, int K) {
  __shared__ __align__(16) short lds[2][32768];
  const int t = threadIdx.x;
  const int lane = t & 63;
  const int wid = t >> 6;
  const int wr = wid >> 2;
  const int wc = wid & 3;
  const int ntx = N / 256;
  const int nwg = (int)gridDim.x;
  const int bid = (int)blockIdx.x;
  const int swzb = (bid & 7) * (nwg >> 3) + (bid >> 3);
  const int m0 = (swzb / ntx) * 256;
  const int n0 = (swzb % ntx) * 256;

  f32x4 acc[8][4];
#pragma unroll
  for (int i = 0; i < 8; ++i)
#pragma unroll
    for (int j = 0; j < 4; ++j) { f32x4 z = {0.f, 0.f, 0.f, 0.f}; acc[i][j] = z; }

  const int srow = t >> 3;
  const int schunk = (t & 7) ^ (srow & 7);
  const unsigned short* gA = A + (size_t)(m0 + srow) * K + schunk * 8;
  const unsigned short* gB = B + (size_t)(n0 + srow) * K + schunk * 8;

  auto STAGE_HALF = [&](int buf, int kt, int which) {
    const unsigned short* g = (which < 2 ? gA : gB) + (size_t)(which & 1) * 128 * K + (size_t)kt * 64;
    char* d = (char*)lds + buf * 65536 + which * 16384 + t * 16;
    __builtin_amdgcn_global_load_lds((const AS1 void*)g, (AS3 void*)d, 16, 0, 0);
    __builtin_amdgcn_global_load_lds((const AS1 void*)(g + (size_t)64 * K), (AS3 void*)(d + 8192), 16, 0, 0);
  };

  const int NT = K / 64;
  STAGE_HALF(0, 0, 0); STAGE_HALF(0, 0, 1); STAGE_HALF(0, 0, 2); STAGE_HALF(0, 0, 3);
  STAGE_HALF(1, 1, 2); STAGE_HALF(1, 1, 0); STAGE_HALF(1, 1, 1);
  asm volatile("s_waitcnt vmcnt(6)" ::: "memory");
  BAR();

  const int ar = wr * 128 + (lane & 15);
  const int br = wc * 64 + (lane & 15);
  const int kof = (lane >> 4) * 8;
  const int rsw = (lane & 7) * 8;

  for (int kt = 0; kt < NT; ++kt) {
    const int buf = kt & 1;
    const short* As = &lds[buf][0];
    const short* Bs = &lds[buf][16384];
    const bool s1 = (kt + 1 < NT);
    const bool s2 = (kt + 2 < NT);
    bf16x8 aLo[4][2], aHi[4][2], bLo[2][2], bHi[2][2];

#pragma unroll
    for (int i = 0; i < 4; ++i)
#pragma unroll
      for (int k = 0; k < 2; ++k) aLo[i][k] = *(const bf16x8*)(As + (ar + i * 16) * 64 + ((k * 32 + kof) ^ rsw));
#pragma unroll
    for (int j = 0; j < 2; ++j)
#pragma unroll
      for (int k = 0; k < 2; ++k) bLo[j][k] = *(const bf16x8*)(Bs + (br + j * 16) * 64 + ((k * 32 + kof) ^ rsw));
    if (s1) STAGE_HALF(buf ^ 1, kt + 1, 3);
    BAR();
    __builtin_amdgcn_s_setprio(1);
#pragma unroll
    for (int k = 0; k < 2; ++k)
#pragma unroll
      for (int i = 0; i < 4; ++i)
#pragma unroll
        for (int j = 0; j < 2; ++j)
          acc[i][j] = __builtin_amdgcn_mfma_f32_16x16x32_bf16(aLo[i][k], bLo[j][k], acc[i][j], 0, 0, 0);
    __builtin_amdgcn_s_setprio(0);
    BAR();

#pragma unroll
    for (int j = 0; j < 2; ++j)
#pragma unroll
      for (int k = 0; k < 2; ++k) bHi[j][k] = *(const bf16x8*)(Bs + (br + (j + 2) * 16) * 64 + ((k * 32 + kof) ^ rsw));
    BAR();
    __builtin_amdgcn_s_setprio(1);
#pragma unroll
    for (int k = 0; k < 2; ++k)
#pragma unroll
      for (int i = 0; i < 4; ++i)
#pragma unroll
        for (int j = 0; j < 2; ++j)
          acc[i][j + 2] = __builtin_amdgcn_mfma_f32_16x16x32_bf16(aLo[i][k], bHi[j][k], acc[i][j + 2], 0, 0, 0);
    __builtin_amdgcn_s_setprio(0);
    BAR();

#pragma unroll
    for (int i = 0; i < 4; ++i)
#pragma unroll
      for (int k = 0; k < 2; ++k) aHi[i][k] = *(const bf16x8*)(As + (ar + (i + 4) * 16) * 64 + ((k * 32 + kof) ^ rsw));
    if (s2) STAGE_HALF(buf, kt + 2, 2);
    BAR();
    __builtin_amdgcn_s_setprio(1);
#pragma unroll
    for (int k = 0; k < 2; ++k)
#pragma unroll
      for (int i = 0; i < 4; ++i)
#pragma unroll
        for (int j = 0; j < 2; ++j)
          acc[i + 4][j] = __builtin_amdgcn_mfma_f32_16x16x32_bf16(aHi[i][k], bLo[j][k], acc[i + 4][j], 0, 0, 0);
    __builtin_amdgcn_s_setprio(0);
    BAR();

    if (s2) { STAGE_HALF(buf, kt + 2, 0); STAGE_HALF(buf, kt + 2, 1); }
    if (s2) { asm volatile("s_waitcnt vmcnt(6)" ::: "memory"); }
    else    { asm volatile("s_waitcnt vmcnt(0)" ::: "memory"); }
    BAR();
    __builtin_amdgcn_s_setprio(1);
#pragma unroll
    for (int k = 0; k < 2; ++k)
#pragma unroll
      for (int i = 0; i < 4; ++i)
#pragma unroll
        for (int j = 0; j < 2; ++j)
          acc[i + 4][j + 2] = __builtin_amdgcn_mfma_f32_16x16x32_bf16(aHi[i][k], bHi[j][k], acc[i + 4][j + 2], 0, 0, 0);
    __builtin_amdgcn_s_setprio(0);
    BAR();
  }

  const int crow = (lane >> 4) * 4;
  const int ccol = lane & 15;
#pragma unroll
  for (int i = 0; i < 8; ++i)
#pragma unroll
    for (int j = 0; j < 4; ++j) {
      size_t base = (size_t)(m0 + wr * 128 + i * 16 + crow) * N + (n0 + wc * 64 + j * 16 + ccol);
#pragma unroll
      for (int r = 0; r < 4; ++r) C[base + (size_t)r * N] = f2bf(acc[i][j][r]);
    }
}

// ---- 128x128 BK=64 double-buffered GEMM ----
template <int BF16OUT>
__global__ __launch_bounds__(256, 2) void k_gemm128(const unsigned short* __restrict__ A,
                                                    const unsigned short* __restrict__ B,
                                                    void* __restrict__ Cv, int M, int N, int K) {
  constexpr int BK = 64;
  __shared__ __align__(16) short lds[2][256 * BK];
  const int t = threadIdx.x;
  const int lane = t & 63;
  const int wid = t >> 6;
  const int wr = wid >> 1;
  const int wc = wid & 1;
  const int ntx = N / 128;
  const int nwg = (int)gridDim.x;
  const int bid = (int)blockIdx.x;
  const int swzb = (bid & 7) * (nwg >> 3) + (bid >> 3);
  const int m0 = (swzb / ntx) * 128;
  const int n0 = (swzb % ntx) * 128;

  f32x4 acc[4][4];
#pragma unroll
  for (int i = 0; i < 4; ++i)
#pragma unroll
    for (int j = 0; j < 4; ++j) { f32x4 z = {0.f, 0.f, 0.f, 0.f}; acc[i][j] = z; }

  const int srow = t >> 3;
  const int schunk = (t & 7) ^ (srow & 7);
  const unsigned short* gA = A + (size_t)(m0 + srow) * K + schunk * 8;
  const unsigned short* gB = B + (size_t)(n0 + srow) * K + schunk * 8;

  auto STAGE = [&](int buf, int kt) {
    char* dA = (char*)&lds[buf][0] + t * 16;
    char* dB = (char*)&lds[buf][128 * BK] + t * 16;
#pragma unroll
    for (int ii = 0; ii < 4; ++ii)
      __builtin_amdgcn_global_load_lds((const AS1 void*)(gA + (size_t)ii * 32 * K + kt * BK),
                                       (AS3 void*)(dA + ii * 4096), 16, 0, 0);
#pragma unroll
    for (int ii = 0; ii < 4; ++ii)
      __builtin_amdgcn_global_load_lds((const AS1 void*)(gB + (size_t)ii * 32 * K + kt * BK),
                                       (AS3 void*)(dB + ii * 4096), 16, 0, 0);
  };

  STAGE(0, 0);

  const int NT = K / BK;
  const int ar = wr * 64 + (lane & 15);
  const int br = wc * 64 + (lane & 15);
  const int kof = (lane >> 4) * 8;
  const int rsw = (lane & 7) * 8;
  int cur = 0;
  for (int kt = 0; kt < NT; ++kt) {
    if (kt + 1 < NT) {
      STAGE(cur ^ 1, kt + 1);
      asm volatile("s_waitcnt vmcnt(8)" ::: "memory");
    } else {
      asm volatile("s_waitcnt vmcnt(0)" ::: "memory");
    }
    __builtin_amdgcn_s_barrier();
    asm volatile("" ::: "memory");
    const short* As = &lds[cur][0];
    const short* Bs = &lds[cur][128 * BK];
#pragma unroll
    for (int kk = 0; kk < 2; ++kk) {
      bf16x8 bfr[4];
#pragma unroll
      for (int j = 0; j < 4; ++j)
        bfr[j] = *(const bf16x8*)(Bs + (br + j * 16) * BK + ((kk * 32 + kof) ^ rsw));
#pragma unroll
      for (int i = 0; i < 4; ++i) {
        bf16x8 af = *(const bf16x8*)(As + (ar + i * 16) * BK + ((kk * 32 + kof) ^ rsw));
#pragma unroll
        for (int j = 0; j < 4; ++j)
          acc[i][j] = __builtin_amdgcn_mfma_f32_16x16x32_bf16(af, bfr[j], acc[i][j], 0, 0, 0);
      }
    }
    asm volatile("" ::: "memory");
    __builtin_amdgcn_s_barrier();
    asm volatile("" ::: "memory");
    cur ^= 1;
  }

  const int crow = (lane >> 4) * 4;
  const int ccol = lane & 15;
#pragma unroll
  for (int i = 0; i < 4; ++i)
#pragma unroll
    for (int j = 0; j < 4; ++j) {
      size_t base = (size_t)(m0 + wr * 64 + i * 16 + crow) * N + (n0 + wc * 64 + j * 16 + ccol);
      if (BF16OUT) {
        unsigned short* C = (unsigned short*)Cv;
#pragma unroll
        for (int r = 0; r < 4; ++r) C[base + (size_t)r * N] = f2bf(acc[i][j][r]);
      } else {
        float* C = (float*)Cv;
#pragma unroll
        for (int r = 0; r < 4; ++r) C[base + (size_t)r * N] = acc[i][j][r];
      }
    }
}

// ---------------- conv weight/bias pack ----------------
__global__ void k_conv_pack(const float* __restrict__ cw, const float* __restrict__ cb,
                            unsigned short* __restrict__ wT, unsigned short* __restrict__ bT) {
  int i = blockIdx.x * blockDim.x + threadIdx.x;
  if (i < CONV_DIM) {
#pragma unroll
    for (int w = 0; w < 4; ++w) wT[w * CONV_DIM + i] = f2bf(cw[i * 4 + w]);
    bT[i] = f2bf(cb[i]);
  }
}

// ---------------- conv1d + silu ----------------
__global__ __launch_bounds__(256) void k_conv_silu(const unsigned short* __restrict__ xb,
                                                   const unsigned short* __restrict__ wT,
                                                   const unsigned short* __restrict__ bT,
                                                   unsigned short* __restrict__ out) {
  long idx = (long)blockIdx.x * blockDim.x + threadIdx.x;
  if (idx >= (long)(NROWS / 4) * CG) return;
  int c8 = (int)(idx % CG);
  long rq = idx / CG;
  int l0 = (int)((rq & (SEQ / 4 - 1)) * 4);
  long brow = (rq >> 9) * (long)SEQ;
  int ch0 = c8 * 8;

  u16x8 wv[4];
#pragma unroll
  for (int w = 0; w < 4; ++w) wv[w] = *(const u16x8*)(wT + w * CONV_DIM + ch0);
  u16x8 bv = *(const u16x8*)(bT + ch0);

  u16x8 xr[7];
#pragma unroll
  for (int i = 0; i < 7; ++i) {
    int ls = l0 - 3 + i;
    if (ls >= 0) xr[i] = *(const u16x8*)(xb + (brow + ls) * (long)CONV_DIM + ch0);
    else { u16x8 z = {0, 0, 0, 0, 0, 0, 0, 0}; xr[i] = z; }
  }

#pragma unroll
  for (int r = 0; r < 4; ++r) {
    float acc[8];
#pragma unroll
    for (int e = 0; e < 8; ++e) acc[e] = bf2f(bv[e]);
#pragma unroll
    for (int w = 0; w < 4; ++w)
#pragma unroll
      for (int e = 0; e < 8; ++e) acc[e] += bf2f(xr[r + w][e]) * bf2f(wv[w][e]);
    u16x8 o;
#pragma unroll
    for (int e = 0; e < 8; ++e) o[e] = f2bf(acc[e] / (1.f + expf(-acc[e])));
    *(u16x8*)(out + (brow + l0 + r) * (long)CONV_DIM + ch0) = o;
  }
}

// ---------------- per-chunk cumsum of dA ----------------
__global__ __launch_bounds__(256) void k_cumsum(const float* __restrict__ dt_t, const float* __restrict__ A_log,
                                                float* __restrict__ A_cum) {
  const int bid = blockIdx.x;
  const int c = bid & 7;
  const int bh = bid >> 3;
  const int h = bh & 63;
  const int l = threadIdx.x;
  float A = -expf(A_log[h]);
  __shared__ float s[256];
  s[l] = dt_t[(size_t)bh * SEQ + c * CHUNK + l] * A;
  __syncthreads();
  for (int off = 1; off < 256; off <<= 1) {
    float x = (l >= off) ? s[l - off] : 0.f;
    __syncthreads();
    s[l] += x;
    __syncthreads();
  }
  A_cum[(size_t)bid * CHUNK + l] = s[l];
}

// ---------------- CBT^T[l][s] = C_l . B_s  (bf16 out), MFMA ----------------
__global__ __launch_bounds__(256) void k_cbtt(const unsigned short* __restrict__ xbc, unsigned short* __restrict__ cbt_t) {
  const int bid = blockIdx.x;
  const int sp = bid & 3;
  const int bc = bid >> 2;
  const int b = bc >> 3, c = bc & 7;
  const int t = threadIdx.x;
  const int lane = t & 63;
  const int w = t >> 6;
  const int g = lane >> 4;
  __shared__ unsigned short Cs[256][72];
  __shared__ unsigned short Bs2[64][72];
  const long rowbase = (long)b * SEQ + c * CHUNK;
  f32x4 acc[4][4];
#pragma unroll
  for (int i = 0; i < 4; ++i)
#pragma unroll
    for (int j = 0; j < 4; ++j) { f32x4 z = {0.f, 0.f, 0.f, 0.f}; acc[i][j] = z; }

  for (int np = 0; np < 2; ++np) {
    __syncthreads();
    for (int i = t; i < 256 * 16; i += 256) {
      int row = i >> 4, c4 = (i & 15) * 4;
      ushort4 v = *(const ushort4*)(xbc + (rowbase + row) * (long)CONV_DIM + D_INNER + D_STATE + np * 64 + c4);
      *(ushort4*)&Cs[row][c4] = v;
    }
    for (int i = t; i < 64 * 16; i += 256) {
      int row = i >> 4, c4 = (i & 15) * 4;
      ushort4 v = *(const ushort4*)(xbc + (rowbase + sp * 64 + row) * (long)CONV_DIM + D_INNER + np * 64 + c4);
      *(ushort4*)&Bs2[row][c4] = v;
    }
    __syncthreads();
#pragma unroll
    for (int ks = 0; ks < 2; ++ks) {
      const int kofs = ks * 32 + g * 8;
      bf16x8 af[4], bfr[4];
#pragma unroll
      for (int i = 0; i < 4; ++i) af[i] = *(const bf16x8*)&Cs[w * 64 + i * 16 + (lane & 15)][kofs];
#pragma unroll
      for (int j = 0; j < 4; ++j) bfr[j] = *(const bf16x8*)&Bs2[j * 16 + (lane & 15)][kofs];
#pragma unroll
      for (int i = 0; i < 4; ++i)
#pragma unroll
        for (int j = 0; j < 4; ++j)
          acc[i][j] = __builtin_amdgcn_mfma_f32_16x16x32_bf16(af[i], bfr[j], acc[i][j], 0, 0, 0);
    }
  }
  unsigned short* ob = cbt_t + (long)bc * CHUNK * CHUNK;
#pragma unroll
  for (int i = 0; i < 4; ++i)
#pragma unroll
    for (int j = 0; j < 4; ++j) {
      int l0 = w * 64 + i * 16 + g * 4;
      int s = sp * 64 + j * 16 + (lane & 15);
#pragma unroll
      for (int r = 0; r < 4; ++r) ob[(long)(l0 + r) * CHUNK + s] = f2bf(acc[i][j][r]);
    }
}

// ---------------- states[n][p] = sum_l B[l][n]*w_l*x[l][p], MFMA ----------------
__global__ __launch_bounds__(256) void k_states(const unsigned short* __restrict__ xbc, const float* __restrict__ dt_t,
                                                const float* __restrict__ A_cum, float* __restrict__ states) {
  const int bid = blockIdx.x;
  const int h = bid & 63;
  const int bc = bid >> 6;
  const int b = bc >> 3, c = bc & 7;
  const int t = threadIdx.x;
  const int lane = t & 63;
  const int w = t >> 6;
  const int g = lane >> 4;
  __shared__ unsigned short BT[128][72];
  __shared__ unsigned short WXT[64][72];
  __shared__ float csL[256], dtL[256];
  const long rowbase = (long)b * SEQ + c * CHUNK;
  const long bh8 = ((long)(b * NHEADS + h)) * NCHUNK + c;
  const float* acum = A_cum + bh8 * CHUNK;
  if (t < 256) { csL[t] = acum[t]; dtL[t] = dt_t[((size_t)(b * NHEADS + h)) * SEQ + c * CHUNK + t]; }
  float cs_last = acum[255];
  f32x4 acc[2][4];
#pragma unroll
  for (int i = 0; i < 2; ++i)
#pragma unroll
    for (int j = 0; j < 4; ++j) { f32x4 z = {0.f, 0.f, 0.f, 0.f}; acc[i][j] = z; }

  for (int lp = 0; lp < 4; ++lp) {
    __syncthreads();
    for (int i = t; i < 64 * 32; i += 256) {
      int l = i >> 5, n4 = (i & 31) * 4;
      ushort4 v = *(const ushort4*)(xbc + (rowbase + lp * 64 + l) * (long)CONV_DIM + D_INNER + n4);
      BT[n4 + 0][l] = v.x; BT[n4 + 1][l] = v.y; BT[n4 + 2][l] = v.z; BT[n4 + 3][l] = v.w;
    }
    for (int i = t; i < 64 * 16; i += 256) {
      int l = i >> 4, p4 = (i & 15) * 4;
      int lg = lp * 64 + l;
      float wgt = expf(cs_last - csL[lg]) * dtL[lg];
      ushort4 v = *(const ushort4*)(xbc + (rowbase + lg) * (long)CONV_DIM + h * HEADDIM + p4);
      WXT[p4 + 0][l] = f2bf(bf2f(v.x) * wgt);
      WXT[p4 + 1][l] = f2bf(bf2f(v.y) * wgt);
      WXT[p4 + 2][l] = f2bf(bf2f(v.z) * wgt);
      WXT[p4 + 3][l] = f2bf(bf2f(v.w) * wgt);
    }
    __syncthreads();
#pragma unroll
    for (int ks = 0; ks < 2; ++ks) {
      const int kofs = ks * 32 + g * 8;
      bf16x8 am[2], bp[4];
#pragma unroll
      for (int i = 0; i < 2; ++i) am[i] = *(const bf16x8*)&BT[w * 32 + i * 16 + (lane & 15)][kofs];
#pragma unroll
      for (int j = 0; j < 4; ++j) bp[j] = *(const bf16x8*)&WXT[j * 16 + (lane & 15)][kofs];
#pragma unroll
      for (int i = 0; i < 2; ++i)
#pragma unroll
        for (int j = 0; j < 4; ++j)
          acc[i][j] = __builtin_amdgcn_mfma_f32_16x16x32_bf16(am[i], bp[j], acc[i][j], 0, 0, 0);
    }
  }
  float* sp = states + ((long)bc * NHEADS + h) * (D_STATE * HEADDIM);
#pragma unroll
  for (int i = 0; i < 2; ++i)
#pragma unroll
    for (int j = 0; j < 4; ++j) {
      int n0 = w * 32 + i * 16 + g * 4;
      int p = j * 16 + (lane & 15);
#pragma unroll
      for (int r = 0; r < 4; ++r) sp[(long)(n0 + r) * HEADDIM + p] = acc[i][j][r];
    }
}

// ---------------- inter-chunk scan -> prev_states (bf16, [n][p]) ----------------
__global__ void k_scan(const float* __restrict__ states, const float* __restrict__ A_cum, unsigned short* __restrict__ psb) {
  long idx = (long)blockIdx.x * blockDim.x + threadIdx.x;
  if (idx >= (long)BATCH * NHEADS * D_STATE * HEADDIM) return;
  int p = idx & 63;
  int n = (int)((idx >> 6) & 127);
  long bh = idx >> 13;
  int h = (int)(bh & 63);
  int b = (int)(bh >> 6);
  float S = 0.f;
  for (int c = 0; c < NCHUNK; ++c) {
    long soff = (((long)(b * NCHUNK + c) * NHEADS + h) * (D_STATE * HEADDIM)) + (long)n * HEADDIM + p;
    psb[soff] = f2bf(S);
    float decay = expf(A_cum[(bh * NCHUNK + c) * CHUNK + 255]);
    S = S * decay + states[soff];
  }
}

// ---------------- Y = Y_diag + Y_off + x*D (bf16 out), MFMA ----------------
__global__ __launch_bounds__(256) void k_y(const unsigned short* __restrict__ xbc, const float* __restrict__ dt_t,
                                           const float* __restrict__ A_cum, const unsigned short* __restrict__ cbt_t,
                                           const unsigned short* __restrict__ psb, const float* __restrict__ Dp,
                                           unsigned short* __restrict__ y) {
  const int bid = blockIdx.x;
  const int h = bid & 63;
  const int bc = bid >> 6;
  const int b = bc >> 3, c = bc & 7;
  const int t = threadIdx.x;
  const int lane = t & 63;
  const int w = t >> 6;
  const int g = lane >> 4;
  __shared__ unsigned short Abuf[256][72];
  __shared__ unsigned short Bbuf[64][72];
  __shared__ float csL[256], dtL[256], expL[256];
  const long rowbase = (long)b * SEQ + c * CHUNK;
  const long bh8 = ((long)(b * NHEADS + h)) * NCHUNK + c;
  const float* acum = A_cum + bh8 * CHUNK;
  if (t < 256) {
    float cv = acum[t];
    csL[t] = cv;
    expL[t] = expf(cv);
    dtL[t] = dt_t[((size_t)(b * NHEADS + h)) * SEQ + c * CHUNK + t];
  }
  f32x4 acc[4][4];
#pragma unroll
  for (int i = 0; i < 4; ++i)
#pragma unroll
    for (int j = 0; j < 4; ++j) { f32x4 z = {0.f, 0.f, 0.f, 0.f}; acc[i][j] = z; }

  const unsigned short* psbase = psb + ((long)bc * NHEADS + h) * (D_STATE * HEADDIM);
  for (int np = 0; np < 2; ++np) {
    __syncthreads();
    for (int i = t; i < 256 * 16; i += 256) {
      int row = i >> 4, c4 = (i & 15) * 4;
      float el = expL[row];
      ushort4 v = *(const ushort4*)(xbc + (rowbase + row) * (long)CONV_DIM + D_INNER + D_STATE + np * 64 + c4);
      ushort4 o = make_ushort4(f2bf(bf2f(v.x) * el), f2bf(bf2f(v.y) * el), f2bf(bf2f(v.z) * el), f2bf(bf2f(v.w) * el));
      *(ushort4*)&Abuf[row][c4] = o;
    }
    for (int i = t; i < 64 * 16; i += 256) {
      int n = i >> 4, p4 = (i & 15) * 4;
      ushort4 v = *(const ushort4*)(psbase + (long)(np * 64 + n) * HEADDIM + p4);
      Bbuf[p4 + 0][n] = v.x; Bbuf[p4 + 1][n] = v.y; Bbuf[p4 + 2][n] = v.z; Bbuf[p4 + 3][n] = v.w;
    }
    __syncthreads();
#pragma unroll
    for (int ks = 0; ks < 2; ++ks) {
      const int kofs = ks * 32 + g * 8;
      bf16x8 af[4], bfr[4];
#pragma unroll
      for (int i = 0; i < 4; ++i) af[i] = *(const bf16x8*)&Abuf[w * 64 + i * 16 + (lane & 15)][kofs];
#pragma unroll
      for (int j = 0; j < 4; ++j) bfr[j] = *(const bf16x8*)&Bbuf[j * 16 + (lane & 15)][kofs];
#pragma unroll
      for (int i = 0; i < 4; ++i)
#pragma unroll
        for (int j = 0; j < 4; ++j)
          acc[i][j] = __builtin_amdgcn_mfma_f32_16x16x32_bf16(af[i], bfr[j], acc[i][j], 0, 0, 0);
    }
  }

  const unsigned short* cbtb = cbt_t + (long)bc * CHUNK * CHUNK;
  for (int sp = 0; sp < 4; ++sp) {
    __syncthreads();
    for (int i = t; i < 64 * 8; i += 256) {
      int s = i >> 3, p0 = (i & 7) * 8;
      u16x8 v = *(const u16x8*)(xbc + (rowbase + sp * 64 + s) * (long)CONV_DIM + h * HEADDIM + p0);
#pragma unroll
      for (int e = 0; e < 8; ++e) Bbuf[p0 + e][s] = v[e];
    }
    __syncthreads();
    if (sp > w) continue;
#pragma unroll
    for (int ks = 0; ks < 2; ++ks) {
      const int kofs = ks * 32 + g * 8;
      bf16x8 bfr[4];
#pragma unroll
      for (int j = 0; j < 4; ++j) bfr[j] = *(const bf16x8*)&Bbuf[j * 16 + (lane & 15)][kofs];
      const int sbase = sp * 64 + ks * 32 + g * 8;
#pragma unroll
      for (int i = 0; i < 4; ++i) {
        if (sp == w && ks * 32 > i * 16 + 15) continue;
        const int l = w * 64 + i * 16 + (lane & 15);
        u16x8 cv = *(const u16x8*)(cbtb + (long)l * CHUNK + sbase);
        const float cl = csL[l];
        bf16x8 af;
#pragma unroll
        for (int e = 0; e < 8; ++e) {
          int s = sbase + e;
          float val = (s <= l) ? bf2f(cv[e]) * expf(cl - csL[s]) * dtL[s] : 0.f;
          af[e] = (short)f2bf(val);
        }
#pragma unroll
        for (int j = 0; j < 4; ++j)
          acc[i][j] = __builtin_amdgcn_mfma_f32_16x16x32_bf16(af, bfr[j], acc[i][j], 0, 0, 0);
      }
    }
  }

  const float Dh = Dp[h];
#pragma unroll
  for (int i = 0; i < 4; ++i) {
    int l0 = w * 64 + i * 16 + g * 4;
#pragma unroll
    for (int r = 0; r < 4; ++r) {
      long grow = rowbase + l0 + r;
      const unsigned short* xrow = xbc + grow * (long)CONV_DIM + h * HEADDIM;
      unsigned short* yrow = y + grow * (long)D_INNER + h * HEADDIM;
#pragma unroll
      for (int j = 0; j < 4; ++j) {
        int p = j * 16 + (lane & 15);
        yrow[p] = f2bf(acc[i][j][r] + bf2f(xrow[p]) * Dh);
      }
    }
  }
}

// ---------------- gated RMSNorm ----------------
__global__ __launch_bounds__(256) void k_norm(unsigned short* yz, const unsigned short* __restrict__ zb,
                                              const float* __restrict__ norm_w, unsigned short* out) {
  const int row = blockIdx.x;
  const int t = threadIdx.x;
  const unsigned short* yr = yz + (size_t)row * D_INNER;
  const unsigned short* zr = zb + (size_t)row * D_INNER;
  float yv[16];
  float ss = 0.f;
#pragma unroll
  for (int j = 0; j < 4; ++j) {
    int e = (t + j * 256) * 4;
    ushort4 yy = *(const ushort4*)(yr + e);
    ushort4 zz = *(const ushort4*)(zr + e);
    float z0 = bf2f(zz.x), z1 = bf2f(zz.y), z2 = bf2f(zz.z), z3 = bf2f(zz.w);
    float g0 = bf2f(yy.x) * z0 / (1.f + expf(-z0));
    float g1 = bf2f(yy.y) * z1 / (1.f + expf(-z1));
    float g2 = bf2f(yy.z) * z2 / (1.f + expf(-z2));
    float g3 = bf2f(yy.w) * z3 / (1.f + expf(-z3));
    ss += g0 * g0 + g1 * g1 + g2 * g2 + g3 * g3;
    yv[j * 4 + 0] = g0; yv[j * 4 + 1] = g1; yv[j * 4 + 2] = g2; yv[j * 4 + 3] = g3;
  }
#pragma unroll
  for (int off = 32; off > 0; off >>= 1) ss += __shfl_xor(ss, off);
  __shared__ float red[4];
  if ((t & 63) == 0) red[t >> 6] = ss;
  __syncthreads();
  float tot = red[0] + red[1] + red[2] + red[3];
  float scale = rsqrtf(tot / (float)D_INNER + EPSV);
  unsigned short* orow = out + (size_t)row * D_INNER;
#pragma unroll
  for (int j = 0; j < 4; ++j) {
    int e = (t + j * 256) * 4;
    float4 w = *(const float4*)(norm_w + e);
    ushort4 o = make_ushort4(f2bf(yv[j * 4 + 0] * scale * w.x), f2bf(yv[j * 4 + 1] * scale * w.y),
                             f2bf(yv[j * 4 + 2] * scale * w.z), f2bf(yv[j * 4 + 3] * scale * w.w));
    *(ushort4*)(orow + e) = o;
  }
}

extern "C" void kernel_launch(void* const* d_in, const int* in_sizes, int n_in,
                              void* d_out, int out_size, void* d_ws, size_t ws_size,
                              hipStream_t stream) {
  const float* u       = (const float*)d_in[0];
  const float* W_in    = (const float*)d_in[1];
  const float* conv_w  = (const float*)d_in[2];
  const float* conv_b  = (const float*)d_in[3];
  const float* dt_bias = (const float*)d_in[4];
  const float* A_log   = (const float*)d_in[5];
  const float* Dp      = (const float*)d_in[6];
  const float* norm_w  = (const float*)d_in[7];
  const float* W_out   = (const float*)d_in[8];
  float* out = (float*)d_out;

  char* ws = (char*)d_ws;
  size_t off = 0;
  auto alloc = [&](size_t bytes) { char* p = ws + off; off += (bytes + 255) & ~(size_t)255; return p; };
  unsigned short* ub   = (unsigned short*)alloc((size_t)NROWS * D_MODEL * 2);
  unsigned short* winb = (unsigned short*)alloc((size_t)D_IN_PROJ * D_MODEL * 2);
  unsigned short* zb   = (unsigned short*)alloc((size_t)NROWS * D_INNER * 2);
  unsigned short* xb   = (unsigned short*)alloc((size_t)NROWS * CONV_DIM * 2);
  unsigned short* xbcb = (unsigned short*)alloc((size_t)NROWS * CONV_DIM * 2);
  float* dtt  = (float*)alloc((size_t)BATCH * NHEADS * SEQ * 4);
  float* acum = (float*)alloc((size_t)BATCH * NHEADS * NCHUNK * CHUNK * 4);
  unsigned short* cwT = (unsigned short*)alloc((size_t)4 * CONV_DIM * 2);
  unsigned short* cbT = (unsigned short*)alloc((size_t)CONV_DIM * 2);
  unsigned short* whl = (unsigned short*)alloc((size_t)128 * D_MODEL * 2);
  unsigned short* wob = ub;                     // W_out bf16, after GEMMs
  unsigned short* cbt = winb;                   // CBT^T bf16, after GEMMs
  unsigned short* psb = winb + (size_t)BATCH * NCHUNK * CHUNK * CHUNK + 1024;
  unsigned short* ulob = xbcb;                  // u residual bf16; dead before conv writes xbcb
  unsigned short* yb = xb;                      // y bf16, after conv
  float* states = (float*)d_out;

  if (off > ws_size) {
    k_sentinel<<<1, 64, 0, stream>>>(out);
    return;
  }

  k_usplit<<<2048, 256, 0, stream>>>(u, ub, ulob, (long)NROWS * D_MODEL / 4);
  k_f32_to_bf16_v4<<<2048, 256, 0, stream>>>(W_in, winb, (long)D_IN_PROJ * D_MODEL / 4);
  k_wpack<<<(64 * D_MODEL + 255) / 256, 256, 0, stream>>>(W_in, whl);
  k_conv_pack<<<(CONV_DIM + 255) / 256, 256, 0, stream>>>(conv_w, conv_b, cwT, cbT);
  k_gemm8p<<<(NROWS / 256) * (D_INNER / 256), 512, 0, stream>>>(ub, winb, zb, NROWS, D_INNER, D_MODEL);
  k_gemm128<1><<<(NROWS / 128) * (CONV_DIM / 128), 256, 0, stream>>>(ub, winb + (size_t)D_INNER * D_MODEL, xb, NROWS, CONV_DIM, D_MODEL);
  k_dtm<<<NROWS / 64, 256, 0, stream>>>(ub, ulob, whl, dt_bias, dtt);
  k_conv_silu<<<(int)(((long)(NROWS / 4) * CG + 255) / 256), 256, 0, stream>>>(xb, cwT, cbT, xbcb);
  k_cumsum<<<BATCH * NHEADS * NCHUNK, 256, 0, stream>>>(dtt, A_log, acum);
  k_cbtt<<<BATCH * NCHUNK * 4, 256, 0, stream>>>(xbcb, cbt);
  k_states<<<BATCH * NCHUNK * NHEADS, 256, 0, stream>>>(xbcb, dtt, acum, states);
  k_scan<<<(BATCH * NHEADS * D_STATE * HEADDIM + 255) / 256, 256, 0, stream>>>(states, acum, psb);
  k_y<<<BATCH * NCHUNK * NHEADS, 256, 0, stream>>>(xbcb, dtt, acum, cbt, psb, Dp, yb);
  k_norm<<<NROWS, 256, 0, stream>>>(yb, zb, norm_w, yb);
  k_f32_to_bf16_v4<<<2048, 256, 0, stream>>>(W_out, wob, (long)D_MODEL * D_INNER / 4);
  k_gemm128<0><<<(NROWS / 128) * (D_MODEL / 128), 256, 0, stream>>>(yb, wob, out, NROWS, D_MODEL, D_INNER);
}

// Round 9
// 499.866 us; speedup vs baseline: 2.1945x; 1.0143x over previous
//
#include <hip/hip_runtime.h>

#define D_MODEL   2048
#define D_INNER   4096
#define HEADDIM   64
#define NHEADS    64
#define D_STATE   128
#define CHUNK     256
#define CONV_DIM  4352
#define D_IN_PROJ 8512
#define BATCH     2
#define SEQ       2048
#define NCHUNK    8
#define NROWS     4096
#define EPSV      1e-5f
#define CG        (CONV_DIM / 8)   // 544

typedef __attribute__((ext_vector_type(8))) short bf16x8;
typedef __attribute__((ext_vector_type(8))) unsigned short u16x8;
typedef __attribute__((ext_vector_type(4))) float f32x4;

#define AS1 __attribute__((address_space(1)))
#define AS3 __attribute__((address_space(3)))

#define BAR() do { asm volatile("" ::: "memory"); __builtin_amdgcn_s_barrier(); asm volatile("" ::: "memory"); } while (0)

__device__ __forceinline__ unsigned short f2bf(float f) {
  unsigned int x = __float_as_uint(f);
  unsigned int r = (x + 0x7fffu + ((x >> 16) & 1u)) >> 16;
  return (unsigned short)r;
}
__device__ __forceinline__ float bf2f(unsigned short u) {
  return __uint_as_float((unsigned int)u << 16);
}

__global__ void k_sentinel(float* out) { if (threadIdx.x == 0) out[0] = 1.0e6f; }

// ---------------- converts ----------------
__global__ void k_f32_to_bf16_v4(const float* __restrict__ in, unsigned short* __restrict__ out, long n4) {
  long i = (long)blockIdx.x * blockDim.x + threadIdx.x;
  long stride = (long)gridDim.x * blockDim.x;
  for (; i < n4; i += stride) {
    float4 v = ((const float4*)in)[i];
    ushort4 o = make_ushort4(f2bf(v.x), f2bf(v.y), f2bf(v.z), f2bf(v.w));
    ((ushort4*)out)[i] = o;
  }
}

// u -> bf16 hi + bf16 residual lo (one pass)
__global__ void k_usplit(const float* __restrict__ in, unsigned short* __restrict__ hi,
                         unsigned short* __restrict__ lo, long n4) {
  long i = (long)blockIdx.x * blockDim.x + threadIdx.x;
  long stride = (long)gridDim.x * blockDim.x;
  for (; i < n4; i += stride) {
    float4 v = ((const float4*)in)[i];
    ushort4 h, l;
    h.x = f2bf(v.x); l.x = f2bf(v.x - bf2f(h.x));
    h.y = f2bf(v.y); l.y = f2bf(v.y - bf2f(h.y));
    h.z = f2bf(v.z); l.z = f2bf(v.z - bf2f(h.z));
    h.w = f2bf(v.w); l.w = f2bf(v.w - bf2f(h.w));
    ((ushort4*)hi)[i] = h;
    ((ushort4*)lo)[i] = l;
  }
}

// W_in dt rows (8448..8511) -> whl[0:64]=bf16 hi, whl[64:128]=bf16 residual
__global__ void k_wpack(const float* __restrict__ W, unsigned short* __restrict__ whl) {
  long i = (long)blockIdx.x * blockDim.x + threadIdx.x;
  if (i >= (long)64 * D_MODEL) return;
  float v = W[(size_t)8448 * D_MODEL + i];
  unsigned short h = f2bf(v);
  whl[i] = h;
  whl[(size_t)64 * D_MODEL + i] = f2bf(v - bf2f(h));
}

// ---- dt split-bf16 MFMA, SPLIT-K=4: raw partial sums -> PD[ks][bh][l] (f32) ----
// grid 256 = 64 m-blocks x 4 k-slices; NT=8 per slice.
__global__ __launch_bounds__(256, 2) void k_dtm(const unsigned short* __restrict__ uhi,
                                                const unsigned short* __restrict__ ulo,
                                                const unsigned short* __restrict__ whl,
                                                float* __restrict__ PD) {
  __shared__ __align__(16) short lds[2][256 * 64];   // rows 0-63 uhi, 64-127 ulo, 128-255 [Whi;Wlo]
  const int t = threadIdx.x;
  const int lane = t & 63;
  const int w = t >> 6;
  const int ks = (int)blockIdx.x & 3;
  const int m0 = ((int)blockIdx.x >> 2) * 64;
  const int kbase = ks * 512;

  f32x4 acc1[8], acc2[4];
#pragma unroll
  for (int j = 0; j < 8; ++j) { f32x4 z = {0.f, 0.f, 0.f, 0.f}; acc1[j] = z; }
#pragma unroll
  for (int j = 0; j < 4; ++j) { f32x4 z = {0.f, 0.f, 0.f, 0.f}; acc2[j] = z; }

  const int srow = t >> 3;                 // 0..31
  const int schunk = (t & 7) ^ (srow & 7); // T2 inverse pre-swizzle
  const unsigned short* gU = uhi + (size_t)(m0 + srow) * D_MODEL + kbase + schunk * 8;
  const unsigned short* gL = ulo + (size_t)(m0 + srow) * D_MODEL + kbase + schunk * 8;
  const unsigned short* gW = whl + (size_t)srow * D_MODEL + kbase + schunk * 8;

  auto STAGE = [&](int buf, int kt) {      // 8 global_load_lds per thread
    char* d = (char*)&lds[buf][0] + t * 16;
#pragma unroll
    for (int ii = 0; ii < 2; ++ii)
      __builtin_amdgcn_global_load_lds((const AS1 void*)(gU + (size_t)ii * 32 * D_MODEL + (size_t)kt * 64),
                                       (AS3 void*)(d + ii * 4096), 16, 0, 0);
#pragma unroll
    for (int ii = 0; ii < 2; ++ii)
      __builtin_amdgcn_global_load_lds((const AS1 void*)(gL + (size_t)ii * 32 * D_MODEL + (size_t)kt * 64),
                                       (AS3 void*)(d + 8192 + ii * 4096), 16, 0, 0);
#pragma unroll
    for (int ii = 0; ii < 4; ++ii)
      __builtin_amdgcn_global_load_lds((const AS1 void*)(gW + (size_t)ii * 32 * D_MODEL + (size_t)kt * 64),
                                       (AS3 void*)(d + 16384 + ii * 4096), 16, 0, 0);
  };

  STAGE(0, 0);

  const int NT = 512 / 64;
  const int ar = w * 16 + (lane & 15);
  const int kof = (lane >> 4) * 8;
  const int rsw = (lane & 7) * 8;
  int cur = 0;
  for (int kt = 0; kt < NT; ++kt) {
    if (kt + 1 < NT) {
      STAGE(cur ^ 1, kt + 1);
      asm volatile("s_waitcnt vmcnt(8)" ::: "memory");
    } else {
      asm volatile("s_waitcnt vmcnt(0)" ::: "memory");
    }
    __builtin_amdgcn_s_barrier();
    asm volatile("" ::: "memory");
    const short* L = &lds[cur][0];
#pragma unroll
    for (int kk = 0; kk < 2; ++kk) {
      const int off = (kk * 32 + kof) ^ rsw;
      bf16x8 ah = *(const bf16x8*)(L + ar * 64 + off);
      bf16x8 al = *(const bf16x8*)(L + (64 + ar) * 64 + off);
#pragma unroll
      for (int j = 0; j < 8; ++j) {
        bf16x8 bj = *(const bf16x8*)(L + (128 + j * 16 + (lane & 15)) * 64 + off);
        acc1[j] = __builtin_amdgcn_mfma_f32_16x16x32_bf16(ah, bj, acc1[j], 0, 0, 0);
        if (j < 4) acc2[j] = __builtin_amdgcn_mfma_f32_16x16x32_bf16(al, bj, acc2[j], 0, 0, 0);
      }
    }
    asm volatile("" ::: "memory");
    __builtin_amdgcn_s_barrier();
    asm volatile("" ::: "memory");
    cur ^= 1;
  }

  const int crow = (lane >> 4) * 4;
  float* P = PD + (size_t)ks * BATCH * NHEADS * SEQ;
#pragma unroll
  for (int j = 0; j < 4; ++j) {
    int h = j * 16 + (lane & 15);
#pragma unroll
    for (int r = 0; r < 4; ++r) {
      int row = m0 + w * 16 + crow + r;
      float v = acc1[j][r] + acc1[j + 4][r] + acc2[j][r];
      P[(size_t)((row >> 11) * NHEADS + h) * SEQ + (row & 2047)] = v;
    }
  }
}

// ---- dt reduce (+bias, softplus) -> dtt; fused per-chunk cumsum of dA -> acum ----
// grid = BATCH*NHEADS (128 blocks), 256 threads.
__global__ __launch_bounds__(256) void k_dtred(const float* __restrict__ PD, const float* __restrict__ dt_bias,
                                               const float* __restrict__ A_log,
                                               float* __restrict__ dt_t, float* __restrict__ A_cum) {
  const int bh = blockIdx.x;
  const int h = bh & 63;
  const int t = threadIdx.x;
  const float bias = dt_bias[h];
  const float A = -expf(A_log[h]);
  const size_t base = (size_t)bh * SEQ;
  const size_t pstride = (size_t)BATCH * NHEADS * SEQ;
  __shared__ float s[256];
  for (int c = 0; c < NCHUNK; ++c) {
    int l = c * CHUNK + t;
    float v = PD[base + l] + PD[pstride + base + l] + PD[2 * pstride + base + l] + PD[3 * pstride + base + l] + bias;
    float dtv = (v > 20.f) ? v : log1pf(expf(v));
    dt_t[base + l] = dtv;
    s[t] = dtv * A;
    __syncthreads();
    for (int off = 1; off < 256; off <<= 1) {
      float x = (t >= off) ? s[t - off] : 0.f;
      __syncthreads();
      s[t] += x;
      __syncthreads();
    }
    A_cum[((size_t)bh * NCHUNK + c) * CHUNK + t] = s[t];
    __syncthreads();
  }
}

// ---- 256x256 BK=64 8-phase GEMM (T2+T3+T4+T5), 512 thr, 8 waves (2Mx4N), grid%8==0 ----
__global__ __launch_bounds__(512, 2) void k_gemm8p(const unsigned short* __restrict__ A,
                                                   const unsigned short* __restrict__ B,
                                                   unsigned short* __restrict__ C, int M, int N, int K) {
  __shared__ __align__(16) short lds[2][32768];
  const int t = threadIdx.x;
  const int lane = t & 63;
  const int wid = t >> 6;
  const int wr = wid >> 2;
  const int wc = wid & 3;
  const int ntx = N / 256;
  const int nwg = (int)gridDim.x;
  const int bid = (int)blockIdx.x;
  const int swzb = (bid & 7) * (nwg >> 3) + (bid >> 3);
  const int m0 = (swzb / ntx) * 256;
  const int n0 = (swzb % ntx) * 256;

  f32x4 acc[8][4];
#pragma unroll
  for (int i = 0; i < 8; ++i)
#pragma unroll
    for (int j = 0; j < 4; ++j) { f32x4 z = {0.f, 0.f, 0.f, 0.f}; acc[i][j] = z; }

  const int srow = t >> 3;
  const int schunk = (t & 7) ^ (srow & 7);
  const unsigned short* gA = A + (size_t)(m0 + srow) * K + schunk * 8;
  const unsigned short* gB = B + (size_t)(n0 + srow) * K + schunk * 8;

  auto STAGE_HALF = [&](int buf, int kt, int which) {
    const unsigned short* g = (which < 2 ? gA : gB) + (size_t)(which & 1) * 128 * K + (size_t)kt * 64;
    char* d = (char*)lds + buf * 65536 + which * 16384 + t * 16;
    __builtin_amdgcn_global_load_lds((const AS1 void*)g, (AS3 void*)d, 16, 0, 0);
    __builtin_amdgcn_global_load_lds((const AS1 void*)(g + (size_t)64 * K), (AS3 void*)(d + 8192), 16, 0, 0);
  };

  const int NT = K / 64;
  STAGE_HALF(0, 0, 0); STAGE_HALF(0, 0, 1); STAGE_HALF(0, 0, 2); STAGE_HALF(0, 0, 3);
  STAGE_HALF(1, 1, 2); STAGE_HALF(1, 1, 0); STAGE_HALF(1, 1, 1);
  asm volatile("s_waitcnt vmcnt(6)" ::: "memory");
  BAR();

  const int ar = wr * 128 + (lane & 15);
  const int br = wc * 64 + (lane & 15);
  const int kof = (lane >> 4) * 8;
  const int rsw = (lane & 7) * 8;

  for (int kt = 0; kt < NT; ++kt) {
    const int buf = kt & 1;
    const short* As = &lds[buf][0];
    const short* Bs = &lds[buf][16384];
    const bool s1 = (kt + 1 < NT);
    const bool s2 = (kt + 2 < NT);
    bf16x8 aLo[4][2], aHi[4][2], bLo[2][2], bHi[2][2];

#pragma unroll
    for (int i = 0; i < 4; ++i)
#pragma unroll
      for (int k = 0; k < 2; ++k) aLo[i][k] = *(const bf16x8*)(As + (ar + i * 16) * 64 + ((k * 32 + kof) ^ rsw));
#pragma unroll
    for (int j = 0; j < 2; ++j)
#pragma unroll
      for (int k = 0; k < 2; ++k) bLo[j][k] = *(const bf16x8*)(Bs + (br + j * 16) * 64 + ((k * 32 + kof) ^ rsw));
    if (s1) STAGE_HALF(buf ^ 1, kt + 1, 3);
    BAR();
    __builtin_amdgcn_s_setprio(1);
#pragma unroll
    for (int k = 0; k < 2; ++k)
#pragma unroll
      for (int i = 0; i < 4; ++i)
#pragma unroll
        for (int j = 0; j < 2; ++j)
          acc[i][j] = __builtin_amdgcn_mfma_f32_16x16x32_bf16(aLo[i][k], bLo[j][k], acc[i][j], 0, 0, 0);
    __builtin_amdgcn_s_setprio(0);
    BAR();

#pragma unroll
    for (int j = 0; j < 2; ++j)
#pragma unroll
      for (int k = 0; k < 2; ++k) bHi[j][k] = *(const bf16x8*)(Bs + (br + (j + 2) * 16) * 64 + ((k * 32 + kof) ^ rsw));
    BAR();
    __builtin_amdgcn_s_setprio(1);
#pragma unroll
    for (int k = 0; k < 2; ++k)
#pragma unroll
      for (int i = 0; i < 4; ++i)
#pragma unroll
        for (int j = 0; j < 2; ++j)
          acc[i][j + 2] = __builtin_amdgcn_mfma_f32_16x16x32_bf16(aLo[i][k], bHi[j][k], acc[i][j + 2], 0, 0, 0);
    __builtin_amdgcn_s_setprio(0);
    BAR();

#pragma unroll
    for (int i = 0; i < 4; ++i)
#pragma unroll
      for (int k = 0; k < 2; ++k) aHi[i][k] = *(const bf16x8*)(As + (ar + (i + 4) * 16) * 64 + ((k * 32 + kof) ^ rsw));
    if (s2) STAGE_HALF(buf, kt + 2, 2);
    BAR();
    __builtin_amdgcn_s_setprio(1);
#pragma unroll
    for (int k = 0; k < 2; ++k)
#pragma unroll
      for (int i = 0; i < 4; ++i)
#pragma unroll
        for (int j = 0; j < 2; ++j)
          acc[i + 4][j] = __builtin_amdgcn_mfma_f32_16x16x32_bf16(aHi[i][k], bLo[j][k], acc[i + 4][j], 0, 0, 0);
    __builtin_amdgcn_s_setprio(0);
    BAR();

    if (s2) { STAGE_HALF(buf, kt + 2, 0); STAGE_HALF(buf, kt + 2, 1); }
    if (s2) { asm volatile("s_waitcnt vmcnt(6)" ::: "memory"); }
    else    { asm volatile("s_waitcnt vmcnt(0)" ::: "memory"); }
    BAR();
    __builtin_amdgcn_s_setprio(1);
#pragma unroll
    for (int k = 0; k < 2; ++k)
#pragma unroll
      for (int i = 0; i < 4; ++i)
#pragma unroll
        for (int j = 0; j < 2; ++j)
          acc[i + 4][j + 2] = __builtin_amdgcn_mfma_f32_16x16x32_bf16(aHi[i][k], bHi[j][k], acc[i + 4][j + 2], 0, 0, 0);
    __builtin_amdgcn_s_setprio(0);
    BAR();
  }

  const int crow = (lane >> 4) * 4;
  const int ccol = lane & 15;
#pragma unroll
  for (int i = 0; i < 8; ++i)
#pragma unroll
    for (int j = 0; j < 4; ++j) {
      size_t base = (size_t)(m0 + wr * 128 + i * 16 + crow) * N + (n0 + wc * 64 + j * 16 + ccol);
#pragma unroll
      for (int r = 0; r < 4; ++r) C[base + (size_t)r * N] = f2bf(acc[i][j][r]);
    }
}

// ---- 128x128 BK=64 double-buffered GEMM ----
template <int BF16OUT>
__global__ __launch_bounds__(256, 2) void k_gemm128(const unsigned short* __restrict__ A,
                                                    const unsigned short* __restrict__ B,
                                                    void* __restrict__ Cv, int M, int N, int K) {
  constexpr int BK = 64;
  __shared__ __align__(16) short lds[2][256 * BK];
  const int t = threadIdx.x;
  const int lane = t & 63;
  const int wid = t >> 6;
  const int wr = wid >> 1;
  const int wc = wid & 1;
  const int ntx = N / 128;
  const int nwg = (int)gridDim.x;
  const int bid = (int)blockIdx.x;
  const int swzb = (bid & 7) * (nwg >> 3) + (bid >> 3);
  const int m0 = (swzb / ntx) * 128;
  const int n0 = (swzb % ntx) * 128;

  f32x4 acc[4][4];
#pragma unroll
  for (int i = 0; i < 4; ++i)
#pragma unroll
    for (int j = 0; j < 4; ++j) { f32x4 z = {0.f, 0.f, 0.f, 0.f}; acc[i][j] = z; }

  const int srow = t >> 3;
  const int schunk = (t & 7) ^ (srow & 7);
  const unsigned short* gA = A + (size_t)(m0 + srow) * K + schunk * 8;
  const unsigned short* gB = B + (size_t)(n0 + srow) * K + schunk * 8;

  auto STAGE = [&](int buf, int kt) {
    char* dA = (char*)&lds[buf][0] + t * 16;
    char* dB = (char*)&lds[buf][128 * BK] + t * 16;
#pragma unroll
    for (int ii = 0; ii < 4; ++ii)
      __builtin_amdgcn_global_load_lds((const AS1 void*)(gA + (size_t)ii * 32 * K + kt * BK),
                                       (AS3 void*)(dA + ii * 4096), 16, 0, 0);
#pragma unroll
    for (int ii = 0; ii < 4; ++ii)
      __builtin_amdgcn_global_load_lds((const AS1 void*)(gB + (size_t)ii * 32 * K + kt * BK),
                                       (AS3 void*)(dB + ii * 4096), 16, 0, 0);
  };

  STAGE(0, 0);

  const int NT = K / BK;
  const int ar = wr * 64 + (lane & 15);
  const int br = wc * 64 + (lane & 15);
  const int kof = (lane >> 4) * 8;
  const int rsw = (lane & 7) * 8;
  int cur = 0;
  for (int kt = 0; kt < NT; ++kt) {
    if (kt + 1 < NT) {
      STAGE(cur ^ 1, kt + 1);
      asm volatile("s_waitcnt vmcnt(8)" ::: "memory");
    } else {
      asm volatile("s_waitcnt vmcnt(0)" ::: "memory");
    }
    __builtin_amdgcn_s_barrier();
    asm volatile("" ::: "memory");
    const short* As = &lds[cur][0];
    const short* Bs = &lds[cur][128 * BK];
#pragma unroll
    for (int kk = 0; kk < 2; ++kk) {
      bf16x8 bfr[4];
#pragma unroll
      for (int j = 0; j < 4; ++j)
        bfr[j] = *(const bf16x8*)(Bs + (br + j * 16) * BK + ((kk * 32 + kof) ^ rsw));
#pragma unroll
      for (int i = 0; i < 4; ++i) {
        bf16x8 af = *(const bf16x8*)(As + (ar + i * 16) * BK + ((kk * 32 + kof) ^ rsw));
#pragma unroll
        for (int j = 0; j < 4; ++j)
          acc[i][j] = __builtin_amdgcn_mfma_f32_16x16x32_bf16(af, bfr[j], acc[i][j], 0, 0, 0);
      }
    }
    asm volatile("" ::: "memory");
    __builtin_amdgcn_s_barrier();
    asm volatile("" ::: "memory");
    cur ^= 1;
  }

  const int crow = (lane >> 4) * 4;
  const int ccol = lane & 15;
#pragma unroll
  for (int i = 0; i < 4; ++i)
#pragma unroll
    for (int j = 0; j < 4; ++j) {
      size_t base = (size_t)(m0 + wr * 64 + i * 16 + crow) * N + (n0 + wc * 64 + j * 16 + ccol);
      if (BF16OUT) {
        unsigned short* C = (unsigned short*)Cv;
#pragma unroll
        for (int r = 0; r < 4; ++r) C[base + (size_t)r * N] = f2bf(acc[i][j][r]);
      } else {
        float* C = (float*)Cv;
#pragma unroll
        for (int r = 0; r < 4; ++r) C[base + (size_t)r * N] = acc[i][j][r];
      }
    }
}

// ---------------- conv weight/bias pack ----------------
__global__ void k_conv_pack(const float* __restrict__ cw, const float* __restrict__ cb,
                            unsigned short* __restrict__ wT, unsigned short* __restrict__ bT) {
  int i = blockIdx.x * blockDim.x + threadIdx.x;
  if (i < CONV_DIM) {
#pragma unroll
    for (int w = 0; w < 4; ++w) wT[w * CONV_DIM + i] = f2bf(cw[i * 4 + w]);
    bT[i] = f2bf(cb[i]);
  }
}

// ---------------- conv1d + silu ----------------
__global__ __launch_bounds__(256) void k_conv_silu(const unsigned short* __restrict__ xb,
                                                   const unsigned short* __restrict__ wT,
                                                   const unsigned short* __restrict__ bT,
                                                   unsigned short* __restrict__ out) {
  long idx = (long)blockIdx.x * blockDim.x + threadIdx.x;
  if (idx >= (long)(NROWS / 4) * CG) return;
  int c8 = (int)(idx % CG);
  long rq = idx / CG;
  int l0 = (int)((rq & (SEQ / 4 - 1)) * 4);
  long brow = (rq >> 9) * (long)SEQ;
  int ch0 = c8 * 8;

  u16x8 wv[4];
#pragma unroll
  for (int w = 0; w < 4; ++w) wv[w] = *(const u16x8*)(wT + w * CONV_DIM + ch0);
  u16x8 bv = *(const u16x8*)(bT + ch0);

  u16x8 xr[7];
#pragma unroll
  for (int i = 0; i < 7; ++i) {
    int ls = l0 - 3 + i;
    if (ls >= 0) xr[i] = *(const u16x8*)(xb + (brow + ls) * (long)CONV_DIM + ch0);
    else { u16x8 z = {0, 0, 0, 0, 0, 0, 0, 0}; xr[i] = z; }
  }

#pragma unroll
  for (int r = 0; r < 4; ++r) {
    float acc[8];
#pragma unroll
    for (int e = 0; e < 8; ++e) acc[e] = bf2f(bv[e]);
#pragma unroll
    for (int w = 0; w < 4; ++w)
#pragma unroll
      for (int e = 0; e < 8; ++e) acc[e] += bf2f(xr[r + w][e]) * bf2f(wv[w][e]);
    u16x8 o;
#pragma unroll
    for (int e = 0; e < 8; ++e) o[e] = f2bf(acc[e] / (1.f + expf(-acc[e])));
    *(u16x8*)(out + (brow + l0 + r) * (long)CONV_DIM + ch0) = o;
  }
}

// ---------------- CBT^T[l][s] = C_l . B_s  (bf16 out), MFMA ----------------
__global__ __launch_bounds__(256) void k_cbtt(const unsigned short* __restrict__ xbc, unsigned short* __restrict__ cbt_t) {
  const int bid = blockIdx.x;
  const int sp = bid & 3;
  const int bc = bid >> 2;
  const int b = bc >> 3, c = bc & 7;
  const int t = threadIdx.x;
  const int lane = t & 63;
  const int w = t >> 6;
  const int g = lane >> 4;
  __shared__ unsigned short Cs[256][72];
  __shared__ unsigned short Bs2[64][72];
  const long rowbase = (long)b * SEQ + c * CHUNK;
  f32x4 acc[4][4];
#pragma unroll
  for (int i = 0; i < 4; ++i)
#pragma unroll
    for (int j = 0; j < 4; ++j) { f32x4 z = {0.f, 0.f, 0.f, 0.f}; acc[i][j] = z; }

  for (int np = 0; np < 2; ++np) {
    __syncthreads();
    for (int i = t; i < 256 * 16; i += 256) {
      int row = i >> 4, c4 = (i & 15) * 4;
      ushort4 v = *(const ushort4*)(xbc + (rowbase + row) * (long)CONV_DIM + D_INNER + D_STATE + np * 64 + c4);
      *(ushort4*)&Cs[row][c4] = v;
    }
    for (int i = t; i < 64 * 16; i += 256) {
      int row = i >> 4, c4 = (i & 15) * 4;
      ushort4 v = *(const ushort4*)(xbc + (rowbase + sp * 64 + row) * (long)CONV_DIM + D_INNER + np * 64 + c4);
      *(ushort4*)&Bs2[row][c4] = v;
    }
    __syncthreads();
#pragma unroll
    for (int ks = 0; ks < 2; ++ks) {
      const int kofs = ks * 32 + g * 8;
      bf16x8 af[4], bfr[4];
#pragma unroll
      for (int i = 0; i < 4; ++i) af[i] = *(const bf16x8*)&Cs[w * 64 + i * 16 + (lane & 15)][kofs];
#pragma unroll
      for (int j = 0; j < 4; ++j) bfr[j] = *(const bf16x8*)&Bs2[j * 16 + (lane & 15)][kofs];
#pragma unroll
      for (int i = 0; i < 4; ++i)
#pragma unroll
        for (int j = 0; j < 4; ++j)
          acc[i][j] = __builtin_amdgcn_mfma_f32_16x16x32_bf16(af[i], bfr[j], acc[i][j], 0, 0, 0);
    }
  }
  unsigned short* ob = cbt_t + (long)bc * CHUNK * CHUNK;
#pragma unroll
  for (int i = 0; i < 4; ++i)
#pragma unroll
    for (int j = 0; j < 4; ++j) {
      int l0 = w * 64 + i * 16 + g * 4;
      int s = sp * 64 + j * 16 + (lane & 15);
#pragma unroll
      for (int r = 0; r < 4; ++r) ob[(long)(l0 + r) * CHUNK + s] = f2bf(acc[i][j][r]);
    }
}

// ---------------- states[n][p] = sum_l B[l][n]*w_l*x[l][p], MFMA ----------------
__global__ __launch_bounds__(256) void k_states(const unsigned short* __restrict__ xbc, const float* __restrict__ dt_t,
                                                const float* __restrict__ A_cum, float* __restrict__ states) {
  const int bid = blockIdx.x;
  const int h = bid & 63;
  const int bc = bid >> 6;
  const int b = bc >> 3, c = bc & 7;
  const int t = threadIdx.x;
  const int lane = t & 63;
  const int w = t >> 6;
  const int g = lane >> 4;
  __shared__ unsigned short BT[128][72];
  __shared__ unsigned short WXT[64][72];
  __shared__ float csL[256], dtL[256];
  const long rowbase = (long)b * SEQ + c * CHUNK;
  const long bh8 = ((long)(b * NHEADS + h)) * NCHUNK + c;
  const float* acum = A_cum + bh8 * CHUNK;
  if (t < 256) { csL[t] = acum[t]; dtL[t] = dt_t[((size_t)(b * NHEADS + h)) * SEQ + c * CHUNK + t]; }
  float cs_last = acum[255];
  f32x4 acc[2][4];
#pragma unroll
  for (int i = 0; i < 2; ++i)
#pragma unroll
    for (int j = 0; j < 4; ++j) { f32x4 z = {0.f, 0.f, 0.f, 0.f}; acc[i][j] = z; }

  for (int lp = 0; lp < 4; ++lp) {
    __syncthreads();
    for (int i = t; i < 64 * 32; i += 256) {
      int l = i >> 5, n4 = (i & 31) * 4;
      ushort4 v = *(const ushort4*)(xbc + (rowbase + lp * 64 + l) * (long)CONV_DIM + D_INNER + n4);
      BT[n4 + 0][l] = v.x; BT[n4 + 1][l] = v.y; BT[n4 + 2][l] = v.z; BT[n4 + 3][l] = v.w;
    }
    for (int i = t; i < 64 * 16; i += 256) {
      int l = i >> 4, p4 = (i & 15) * 4;
      int lg = lp * 64 + l;
      float wgt = expf(cs_last - csL[lg]) * dtL[lg];
      ushort4 v = *(const ushort4*)(xbc + (rowbase + lg) * (long)CONV_DIM + h * HEADDIM + p4);
      WXT[p4 + 0][l] = f2bf(bf2f(v.x) * wgt);
      WXT[p4 + 1][l] = f2bf(bf2f(v.y) * wgt);
      WXT[p4 + 2][l] = f2bf(bf2f(v.z) * wgt);
      WXT[p4 + 3][l] = f2bf(bf2f(v.w) * wgt);
    }
    __syncthreads();
#pragma unroll
    for (int ks = 0; ks < 2; ++ks) {
      const int kofs = ks * 32 + g * 8;
      bf16x8 am[2], bp[4];
#pragma unroll
      for (int i = 0; i < 2; ++i) am[i] = *(const bf16x8*)&BT[w * 32 + i * 16 + (lane & 15)][kofs];
#pragma unroll
      for (int j = 0; j < 4; ++j) bp[j] = *(const bf16x8*)&WXT[j * 16 + (lane & 15)][kofs];
#pragma unroll
      for (int i = 0; i < 2; ++i)
#pragma unroll
        for (int j = 0; j < 4; ++j)
          acc[i][j] = __builtin_amdgcn_mfma_f32_16x16x32_bf16(am[i], bp[j], acc[i][j], 0, 0, 0);
    }
  }
  float* sp = states + ((long)bc * NHEADS + h) * (D_STATE * HEADDIM);
#pragma unroll
  for (int i = 0; i < 2; ++i)
#pragma unroll
    for (int j = 0; j < 4; ++j) {
      int n0 = w * 32 + i * 16 + g * 4;
      int p = j * 16 + (lane & 15);
#pragma unroll
      for (int r = 0; r < 4; ++r) sp[(long)(n0 + r) * HEADDIM + p] = acc[i][j][r];
    }
}

// ---------------- inter-chunk scan -> prev_states (bf16, [n][p]) ----------------
__global__ void k_scan(const float* __restrict__ states, const float* __restrict__ A_cum, unsigned short* __restrict__ psb) {
  long idx = (long)blockIdx.x * blockDim.x + threadIdx.x;
  if (idx >= (long)BATCH * NHEADS * D_STATE * HEADDIM) return;
  int p = idx & 63;
  int n = (int)((idx >> 6) & 127);
  long bh = idx >> 13;
  int h = (int)(bh & 63);
  int b = (int)(bh >> 6);
  float S = 0.f;
  for (int c = 0; c < NCHUNK; ++c) {
    long soff = (((long)(b * NCHUNK + c) * NHEADS + h) * (D_STATE * HEADDIM)) + (long)n * HEADDIM + p;
    psb[soff] = f2bf(S);
    float decay = expf(A_cum[(bh * NCHUNK + c) * CHUNK + 255]);
    S = S * decay + states[soff];
  }
}

// ---------------- Y = Y_diag + Y_off + x*D (bf16 out), MFMA ----------------
__global__ __launch_bounds__(256) void k_y(const unsigned short* __restrict__ xbc, const float* __restrict__ dt_t,
                                           const float* __restrict__ A_cum, const unsigned short* __restrict__ cbt_t,
                                           const unsigned short* __restrict__ psb, const float* __restrict__ Dp,
                                           unsigned short* __restrict__ y) {
  const int bid = blockIdx.x;
  const int h = bid & 63;
  const int bc = bid >> 6;
  const int b = bc >> 3, c = bc & 7;
  const int t = threadIdx.x;
  const int lane = t & 63;
  const int w = t >> 6;
  const int g = lane >> 4;
  __shared__ unsigned short Abuf[256][72];
  __shared__ unsigned short Bbuf[64][72];
  __shared__ float csL[256], dtL[256], expL[256];
  const long rowbase = (long)b * SEQ + c * CHUNK;
  const long bh8 = ((long)(b * NHEADS + h)) * NCHUNK + c;
  const float* acum = A_cum + bh8 * CHUNK;
  if (t < 256) {
    float cv = acum[t];
    csL[t] = cv;
    expL[t] = expf(cv);
    dtL[t] = dt_t[((size_t)(b * NHEADS + h)) * SEQ + c * CHUNK + t];
  }
  f32x4 acc[4][4];
#pragma unroll
  for (int i = 0; i < 4; ++i)
#pragma unroll
    for (int j = 0; j < 4; ++j) { f32x4 z = {0.f, 0.f, 0.f, 0.f}; acc[i][j] = z; }

  const unsigned short* psbase = psb + ((long)bc * NHEADS + h) * (D_STATE * HEADDIM);
  for (int np = 0; np < 2; ++np) {
    __syncthreads();
    for (int i = t; i < 256 * 16; i += 256) {
      int row = i >> 4, c4 = (i & 15) * 4;
      float el = expL[row];
      ushort4 v = *(const ushort4*)(xbc + (rowbase + row) * (long)CONV_DIM + D_INNER + D_STATE + np * 64 + c4);
      ushort4 o = make_ushort4(f2bf(bf2f(v.x) * el), f2bf(bf2f(v.y) * el), f2bf(bf2f(v.z) * el), f2bf(bf2f(v.w) * el));
      *(ushort4*)&Abuf[row][c4] = o;
    }
    for (int i = t; i < 64 * 16; i += 256) {
      int n = i >> 4, p4 = (i & 15) * 4;
      ushort4 v = *(const ushort4*)(psbase + (long)(np * 64 + n) * HEADDIM + p4);
      Bbuf[p4 + 0][n] = v.x; Bbuf[p4 + 1][n] = v.y; Bbuf[p4 + 2][n] = v.z; Bbuf[p4 + 3][n] = v.w;
    }
    __syncthreads();
#pragma unroll
    for (int ks = 0; ks < 2; ++ks) {
      const int kofs = ks * 32 + g * 8;
      bf16x8 af[4], bfr[4];
#pragma unroll
      for (int i = 0; i < 4; ++i) af[i] = *(const bf16x8*)&Abuf[w * 64 + i * 16 + (lane & 15)][kofs];
#pragma unroll
      for (int j = 0; j < 4; ++j) bfr[j] = *(const bf16x8*)&Bbuf[j * 16 + (lane & 15)][kofs];
#pragma unroll
      for (int i = 0; i < 4; ++i)
#pragma unroll
        for (int j = 0; j < 4; ++j)
          acc[i][j] = __builtin_amdgcn_mfma_f32_16x16x32_bf16(af[i], bfr[j], acc[i][j], 0, 0, 0);
    }
  }

  const unsigned short* cbtb = cbt_t + (long)bc * CHUNK * CHUNK;
  for (int sp = 0; sp < 4; ++sp) {
    __syncthreads();
    for (int i = t; i < 64 * 8; i += 256) {
      int s = i >> 3, p0 = (i & 7) * 8;
      u16x8 v = *(const u16x8*)(xbc + (rowbase + sp * 64 + s) * (long)CONV_DIM + h * HEADDIM + p0);
#pragma unroll
      for (int e = 0; e < 8; ++e) Bbuf[p0 + e][s] = v[e];
    }
    __syncthreads();
    if (sp > w) continue;
#pragma unroll
    for (int ks = 0; ks < 2; ++ks) {
      const int kofs = ks * 32 + g * 8;
      bf16x8 bfr[4];
#pragma unroll
      for (int j = 0; j < 4; ++j) bfr[j] = *(const bf16x8*)&Bbuf[j * 16 + (lane & 15)][kofs];
      const int sbase = sp * 64 + ks * 32 + g * 8;
#pragma unroll
      for (int i = 0; i < 4; ++i) {
        if (sp == w && ks * 32 > i * 16 + 15) continue;
        const int l = w * 64 + i * 16 + (lane & 15);
        u16x8 cv = *(const u16x8*)(cbtb + (long)l * CHUNK + sbase);
        const float cl = csL[l];
        bf16x8 af;
#pragma unroll
        for (int e = 0; e < 8; ++e) {
          int s = sbase + e;
          float val = (s <= l) ? bf2f(cv[e]) * expf(cl - csL[s]) * dtL[s] : 0.f;
          af[e] = (short)f2bf(val);
        }
#pragma unroll
        for (int j = 0; j < 4; ++j)
          acc[i][j] = __builtin_amdgcn_mfma_f32_16x16x32_bf16(af, bfr[j], acc[i][j], 0, 0, 0);
      }
    }
  }

  const float Dh = Dp[h];
#pragma unroll
  for (int i = 0; i < 4; ++i) {
    int l0 = w * 64 + i * 16 + g * 4;
#pragma unroll
    for (int r = 0; r < 4; ++r) {
      long grow = rowbase + l0 + r;
      const unsigned short* xrow = xbc + grow * (long)CONV_DIM + h * HEADDIM;
      unsigned short* yrow = y + grow * (long)D_INNER + h * HEADDIM;
#pragma unroll
      for (int j = 0; j < 4; ++j) {
        int p = j * 16 + (lane & 15);
        yrow[p] = f2bf(acc[i][j][r] + bf2f(xrow[p]) * Dh);
      }
    }
  }
}

// ---------------- gated RMSNorm ----------------
__global__ __launch_bounds__(256) void k_norm(unsigned short* yz, const unsigned short* __restrict__ zb,
                                              const float* __restrict__ norm_w, unsigned short* out) {
  const int row = blockIdx.x;
  const int t = threadIdx.x;
  const unsigned short* yr = yz + (size_t)row * D_INNER;
  const unsigned short* zr = zb + (size_t)row * D_INNER;
  float yv[16];
  float ss = 0.f;
#pragma unroll
  for (int j = 0; j < 4; ++j) {
    int e = (t + j * 256) * 4;
    ushort4 yy = *(const ushort4*)(yr + e);
    ushort4 zz = *(const ushort4*)(zr + e);
    float z0 = bf2f(zz.x), z1 = bf2f(zz.y), z2 = bf2f(zz.z), z3 = bf2f(zz.w);
    float g0 = bf2f(yy.x) * z0 / (1.f + expf(-z0));
    float g1 = bf2f(yy.y) * z1 / (1.f + expf(-z1));
    float g2 = bf2f(yy.z) * z2 / (1.f + expf(-z2));
    float g3 = bf2f(yy.w) * z3 / (1.f + expf(-z3));
    ss += g0 * g0 + g1 * g1 + g2 * g2 + g3 * g3;
    yv[j * 4 + 0] = g0; yv[j * 4 + 1] = g1; yv[j * 4 + 2] = g2; yv[j * 4 + 3] = g3;
  }
#pragma unroll
  for (int off = 32; off > 0; off >>= 1) ss += __shfl_xor(ss, off);
  __shared__ float red[4];
  if ((t & 63) == 0) red[t >> 6] = ss;
  __syncthreads();
  float tot = red[0] + red[1] + red[2] + red[3];
  float scale = rsqrtf(tot / (float)D_INNER + EPSV);
  unsigned short* orow = out + (size_t)row * D_INNER;
#pragma unroll
  for (int j = 0; j < 4; ++j) {
    int e = (t + j * 256) * 4;
    float4 w = *(const float4*)(norm_w + e);
    ushort4 o = make_ushort4(f2bf(yv[j * 4 + 0] * scale * w.x), f2bf(yv[j * 4 + 1] * scale * w.y),
                             f2bf(yv[j * 4 + 2] * scale * w.z), f2bf(yv[j * 4 + 3] * scale * w.w));
    *(ushort4*)(orow + e) = o;
  }
}

extern "C" void kernel_launch(void* const* d_in, const int* in_sizes, int n_in,
                              void* d_out, int out_size, void* d_ws, size_t ws_size,
                              hipStream_t stream) {
  const float* u       = (const float*)d_in[0];
  const float* W_in    = (const float*)d_in[1];
  const float* conv_w  = (const float*)d_in[2];
  const float* conv_b  = (const float*)d_in[3];
  const float* dt_bias = (const float*)d_in[4];
  const float* A_log   = (const float*)d_in[5];
  const float* Dp      = (const float*)d_in[6];
  const float* norm_w  = (const float*)d_in[7];
  const float* W_out   = (const float*)d_in[8];
  float* out = (float*)d_out;

  char* ws = (char*)d_ws;
  size_t off = 0;
  auto alloc = [&](size_t bytes) { char* p = ws + off; off += (bytes + 255) & ~(size_t)255; return p; };
  unsigned short* ub   = (unsigned short*)alloc((size_t)NROWS * D_MODEL * 2);
  unsigned short* winb = (unsigned short*)alloc((size_t)D_IN_PROJ * D_MODEL * 2);
  unsigned short* zb   = (unsigned short*)alloc((size_t)NROWS * D_INNER * 2);
  unsigned short* xb   = (unsigned short*)alloc((size_t)NROWS * CONV_DIM * 2);
  unsigned short* xbcb = (unsigned short*)alloc((size_t)NROWS * CONV_DIM * 2);
  float* dtt  = (float*)alloc((size_t)BATCH * NHEADS * SEQ * 4);
  float* acum = (float*)alloc((size_t)BATCH * NHEADS * NCHUNK * CHUNK * 4);
  unsigned short* cwT = (unsigned short*)alloc((size_t)4 * CONV_DIM * 2);
  unsigned short* cbT = (unsigned short*)alloc((size_t)CONV_DIM * 2);
  unsigned short* whl = (unsigned short*)alloc((size_t)128 * D_MODEL * 2);
  float* PD = (float*)alloc((size_t)4 * BATCH * NHEADS * SEQ * 4);   // dt split-K partials
  unsigned short* wob = ub;                     // W_out bf16, after GEMMs
  unsigned short* cbt = winb;                   // CBT^T bf16, after GEMMs
  unsigned short* psb = winb + (size_t)BATCH * NCHUNK * CHUNK * CHUNK + 1024;
  unsigned short* ulob = xbcb;                  // u residual bf16; dead before conv writes xbcb
  unsigned short* yb = xb;                      // y bf16, after conv
  float* states = (float*)d_out;

  if (off > ws_size) {
    k_sentinel<<<1, 64, 0, stream>>>(out);
    return;
  }

  k_usplit<<<2048, 256, 0, stream>>>(u, ub, ulob, (long)NROWS * D_MODEL / 4);
  k_f32_to_bf16_v4<<<2048, 256, 0, stream>>>(W_in, winb, (long)D_IN_PROJ * D_MODEL / 4);
  k_wpack<<<(64 * D_MODEL + 255) / 256, 256, 0, stream>>>(W_in, whl);
  k_conv_pack<<<(CONV_DIM + 255) / 256, 256, 0, stream>>>(conv_w, conv_b, cwT, cbT);
  k_gemm8p<<<(NROWS / 256) * (D_INNER / 256), 512, 0, stream>>>(ub, winb, zb, NROWS, D_INNER, D_MODEL);
  k_gemm128<1><<<(NROWS / 128) * (CONV_DIM / 128), 256, 0, stream>>>(ub, winb + (size_t)D_INNER * D_MODEL, xb, NROWS, CONV_DIM, D_MODEL);
  k_dtm<<<256, 256, 0, stream>>>(ub, ulob, whl, PD);
  k_dtred<<<BATCH * NHEADS, 256, 0, stream>>>(PD, dt_bias, A_log, dtt, acum);
  k_conv_silu<<<(int)(((long)(NROWS / 4) * CG + 255) / 256), 256, 0, stream>>>(xb, cwT, cbT, xbcb);
  k_cbtt<<<BATCH * NCHUNK * 4, 256, 0, stream>>>(xbcb, cbt);
  k_states<<<BATCH * NCHUNK * NHEADS, 256, 0, stream>>>(xbcb, dtt, acum, states);
  k_scan<<<(BATCH * NHEADS * D_STATE * HEADDIM + 255) / 256, 256, 0, stream>>>(states, acum, psb);
  k_y<<<BATCH * NCHUNK * NHEADS, 256, 0, stream>>>(xbcb, dtt, acum, cbt, psb, Dp, yb);
  k_norm<<<NROWS, 256, 0, stream>>>(yb, zb, norm_w, yb);
  k_f32_to_bf16_v4<<<2048, 256, 0, stream>>>(W_out, wob, (long)D_MODEL * D_INNER / 4);
  k_gemm128<0><<<(NROWS / 128) * (D_MODEL / 128), 256, 0, stream>>>(yb, wob, out, NROWS, D_MODEL, D_INNER);
}

// Round 10
// 478.477 us; speedup vs baseline: 2.2926x; 1.0447x over previous
//
#include <hip/hip_runtime.h>

#define D_MODEL   2048
#define D_INNER   4096
#define HEADDIM   64
#define NHEADS    64
#define D_STATE   128
#define CHUNK     256
#define CONV_DIM  4352
#define D_IN_PROJ 8512
#define BATCH     2
#define SEQ       2048
#define NCHUNK    8
#define NROWS     4096
#define EPSV      1e-5f
#define CG        (CONV_DIM / 8)   // 544

typedef __attribute__((ext_vector_type(8))) short bf16x8;
typedef __attribute__((ext_vector_type(8))) unsigned short u16x8;
typedef __attribute__((ext_vector_type(4))) float f32x4;

#define AS1 __attribute__((address_space(1)))
#define AS3 __attribute__((address_space(3)))

#define BAR() do { asm volatile("" ::: "memory"); __builtin_amdgcn_s_barrier(); asm volatile("" ::: "memory"); } while (0)

__device__ __forceinline__ unsigned short f2bf(float f) {
  unsigned int x = __float_as_uint(f);
  unsigned int r = (x + 0x7fffu + ((x >> 16) & 1u)) >> 16;
  return (unsigned short)r;
}
__device__ __forceinline__ float bf2f(unsigned short u) {
  return __uint_as_float((unsigned int)u << 16);
}

__global__ void k_sentinel(float* out) { if (threadIdx.x == 0) out[0] = 1.0e6f; }

// ---------------- fused prep: usplit | W_in convert | wpack | conv pack ----------------
__global__ void k_prep(const float* __restrict__ u, unsigned short* __restrict__ uhi, unsigned short* __restrict__ ulo,
                       const float* __restrict__ W, unsigned short* __restrict__ winb, unsigned short* __restrict__ whl,
                       const float* __restrict__ cw, const float* __restrict__ cb,
                       unsigned short* __restrict__ cwT, unsigned short* __restrict__ cbT) {
  const int b = blockIdx.x;
  const int t = threadIdx.x;
  if (b < 2048) {                                   // u -> hi+lo split (f32x4)
    const long n4 = (long)NROWS * D_MODEL / 4;
    for (long i = (long)b * 256 + t; i < n4; i += 2048L * 256) {
      float4 v = ((const float4*)u)[i];
      ushort4 h, l;
      h.x = f2bf(v.x); l.x = f2bf(v.x - bf2f(h.x));
      h.y = f2bf(v.y); l.y = f2bf(v.y - bf2f(h.y));
      h.z = f2bf(v.z); l.z = f2bf(v.z - bf2f(h.z));
      h.w = f2bf(v.w); l.w = f2bf(v.w - bf2f(h.w));
      ((ushort4*)uhi)[i] = h;
      ((ushort4*)ulo)[i] = l;
    }
  } else if (b < 6144) {                            // W_in -> bf16
    const long n4 = (long)D_IN_PROJ * D_MODEL / 4;
    for (long i = (long)(b - 2048) * 256 + t; i < n4; i += 4096L * 256) {
      float4 v = ((const float4*)W)[i];
      ushort4 o = make_ushort4(f2bf(v.x), f2bf(v.y), f2bf(v.z), f2bf(v.w));
      ((ushort4*)winb)[i] = o;
    }
  } else if (b < 6656) {                            // dt-row W split hi/lo
    long i = (long)(b - 6144) * 256 + t;
    float v = W[(size_t)8448 * D_MODEL + i];
    unsigned short h = f2bf(v);
    whl[i] = h;
    whl[(size_t)64 * D_MODEL + i] = f2bf(v - bf2f(h));
  } else {                                          // conv weight/bias pack
    int i = (b - 6656) * 256 + t;
    if (i < CONV_DIM) {
#pragma unroll
      for (int w = 0; w < 4; ++w) cwT[w * CONV_DIM + i] = f2bf(cw[i * 4 + w]);
      cbT[i] = f2bf(cb[i]);
    }
  }
}

// ---------------- W_out convert ----------------
__global__ void k_f32_to_bf16_v4(const float* __restrict__ in, unsigned short* __restrict__ out, long n4) {
  long i = (long)blockIdx.x * blockDim.x + threadIdx.x;
  long stride = (long)gridDim.x * blockDim.x;
  for (; i < n4; i += stride) {
    float4 v = ((const float4*)in)[i];
    ushort4 o = make_ushort4(f2bf(v.x), f2bf(v.y), f2bf(v.z), f2bf(v.w));
    ((ushort4*)out)[i] = o;
  }
}

// ---- dt split-bf16 MFMA, SPLIT-K=4: raw partial sums -> PD[ks][bh][l] (f32) ----
__global__ __launch_bounds__(256, 2) void k_dtm(const unsigned short* __restrict__ uhi,
                                                const unsigned short* __restrict__ ulo,
                                                const unsigned short* __restrict__ whl,
                                                float* __restrict__ PD) {
  __shared__ __align__(16) short lds[2][256 * 64];
  const int t = threadIdx.x;
  const int lane = t & 63;
  const int w = t >> 6;
  const int ks = (int)blockIdx.x & 3;
  const int m0 = ((int)blockIdx.x >> 2) * 64;
  const int kbase = ks * 512;

  f32x4 acc1[8], acc2[4];
#pragma unroll
  for (int j = 0; j < 8; ++j) { f32x4 z = {0.f, 0.f, 0.f, 0.f}; acc1[j] = z; }
#pragma unroll
  for (int j = 0; j < 4; ++j) { f32x4 z = {0.f, 0.f, 0.f, 0.f}; acc2[j] = z; }

  const int srow = t >> 3;
  const int schunk = (t & 7) ^ (srow & 7);
  const unsigned short* gU = uhi + (size_t)(m0 + srow) * D_MODEL + kbase + schunk * 8;
  const unsigned short* gL = ulo + (size_t)(m0 + srow) * D_MODEL + kbase + schunk * 8;
  const unsigned short* gW = whl + (size_t)srow * D_MODEL + kbase + schunk * 8;

  auto STAGE = [&](int buf, int kt) {
    char* d = (char*)&lds[buf][0] + t * 16;
#pragma unroll
    for (int ii = 0; ii < 2; ++ii)
      __builtin_amdgcn_global_load_lds((const AS1 void*)(gU + (size_t)ii * 32 * D_MODEL + (size_t)kt * 64),
                                       (AS3 void*)(d + ii * 4096), 16, 0, 0);
#pragma unroll
    for (int ii = 0; ii < 2; ++ii)
      __builtin_amdgcn_global_load_lds((const AS1 void*)(gL + (size_t)ii * 32 * D_MODEL + (size_t)kt * 64),
                                       (AS3 void*)(d + 8192 + ii * 4096), 16, 0, 0);
#pragma unroll
    for (int ii = 0; ii < 4; ++ii)
      __builtin_amdgcn_global_load_lds((const AS1 void*)(gW + (size_t)ii * 32 * D_MODEL + (size_t)kt * 64),
                                       (AS3 void*)(d + 16384 + ii * 4096), 16, 0, 0);
  };

  STAGE(0, 0);

  const int NT = 512 / 64;
  const int ar = w * 16 + (lane & 15);
  const int kof = (lane >> 4) * 8;
  const int rsw = (lane & 7) * 8;
  int cur = 0;
  for (int kt = 0; kt < NT; ++kt) {
    if (kt + 1 < NT) {
      STAGE(cur ^ 1, kt + 1);
      asm volatile("s_waitcnt vmcnt(8)" ::: "memory");
    } else {
      asm volatile("s_waitcnt vmcnt(0)" ::: "memory");
    }
    __builtin_amdgcn_s_barrier();
    asm volatile("" ::: "memory");
    const short* L = &lds[cur][0];
#pragma unroll
    for (int kk = 0; kk < 2; ++kk) {
      const int off = (kk * 32 + kof) ^ rsw;
      bf16x8 ah = *(const bf16x8*)(L + ar * 64 + off);
      bf16x8 al = *(const bf16x8*)(L + (64 + ar) * 64 + off);
#pragma unroll
      for (int j = 0; j < 8; ++j) {
        bf16x8 bj = *(const bf16x8*)(L + (128 + j * 16 + (lane & 15)) * 64 + off);
        acc1[j] = __builtin_amdgcn_mfma_f32_16x16x32_bf16(ah, bj, acc1[j], 0, 0, 0);
        if (j < 4) acc2[j] = __builtin_amdgcn_mfma_f32_16x16x32_bf16(al, bj, acc2[j], 0, 0, 0);
      }
    }
    asm volatile("" ::: "memory");
    __builtin_amdgcn_s_barrier();
    asm volatile("" ::: "memory");
    cur ^= 1;
  }

  const int crow = (lane >> 4) * 4;
  float* P = PD + (size_t)ks * BATCH * NHEADS * SEQ;
#pragma unroll
  for (int j = 0; j < 4; ++j) {
    int h = j * 16 + (lane & 15);
#pragma unroll
    for (int r = 0; r < 4; ++r) {
      int row = m0 + w * 16 + crow + r;
      float v = acc1[j][r] + acc1[j + 4][r] + acc2[j][r];
      P[(size_t)((row >> 11) * NHEADS + h) * SEQ + (row & 2047)] = v;
    }
  }
}

// ---- dt reduce (+bias, softplus) -> dtt; fused per-chunk cumsum of dA -> acum ----
__global__ __launch_bounds__(256) void k_dtred(const float* __restrict__ PD, const float* __restrict__ dt_bias,
                                               const float* __restrict__ A_log,
                                               float* __restrict__ dt_t, float* __restrict__ A_cum) {
  const int bh = blockIdx.x;
  const int h = bh & 63;
  const int t = threadIdx.x;
  const float bias = dt_bias[h];
  const float A = -expf(A_log[h]);
  const size_t base = (size_t)bh * SEQ;
  const size_t pstride = (size_t)BATCH * NHEADS * SEQ;
  __shared__ float s[256];
  for (int c = 0; c < NCHUNK; ++c) {
    int l = c * CHUNK + t;
    float v = PD[base + l] + PD[pstride + base + l] + PD[2 * pstride + base + l] + PD[3 * pstride + base + l] + bias;
    float dtv = (v > 20.f) ? v : log1pf(expf(v));
    dt_t[base + l] = dtv;
    s[t] = dtv * A;
    __syncthreads();
    for (int off = 1; off < 256; off <<= 1) {
      float x = (t >= off) ? s[t - off] : 0.f;
      __syncthreads();
      s[t] += x;
      __syncthreads();
    }
    A_cum[((size_t)bh * NCHUNK + c) * CHUNK + t] = s[t];
    __syncthreads();
  }
}

// ---- 256x256 BK=64 8-phase GEMM (T2+T3+T4+T5), grouped-raster XCD swizzle ----
__global__ __launch_bounds__(512, 2) void k_gemm8p(const unsigned short* __restrict__ A,
                                                   const unsigned short* __restrict__ B,
                                                   unsigned short* __restrict__ C, int M, int N, int K) {
  __shared__ __align__(16) short lds[2][32768];
  const int t = threadIdx.x;
  const int lane = t & 63;
  const int wid = t >> 6;
  const int wr = wid >> 2;
  const int wc = wid & 3;
  const int ntx = N / 256;
  const int nwg = (int)gridDim.x;
  const int bid = (int)blockIdx.x;
  const int swz = (bid & 7) * (nwg >> 3) + (bid >> 3);
  const int grp = ntx << 3;            // requires nwg % grp == 0
  const int gid = swz / grp;
  const int rem = swz - gid * grp;
  const int m0 = ((gid << 3) + (rem & 7)) * 256;
  const int n0 = (rem >> 3) * 256;

  f32x4 acc[8][4];
#pragma unroll
  for (int i = 0; i < 8; ++i)
#pragma unroll
    for (int j = 0; j < 4; ++j) { f32x4 z = {0.f, 0.f, 0.f, 0.f}; acc[i][j] = z; }

  const int srow = t >> 3;
  const int schunk = (t & 7) ^ (srow & 7);
  const unsigned short* gA = A + (size_t)(m0 + srow) * K + schunk * 8;
  const unsigned short* gB = B + (size_t)(n0 + srow) * K + schunk * 8;

  auto STAGE_HALF = [&](int buf, int kt, int which) {
    const unsigned short* g = (which < 2 ? gA : gB) + (size_t)(which & 1) * 128 * K + (size_t)kt * 64;
    char* d = (char*)lds + buf * 65536 + which * 16384 + t * 16;
    __builtin_amdgcn_global_load_lds((const AS1 void*)g, (AS3 void*)d, 16, 0, 0);
    __builtin_amdgcn_global_load_lds((const AS1 void*)(g + (size_t)64 * K), (AS3 void*)(d + 8192), 16, 0, 0);
  };

  const int NT = K / 64;
  STAGE_HALF(0, 0, 0); STAGE_HALF(0, 0, 1); STAGE_HALF(0, 0, 2); STAGE_HALF(0, 0, 3);
  STAGE_HALF(1, 1, 2); STAGE_HALF(1, 1, 0); STAGE_HALF(1, 1, 1);
  asm volatile("s_waitcnt vmcnt(6)" ::: "memory");
  BAR();

  const int ar = wr * 128 + (lane & 15);
  const int br = wc * 64 + (lane & 15);
  const int kof = (lane >> 4) * 8;
  const int rsw = (lane & 7) * 8;

  for (int kt = 0; kt < NT; ++kt) {
    const int buf = kt & 1;
    const short* As = &lds[buf][0];
    const short* Bs = &lds[buf][16384];
    const bool s1 = (kt + 1 < NT);
    const bool s2 = (kt + 2 < NT);
    bf16x8 aLo[4][2], aHi[4][2], bLo[2][2], bHi[2][2];

#pragma unroll
    for (int i = 0; i < 4; ++i)
#pragma unroll
      for (int k = 0; k < 2; ++k) aLo[i][k] = *(const bf16x8*)(As + (ar + i * 16) * 64 + ((k * 32 + kof) ^ rsw));
#pragma unroll
    for (int j = 0; j < 2; ++j)
#pragma unroll
      for (int k = 0; k < 2; ++k) bLo[j][k] = *(const bf16x8*)(Bs + (br + j * 16) * 64 + ((k * 32 + kof) ^ rsw));
    if (s1) STAGE_HALF(buf ^ 1, kt + 1, 3);
    BAR();
    __builtin_amdgcn_s_setprio(1);
#pragma unroll
    for (int k = 0; k < 2; ++k)
#pragma unroll
      for (int i = 0; i < 4; ++i)
#pragma unroll
        for (int j = 0; j < 2; ++j)
          acc[i][j] = __builtin_amdgcn_mfma_f32_16x16x32_bf16(aLo[i][k], bLo[j][k], acc[i][j], 0, 0, 0);
    __builtin_amdgcn_s_setprio(0);
    BAR();

#pragma unroll
    for (int j = 0; j < 2; ++j)
#pragma unroll
      for (int k = 0; k < 2; ++k) bHi[j][k] = *(const bf16x8*)(Bs + (br + (j + 2) * 16) * 64 + ((k * 32 + kof) ^ rsw));
    BAR();
    __builtin_amdgcn_s_setprio(1);
#pragma unroll
    for (int k = 0; k < 2; ++k)
#pragma unroll
      for (int i = 0; i < 4; ++i)
#pragma unroll
        for (int j = 0; j < 2; ++j)
          acc[i][j + 2] = __builtin_amdgcn_mfma_f32_16x16x32_bf16(aLo[i][k], bHi[j][k], acc[i][j + 2], 0, 0, 0);
    __builtin_amdgcn_s_setprio(0);
    BAR();

#pragma unroll
    for (int i = 0; i < 4; ++i)
#pragma unroll
      for (int k = 0; k < 2; ++k) aHi[i][k] = *(const bf16x8*)(As + (ar + (i + 4) * 16) * 64 + ((k * 32 + kof) ^ rsw));
    if (s2) STAGE_HALF(buf, kt + 2, 2);
    BAR();
    __builtin_amdgcn_s_setprio(1);
#pragma unroll
    for (int k = 0; k < 2; ++k)
#pragma unroll
      for (int i = 0; i < 4; ++i)
#pragma unroll
        for (int j = 0; j < 2; ++j)
          acc[i + 4][j] = __builtin_amdgcn_mfma_f32_16x16x32_bf16(aHi[i][k], bLo[j][k], acc[i + 4][j], 0, 0, 0);
    __builtin_amdgcn_s_setprio(0);
    BAR();

    if (s2) { STAGE_HALF(buf, kt + 2, 0); STAGE_HALF(buf, kt + 2, 1); }
    if (s2) { asm volatile("s_waitcnt vmcnt(6)" ::: "memory"); }
    else    { asm volatile("s_waitcnt vmcnt(0)" ::: "memory"); }
    BAR();
    __builtin_amdgcn_s_setprio(1);
#pragma unroll
    for (int k = 0; k < 2; ++k)
#pragma unroll
      for (int i = 0; i < 4; ++i)
#pragma unroll
        for (int j = 0; j < 2; ++j)
          acc[i + 4][j + 2] = __builtin_amdgcn_mfma_f32_16x16x32_bf16(aHi[i][k], bHi[j][k], acc[i + 4][j + 2], 0, 0, 0);
    __builtin_amdgcn_s_setprio(0);
    BAR();
  }

  const int crow = (lane >> 4) * 4;
  const int ccol = lane & 15;
#pragma unroll
  for (int i = 0; i < 8; ++i)
#pragma unroll
    for (int j = 0; j < 4; ++j) {
      size_t base = (size_t)(m0 + wr * 128 + i * 16 + crow) * N + (n0 + wc * 64 + j * 16 + ccol);
#pragma unroll
      for (int r = 0; r < 4; ++r) C[base + (size_t)r * N] = f2bf(acc[i][j][r]);
    }
}

// ---- 128x128 BK=64 double-buffered GEMM, grouped-raster XCD swizzle ----
template <int BF16OUT>
__global__ __launch_bounds__(256, 2) void k_gemm128(const unsigned short* __restrict__ A,
                                                    const unsigned short* __restrict__ B,
                                                    void* __restrict__ Cv, int M, int N, int K) {
  constexpr int BK = 64;
  __shared__ __align__(16) short lds[2][256 * BK];
  const int t = threadIdx.x;
  const int lane = t & 63;
  const int wid = t >> 6;
  const int wr = wid >> 1;
  const int wc = wid & 1;
  const int ntx = N / 128;
  const int nwg = (int)gridDim.x;
  const int bid = (int)blockIdx.x;
  const int swz = (bid & 7) * (nwg >> 3) + (bid >> 3);
  const int grp = ntx << 3;            // requires nwg % grp == 0
  const int gid = swz / grp;
  const int rem = swz - gid * grp;
  const int m0 = ((gid << 3) + (rem & 7)) * 128;
  const int n0 = (rem >> 3) * 128;

  f32x4 acc[4][4];
#pragma unroll
  for (int i = 0; i < 4; ++i)
#pragma unroll
    for (int j = 0; j < 4; ++j) { f32x4 z = {0.f, 0.f, 0.f, 0.f}; acc[i][j] = z; }

  const int srow = t >> 3;
  const int schunk = (t & 7) ^ (srow & 7);
  const unsigned short* gA = A + (size_t)(m0 + srow) * K + schunk * 8;
  const unsigned short* gB = B + (size_t)(n0 + srow) * K + schunk * 8;

  auto STAGE = [&](int buf, int kt) {
    char* dA = (char*)&lds[buf][0] + t * 16;
    char* dB = (char*)&lds[buf][128 * BK] + t * 16;
#pragma unroll
    for (int ii = 0; ii < 4; ++ii)
      __builtin_amdgcn_global_load_lds((const AS1 void*)(gA + (size_t)ii * 32 * K + kt * BK),
                                       (AS3 void*)(dA + ii * 4096), 16, 0, 0);
#pragma unroll
    for (int ii = 0; ii < 4; ++ii)
      __builtin_amdgcn_global_load_lds((const AS1 void*)(gB + (size_t)ii * 32 * K + kt * BK),
                                       (AS3 void*)(dB + ii * 4096), 16, 0, 0);
  };

  STAGE(0, 0);

  const int NT = K / BK;
  const int ar = wr * 64 + (lane & 15);
  const int br = wc * 64 + (lane & 15);
  const int kof = (lane >> 4) * 8;
  const int rsw = (lane & 7) * 8;
  int cur = 0;
  for (int kt = 0; kt < NT; ++kt) {
    if (kt + 1 < NT) {
      STAGE(cur ^ 1, kt + 1);
      asm volatile("s_waitcnt vmcnt(8)" ::: "memory");
    } else {
      asm volatile("s_waitcnt vmcnt(0)" ::: "memory");
    }
    __builtin_amdgcn_s_barrier();
    asm volatile("" ::: "memory");
    const short* As = &lds[cur][0];
    const short* Bs = &lds[cur][128 * BK];
#pragma unroll
    for (int kk = 0; kk < 2; ++kk) {
      bf16x8 bfr[4];
#pragma unroll
      for (int j = 0; j < 4; ++j)
        bfr[j] = *(const bf16x8*)(Bs + (br + j * 16) * BK + ((kk * 32 + kof) ^ rsw));
#pragma unroll
      for (int i = 0; i < 4; ++i) {
        bf16x8 af = *(const bf16x8*)(As + (ar + i * 16) * BK + ((kk * 32 + kof) ^ rsw));
#pragma unroll
        for (int j = 0; j < 4; ++j)
          acc[i][j] = __builtin_amdgcn_mfma_f32_16x16x32_bf16(af, bfr[j], acc[i][j], 0, 0, 0);
      }
    }
    asm volatile("" ::: "memory");
    __builtin_amdgcn_s_barrier();
    asm volatile("" ::: "memory");
    cur ^= 1;
  }

  const int crow = (lane >> 4) * 4;
  const int ccol = lane & 15;
#pragma unroll
  for (int i = 0; i < 4; ++i)
#pragma unroll
    for (int j = 0; j < 4; ++j) {
      size_t base = (size_t)(m0 + wr * 64 + i * 16 + crow) * N + (n0 + wc * 64 + j * 16 + ccol);
      if (BF16OUT) {
        unsigned short* C = (unsigned short*)Cv;
#pragma unroll
        for (int r = 0; r < 4; ++r) C[base + (size_t)r * N] = f2bf(acc[i][j][r]);
      } else {
        float* C = (float*)Cv;
#pragma unroll
        for (int r = 0; r < 4; ++r) C[base + (size_t)r * N] = acc[i][j][r];
      }
    }
}

// ---------------- conv1d + silu ----------------
__global__ __launch_bounds__(256) void k_conv_silu(const unsigned short* __restrict__ xb,
                                                   const unsigned short* __restrict__ wT,
                                                   const unsigned short* __restrict__ bT,
                                                   unsigned short* __restrict__ out) {
  long idx = (long)blockIdx.x * blockDim.x + threadIdx.x;
  if (idx >= (long)(NROWS / 4) * CG) return;
  int c8 = (int)(idx % CG);
  long rq = idx / CG;
  int l0 = (int)((rq & (SEQ / 4 - 1)) * 4);
  long brow = (rq >> 9) * (long)SEQ;
  int ch0 = c8 * 8;

  u16x8 wv[4];
#pragma unroll
  for (int w = 0; w < 4; ++w) wv[w] = *(const u16x8*)(wT + w * CONV_DIM + ch0);
  u16x8 bv = *(const u16x8*)(bT + ch0);

  u16x8 xr[7];
#pragma unroll
  for (int i = 0; i < 7; ++i) {
    int ls = l0 - 3 + i;
    if (ls >= 0) xr[i] = *(const u16x8*)(xb + (brow + ls) * (long)CONV_DIM + ch0);
    else { u16x8 z = {0, 0, 0, 0, 0, 0, 0, 0}; xr[i] = z; }
  }

#pragma unroll
  for (int r = 0; r < 4; ++r) {
    float acc[8];
#pragma unroll
    for (int e = 0; e < 8; ++e) acc[e] = bf2f(bv[e]);
#pragma unroll
    for (int w = 0; w < 4; ++w)
#pragma unroll
      for (int e = 0; e < 8; ++e) acc[e] += bf2f(xr[r + w][e]) * bf2f(wv[w][e]);
    u16x8 o;
#pragma unroll
    for (int e = 0; e < 8; ++e) o[e] = f2bf(acc[e] / (1.f + expf(-acc[e])));
    *(u16x8*)(out + (brow + l0 + r) * (long)CONV_DIM + ch0) = o;
  }
}

// ---------------- CBT^T[l][s] = C_l . B_s  (bf16 out), MFMA ----------------
__global__ __launch_bounds__(256) void k_cbtt(const unsigned short* __restrict__ xbc, unsigned short* __restrict__ cbt_t) {
  const int bid = blockIdx.x;
  const int sp = bid & 3;
  const int bc = bid >> 2;
  const int b = bc >> 3, c = bc & 7;
  const int t = threadIdx.x;
  const int lane = t & 63;
  const int w = t >> 6;
  const int g = lane >> 4;
  __shared__ unsigned short Cs[256][72];
  __shared__ unsigned short Bs2[64][72];
  const long rowbase = (long)b * SEQ + c * CHUNK;
  f32x4 acc[4][4];
#pragma unroll
  for (int i = 0; i < 4; ++i)
#pragma unroll
    for (int j = 0; j < 4; ++j) { f32x4 z = {0.f, 0.f, 0.f, 0.f}; acc[i][j] = z; }

  for (int np = 0; np < 2; ++np) {
    __syncthreads();
    for (int i = t; i < 256 * 16; i += 256) {
      int row = i >> 4, c4 = (i & 15) * 4;
      ushort4 v = *(const ushort4*)(xbc + (rowbase + row) * (long)CONV_DIM + D_INNER + D_STATE + np * 64 + c4);
      *(ushort4*)&Cs[row][c4] = v;
    }
    for (int i = t; i < 64 * 16; i += 256) {
      int row = i >> 4, c4 = (i & 15) * 4;
      ushort4 v = *(const ushort4*)(xbc + (rowbase + sp * 64 + row) * (long)CONV_DIM + D_INNER + np * 64 + c4);
      *(ushort4*)&Bs2[row][c4] = v;
    }
    __syncthreads();
#pragma unroll
    for (int ks = 0; ks < 2; ++ks) {
      const int kofs = ks * 32 + g * 8;
      bf16x8 af[4], bfr[4];
#pragma unroll
      for (int i = 0; i < 4; ++i) af[i] = *(const bf16x8*)&Cs[w * 64 + i * 16 + (lane & 15)][kofs];
#pragma unroll
      for (int j = 0; j < 4; ++j) bfr[j] = *(const bf16x8*)&Bs2[j * 16 + (lane & 15)][kofs];
#pragma unroll
      for (int i = 0; i < 4; ++i)
#pragma unroll
        for (int j = 0; j < 4; ++j)
          acc[i][j] = __builtin_amdgcn_mfma_f32_16x16x32_bf16(af[i], bfr[j], acc[i][j], 0, 0, 0);
    }
  }
  unsigned short* ob = cbt_t + (long)bc * CHUNK * CHUNK;
#pragma unroll
  for (int i = 0; i < 4; ++i)
#pragma unroll
    for (int j = 0; j < 4; ++j) {
      int l0 = w * 64 + i * 16 + g * 4;
      int s = sp * 64 + j * 16 + (lane & 15);
#pragma unroll
      for (int r = 0; r < 4; ++r) ob[(long)(l0 + r) * CHUNK + s] = f2bf(acc[i][j][r]);
    }
}

// ---------------- states[n][p] = sum_l B[l][n]*w_l*x[l][p], MFMA ----------------
__global__ __launch_bounds__(256) void k_states(const unsigned short* __restrict__ xbc, const float* __restrict__ dt_t,
                                                const float* __restrict__ A_cum, float* __restrict__ states) {
  const int bid = blockIdx.x;
  const int h = bid & 63;
  const int bc = bid >> 6;
  const int b = bc >> 3, c = bc & 7;
  const int t = threadIdx.x;
  const int lane = t & 63;
  const int w = t >> 6;
  const int g = lane >> 4;
  __shared__ unsigned short BT[128][72];
  __shared__ unsigned short WXT[64][72];
  __shared__ float csL[256], dtL[256];
  const long rowbase = (long)b * SEQ + c * CHUNK;
  const long bh8 = ((long)(b * NHEADS + h)) * NCHUNK + c;
  const float* acum = A_cum + bh8 * CHUNK;
  if (t < 256) { csL[t] = acum[t]; dtL[t] = dt_t[((size_t)(b * NHEADS + h)) * SEQ + c * CHUNK + t]; }
  float cs_last = acum[255];
  f32x4 acc[2][4];
#pragma unroll
  for (int i = 0; i < 2; ++i)
#pragma unroll
    for (int j = 0; j < 4; ++j) { f32x4 z = {0.f, 0.f, 0.f, 0.f}; acc[i][j] = z; }

  for (int lp = 0; lp < 4; ++lp) {
    __syncthreads();
    for (int i = t; i < 64 * 32; i += 256) {
      int l = i >> 5, n4 = (i & 31) * 4;
      ushort4 v = *(const ushort4*)(xbc + (rowbase + lp * 64 + l) * (long)CONV_DIM + D_INNER + n4);
      BT[n4 + 0][l] = v.x; BT[n4 + 1][l] = v.y; BT[n4 + 2][l] = v.z; BT[n4 + 3][l] = v.w;
    }
    for (int i = t; i < 64 * 16; i += 256) {
      int l = i >> 4, p4 = (i & 15) * 4;
      int lg = lp * 64 + l;
      float wgt = expf(cs_last - csL[lg]) * dtL[lg];
      ushort4 v = *(const ushort4*)(xbc + (rowbase + lg) * (long)CONV_DIM + h * HEADDIM + p4);
      WXT[p4 + 0][l] = f2bf(bf2f(v.x) * wgt);
      WXT[p4 + 1][l] = f2bf(bf2f(v.y) * wgt);
      WXT[p4 + 2][l] = f2bf(bf2f(v.z) * wgt);
      WXT[p4 + 3][l] = f2bf(bf2f(v.w) * wgt);
    }
    __syncthreads();
#pragma unroll
    for (int ks = 0; ks < 2; ++ks) {
      const int kofs = ks * 32 + g * 8;
      bf16x8 am[2], bp[4];
#pragma unroll
      for (int i = 0; i < 2; ++i) am[i] = *(const bf16x8*)&BT[w * 32 + i * 16 + (lane & 15)][kofs];
#pragma unroll
      for (int j = 0; j < 4; ++j) bp[j] = *(const bf16x8*)&WXT[j * 16 + (lane & 15)][kofs];
#pragma unroll
      for (int i = 0; i < 2; ++i)
#pragma unroll
        for (int j = 0; j < 4; ++j)
          acc[i][j] = __builtin_amdgcn_mfma_f32_16x16x32_bf16(am[i], bp[j], acc[i][j], 0, 0, 0);
    }
  }
  float* sp = states + ((long)bc * NHEADS + h) * (D_STATE * HEADDIM);
#pragma unroll
  for (int i = 0; i < 2; ++i)
#pragma unroll
    for (int j = 0; j < 4; ++j) {
      int n0 = w * 32 + i * 16 + g * 4;
      int p = j * 16 + (lane & 15);
#pragma unroll
      for (int r = 0; r < 4; ++r) sp[(long)(n0 + r) * HEADDIM + p] = acc[i][j][r];
    }
}

// ---------------- inter-chunk scan -> prev_states (bf16, [n][p]) ----------------
__global__ void k_scan(const float* __restrict__ states, const float* __restrict__ A_cum, unsigned short* __restrict__ psb) {
  long idx = (long)blockIdx.x * blockDim.x + threadIdx.x;
  if (idx >= (long)BATCH * NHEADS * D_STATE * HEADDIM) return;
  int p = idx & 63;
  int n = (int)((idx >> 6) & 127);
  long bh = idx >> 13;
  int h = (int)(bh & 63);
  int b = (int)(bh >> 6);
  float S = 0.f;
  for (int c = 0; c < NCHUNK; ++c) {
    long soff = (((long)(b * NCHUNK + c) * NHEADS + h) * (D_STATE * HEADDIM)) + (long)n * HEADDIM + p;
    psb[soff] = f2bf(S);
    float decay = expf(A_cum[(bh * NCHUNK + c) * CHUNK + 255]);
    S = S * decay + states[soff];
  }
}

// ---------------- Y = Y_diag + Y_off + x*D (bf16 out), MFMA ----------------
__global__ __launch_bounds__(256) void k_y(const unsigned short* __restrict__ xbc, const float* __restrict__ dt_t,
                                           const float* __restrict__ A_cum, const unsigned short* __restrict__ cbt_t,
                                           const unsigned short* __restrict__ psb, const float* __restrict__ Dp,
                                           unsigned short* __restrict__ y) {
  const int bid = blockIdx.x;
  const int h = bid & 63;
  const int bc = bid >> 6;
  const int b = bc >> 3, c = bc & 7;
  const int t = threadIdx.x;
  const int lane = t & 63;
  const int w = t >> 6;
  const int g = lane >> 4;
  __shared__ unsigned short Abuf[256][72];
  __shared__ unsigned short Bbuf[64][72];
  __shared__ float csL[256], dtL[256], expL[256];
  const long rowbase = (long)b * SEQ + c * CHUNK;
  const long bh8 = ((long)(b * NHEADS + h)) * NCHUNK + c;
  const float* acum = A_cum + bh8 * CHUNK;
  if (t < 256) {
    float cv = acum[t];
    csL[t] = cv;
    expL[t] = expf(cv);
    dtL[t] = dt_t[((size_t)(b * NHEADS + h)) * SEQ + c * CHUNK + t];
  }
  f32x4 acc[4][4];
#pragma unroll
  for (int i = 0; i < 4; ++i)
#pragma unroll
    for (int j = 0; j < 4; ++j) { f32x4 z = {0.f, 0.f, 0.f, 0.f}; acc[i][j] = z; }

  const unsigned short* psbase = psb + ((long)bc * NHEADS + h) * (D_STATE * HEADDIM);
  for (int np = 0; np < 2; ++np) {
    __syncthreads();
    for (int i = t; i < 256 * 16; i += 256) {
      int row = i >> 4, c4 = (i & 15) * 4;
      float el = expL[row];
      ushort4 v = *(const ushort4*)(xbc + (rowbase + row) * (long)CONV_DIM + D_INNER + D_STATE + np * 64 + c4);
      ushort4 o = make_ushort4(f2bf(bf2f(v.x) * el), f2bf(bf2f(v.y) * el), f2bf(bf2f(v.z) * el), f2bf(bf2f(v.w) * el));
      *(ushort4*)&Abuf[row][c4] = o;
    }
    for (int i = t; i < 64 * 16; i += 256) {
      int n = i >> 4, p4 = (i & 15) * 4;
      ushort4 v = *(const ushort4*)(psbase + (long)(np * 64 + n) * HEADDIM + p4);
      Bbuf[p4 + 0][n] = v.x; Bbuf[p4 + 1][n] = v.y; Bbuf[p4 + 2][n] = v.z; Bbuf[p4 + 3][n] = v.w;
    }
    __syncthreads();
#pragma unroll
    for (int ks = 0; ks < 2; ++ks) {
      const int kofs = ks * 32 + g * 8;
      bf16x8 af[4], bfr[4];
#pragma unroll
      for (int i = 0; i < 4; ++i) af[i] = *(const bf16x8*)&Abuf[w * 64 + i * 16 + (lane & 15)][kofs];
#pragma unroll
      for (int j = 0; j < 4; ++j) bfr[j] = *(const bf16x8*)&Bbuf[j * 16 + (lane & 15)][kofs];
#pragma unroll
      for (int i = 0; i < 4; ++i)
#pragma unroll
        for (int j = 0; j < 4; ++j)
          acc[i][j] = __builtin_amdgcn_mfma_f32_16x16x32_bf16(af[i], bfr[j], acc[i][j], 0, 0, 0);
    }
  }

  const unsigned short* cbtb = cbt_t + (long)bc * CHUNK * CHUNK;
  for (int sp = 0; sp < 4; ++sp) {
    __syncthreads();
    for (int i = t; i < 64 * 8; i += 256) {
      int s = i >> 3, p0 = (i & 7) * 8;
      u16x8 v = *(const u16x8*)(xbc + (rowbase + sp * 64 + s) * (long)CONV_DIM + h * HEADDIM + p0);
#pragma unroll
      for (int e = 0; e < 8; ++e) Bbuf[p0 + e][s] = v[e];
    }
    __syncthreads();
    if (sp > w) continue;
#pragma unroll
    for (int ks = 0; ks < 2; ++ks) {
      const int kofs = ks * 32 + g * 8;
      bf16x8 bfr[4];
#pragma unroll
      for (int j = 0; j < 4; ++j) bfr[j] = *(const bf16x8*)&Bbuf[j * 16 + (lane & 15)][kofs];
      const int sbase = sp * 64 + ks * 32 + g * 8;
#pragma unroll
      for (int i = 0; i < 4; ++i) {
        if (sp == w && ks * 32 > i * 16 + 15) continue;
        const int l = w * 64 + i * 16 + (lane & 15);
        u16x8 cv = *(const u16x8*)(cbtb + (long)l * CHUNK + sbase);
        const float cl = csL[l];
        bf16x8 af;
#pragma unroll
        for (int e = 0; e < 8; ++e) {
          int s = sbase + e;
          float val = (s <= l) ? bf2f(cv[e]) * expf(cl - csL[s]) * dtL[s] : 0.f;
          af[e] = (short)f2bf(val);
        }
#pragma unroll
        for (int j = 0; j < 4; ++j)
          acc[i][j] = __builtin_amdgcn_mfma_f32_16x16x32_bf16(af, bfr[j], acc[i][j], 0, 0, 0);
      }
    }
  }

  const float Dh = Dp[h];
#pragma unroll
  for (int i = 0; i < 4; ++i) {
    int l0 = w * 64 + i * 16 + g * 4;
#pragma unroll
    for (int r = 0; r < 4; ++r) {
      long grow = rowbase + l0 + r;
      const unsigned short* xrow = xbc + grow * (long)CONV_DIM + h * HEADDIM;
      unsigned short* yrow = y + grow * (long)D_INNER + h * HEADDIM;
#pragma unroll
      for (int j = 0; j < 4; ++j) {
        int p = j * 16 + (lane & 15);
        yrow[p] = f2bf(acc[i][j][r] + bf2f(xrow[p]) * Dh);
      }
    }
  }
}

// ---------------- gated RMSNorm ----------------
__global__ __launch_bounds__(256) void k_norm(unsigned short* yz, const unsigned short* __restrict__ zb,
                                              const float* __restrict__ norm_w, unsigned short* out) {
  const int row = blockIdx.x;
  const int t = threadIdx.x;
  const unsigned short* yr = yz + (size_t)row * D_INNER;
  const unsigned short* zr = zb + (size_t)row * D_INNER;
  float yv[16];
  float ss = 0.f;
#pragma unroll
  for (int j = 0; j < 4; ++j) {
    int e = (t + j * 256) * 4;
    ushort4 yy = *(const ushort4*)(yr + e);
    ushort4 zz = *(const ushort4*)(zr + e);
    float z0 = bf2f(zz.x), z1 = bf2f(zz.y), z2 = bf2f(zz.z), z3 = bf2f(zz.w);
    float g0 = bf2f(yy.x) * z0 / (1.f + expf(-z0));
    float g1 = bf2f(yy.y) * z1 / (1.f + expf(-z1));
    float g2 = bf2f(yy.z) * z2 / (1.f + expf(-z2));
    float g3 = bf2f(yy.w) * z3 / (1.f + expf(-z3));
    ss += g0 * g0 + g1 * g1 + g2 * g2 + g3 * g3;
    yv[j * 4 + 0] = g0; yv[j * 4 + 1] = g1; yv[j * 4 + 2] = g2; yv[j * 4 + 3] = g3;
  }
#pragma unroll
  for (int off = 32; off > 0; off >>= 1) ss += __shfl_xor(ss, off);
  __shared__ float red[4];
  if ((t & 63) == 0) red[t >> 6] = ss;
  __syncthreads();
  float tot = red[0] + red[1] + red[2] + red[3];
  float scale = rsqrtf(tot / (float)D_INNER + EPSV);
  unsigned short* orow = out + (size_t)row * D_INNER;
#pragma unroll
  for (int j = 0; j < 4; ++j) {
    int e = (t + j * 256) * 4;
    float4 w = *(const float4*)(norm_w + e);
    ushort4 o = make_ushort4(f2bf(yv[j * 4 + 0] * scale * w.x), f2bf(yv[j * 4 + 1] * scale * w.y),
                             f2bf(yv[j * 4 + 2] * scale * w.z), f2bf(yv[j * 4 + 3] * scale * w.w));
    *(ushort4*)(orow + e) = o;
  }
}

extern "C" void kernel_launch(void* const* d_in, const int* in_sizes, int n_in,
                              void* d_out, int out_size, void* d_ws, size_t ws_size,
                              hipStream_t stream) {
  const float* u       = (const float*)d_in[0];
  const float* W_in    = (const float*)d_in[1];
  const float* conv_w  = (const float*)d_in[2];
  const float* conv_b  = (const float*)d_in[3];
  const float* dt_bias = (const float*)d_in[4];
  const float* A_log   = (const float*)d_in[5];
  const float* Dp      = (const float*)d_in[6];
  const float* norm_w  = (const float*)d_in[7];
  const float* W_out   = (const float*)d_in[8];
  float* out = (float*)d_out;

  char* ws = (char*)d_ws;
  size_t off = 0;
  auto alloc = [&](size_t bytes) { char* p = ws + off; off += (bytes + 255) & ~(size_t)255; return p; };
  unsigned short* ub   = (unsigned short*)alloc((size_t)NROWS * D_MODEL * 2);
  unsigned short* winb = (unsigned short*)alloc((size_t)D_IN_PROJ * D_MODEL * 2);
  unsigned short* zb   = (unsigned short*)alloc((size_t)NROWS * D_INNER * 2);
  unsigned short* xb   = (unsigned short*)alloc((size_t)NROWS * CONV_DIM * 2);
  unsigned short* xbcb = (unsigned short*)alloc((size_t)NROWS * CONV_DIM * 2);
  float* dtt  = (float*)alloc((size_t)BATCH * NHEADS * SEQ * 4);
  float* acum = (float*)alloc((size_t)BATCH * NHEADS * NCHUNK * CHUNK * 4);
  unsigned short* cwT = (unsigned short*)alloc((size_t)4 * CONV_DIM * 2);
  unsigned short* cbT = (unsigned short*)alloc((size_t)CONV_DIM * 2);
  unsigned short* whl = (unsigned short*)alloc((size_t)128 * D_MODEL * 2);
  float* PD = (float*)alloc((size_t)4 * BATCH * NHEADS * SEQ * 4);
  unsigned short* wob = ub;
  unsigned short* cbt = winb;
  unsigned short* psb = winb + (size_t)BATCH * NCHUNK * CHUNK * CHUNK + 1024;
  unsigned short* ulob = xbcb;
  unsigned short* yb = xb;
  float* states = (float*)d_out;

  if (off > ws_size) {
    k_sentinel<<<1, 64, 0, stream>>>(out);
    return;
  }

  k_prep<<<6673, 256, 0, stream>>>(u, ub, ulob, W_in, winb, whl, conv_w, conv_b, cwT, cbT);
  k_gemm8p<<<(NROWS / 256) * (D_INNER / 256), 512, 0, stream>>>(ub, winb, zb, NROWS, D_INNER, D_MODEL);
  k_gemm128<1><<<(NROWS / 128) * (CONV_DIM / 128), 256, 0, stream>>>(ub, winb + (size_t)D_INNER * D_MODEL, xb, NROWS, CONV_DIM, D_MODEL);
  k_dtm<<<256, 256, 0, stream>>>(ub, ulob, whl, PD);
  k_dtred<<<BATCH * NHEADS, 256, 0, stream>>>(PD, dt_bias, A_log, dtt, acum);
  k_conv_silu<<<(int)(((long)(NROWS / 4) * CG + 255) / 256), 256, 0, stream>>>(xb, cwT, cbT, xbcb);
  k_cbtt<<<BATCH * NCHUNK * 4, 256, 0, stream>>>(xbcb, cbt);
  k_states<<<BATCH * NCHUNK * NHEADS, 256, 0, stream>>>(xbcb, dtt, acum, states);
  k_scan<<<(BATCH * NHEADS * D_STATE * HEADDIM + 255) / 256, 256, 0, stream>>>(states, acum, psb);
  k_y<<<BATCH * NCHUNK * NHEADS, 256, 0, stream>>>(xbcb, dtt, acum, cbt, psb, Dp, yb);
  k_norm<<<NROWS, 256, 0, stream>>>(yb, zb, norm_w, yb);
  k_f32_to_bf16_v4<<<2048, 256, 0, stream>>>(W_out, wob, (long)D_MODEL * D_INNER / 4);
  k_gemm128<0><<<(NROWS / 128) * (D_MODEL / 128), 256, 0, stream>>>(yb, wob, out, NROWS, D_MODEL, D_INNER);
}

// Round 11
// 438.722 us; speedup vs baseline: 2.5003x; 1.0906x over previous
//
#include <hip/hip_runtime.h>

#define D_MODEL   2048
#define D_INNER   4096
#define HEADDIM   64
#define NHEADS    64
#define D_STATE   128
#define CHUNK     256
#define CONV_DIM  4352
#define D_IN_PROJ 8512
#define BATCH     2
#define SEQ       2048
#define NCHUNK    8
#define NROWS     4096
#define EPSV      1e-5f
#define CG        (CONV_DIM / 8)   // 544

typedef __attribute__((ext_vector_type(8))) short bf16x8;
typedef __attribute__((ext_vector_type(8))) unsigned short u16x8;
typedef __attribute__((ext_vector_type(4))) float f32x4;

#define AS1 __attribute__((address_space(1)))
#define AS3 __attribute__((address_space(3)))

#define BAR() do { asm volatile("" ::: "memory"); __builtin_amdgcn_s_barrier(); asm volatile("" ::: "memory"); } while (0)

__device__ __forceinline__ unsigned short f2bf(float f) {
  unsigned int x = __float_as_uint(f);
  unsigned int r = (x + 0x7fffu + ((x >> 16) & 1u)) >> 16;
  return (unsigned short)r;
}
__device__ __forceinline__ float bf2f(unsigned short u) {
  return __uint_as_float((unsigned int)u << 16);
}

__global__ void k_sentinel(float* out) { if (threadIdx.x == 0) out[0] = 1.0e6f; }

// ---------------- fused prep: usplit | W_in convert | wpack | conv pack ----------------
__global__ void k_prep(const float* __restrict__ u, unsigned short* __restrict__ uhi, unsigned short* __restrict__ ulo,
                       const float* __restrict__ W, unsigned short* __restrict__ winb, unsigned short* __restrict__ whl,
                       const float* __restrict__ cw, const float* __restrict__ cb,
                       unsigned short* __restrict__ cwT, unsigned short* __restrict__ cbT) {
  const int b = blockIdx.x;
  const int t = threadIdx.x;
  if (b < 2048) {
    const long n4 = (long)NROWS * D_MODEL / 4;
    for (long i = (long)b * 256 + t; i < n4; i += 2048L * 256) {
      float4 v = ((const float4*)u)[i];
      ushort4 h, l;
      h.x = f2bf(v.x); l.x = f2bf(v.x - bf2f(h.x));
      h.y = f2bf(v.y); l.y = f2bf(v.y - bf2f(h.y));
      h.z = f2bf(v.z); l.z = f2bf(v.z - bf2f(h.z));
      h.w = f2bf(v.w); l.w = f2bf(v.w - bf2f(h.w));
      ((ushort4*)uhi)[i] = h;
      ((ushort4*)ulo)[i] = l;
    }
  } else if (b < 6144) {
    const long n4 = (long)D_IN_PROJ * D_MODEL / 4;
    for (long i = (long)(b - 2048) * 256 + t; i < n4; i += 4096L * 256) {
      float4 v = ((const float4*)W)[i];
      ushort4 o = make_ushort4(f2bf(v.x), f2bf(v.y), f2bf(v.z), f2bf(v.w));
      ((ushort4*)winb)[i] = o;
    }
  } else if (b < 6656) {
    long i = (long)(b - 6144) * 256 + t;
    float v = W[(size_t)8448 * D_MODEL + i];
    unsigned short h = f2bf(v);
    whl[i] = h;
    whl[(size_t)64 * D_MODEL + i] = f2bf(v - bf2f(h));
  } else {
    int i = (b - 6656) * 256 + t;
    if (i < CONV_DIM) {
#pragma unroll
      for (int w = 0; w < 4; ++w) cwT[w * CONV_DIM + i] = f2bf(cw[i * 4 + w]);
      cbT[i] = f2bf(cb[i]);
    }
  }
}

// ---------------- W_out convert ----------------
__global__ void k_f32_to_bf16_v4(const float* __restrict__ in, unsigned short* __restrict__ out, long n4) {
  long i = (long)blockIdx.x * blockDim.x + threadIdx.x;
  long stride = (long)gridDim.x * blockDim.x;
  for (; i < n4; i += stride) {
    float4 v = ((const float4*)in)[i];
    ushort4 o = make_ushort4(f2bf(v.x), f2bf(v.y), f2bf(v.z), f2bf(v.w));
    ((ushort4*)out)[i] = o;
  }
}

// ---- dt split-bf16 MFMA, SPLIT-K=4 -> PD[ks][bh][l] (f32) ----
__global__ __launch_bounds__(256, 2) void k_dtm(const unsigned short* __restrict__ uhi,
                                                const unsigned short* __restrict__ ulo,
                                                const unsigned short* __restrict__ whl,
                                                float* __restrict__ PD) {
  __shared__ __align__(16) short lds[2][256 * 64];
  const int t = threadIdx.x;
  const int lane = t & 63;
  const int w = t >> 6;
  const int ks = (int)blockIdx.x & 3;
  const int m0 = ((int)blockIdx.x >> 2) * 64;
  const int kbase = ks * 512;

  f32x4 acc1[8], acc2[4];
#pragma unroll
  for (int j = 0; j < 8; ++j) { f32x4 z = {0.f, 0.f, 0.f, 0.f}; acc1[j] = z; }
#pragma unroll
  for (int j = 0; j < 4; ++j) { f32x4 z = {0.f, 0.f, 0.f, 0.f}; acc2[j] = z; }

  const int srow = t >> 3;
  const int schunk = (t & 7) ^ (srow & 7);
  const unsigned short* gU = uhi + (size_t)(m0 + srow) * D_MODEL + kbase + schunk * 8;
  const unsigned short* gL = ulo + (size_t)(m0 + srow) * D_MODEL + kbase + schunk * 8;
  const unsigned short* gW = whl + (size_t)srow * D_MODEL + kbase + schunk * 8;

  auto STAGE = [&](int buf, int kt) {
    char* d = (char*)&lds[buf][0] + t * 16;
#pragma unroll
    for (int ii = 0; ii < 2; ++ii)
      __builtin_amdgcn_global_load_lds((const AS1 void*)(gU + (size_t)ii * 32 * D_MODEL + (size_t)kt * 64),
                                       (AS3 void*)(d + ii * 4096), 16, 0, 0);
#pragma unroll
    for (int ii = 0; ii < 2; ++ii)
      __builtin_amdgcn_global_load_lds((const AS1 void*)(gL + (size_t)ii * 32 * D_MODEL + (size_t)kt * 64),
                                       (AS3 void*)(d + 8192 + ii * 4096), 16, 0, 0);
#pragma unroll
    for (int ii = 0; ii < 4; ++ii)
      __builtin_amdgcn_global_load_lds((const AS1 void*)(gW + (size_t)ii * 32 * D_MODEL + (size_t)kt * 64),
                                       (AS3 void*)(d + 16384 + ii * 4096), 16, 0, 0);
  };

  STAGE(0, 0);

  const int NT = 512 / 64;
  const int ar = w * 16 + (lane & 15);
  const int kof = (lane >> 4) * 8;
  const int rsw = (lane & 7) * 8;
  int cur = 0;
  for (int kt = 0; kt < NT; ++kt) {
    if (kt + 1 < NT) {
      STAGE(cur ^ 1, kt + 1);
      asm volatile("s_waitcnt vmcnt(8)" ::: "memory");
    } else {
      asm volatile("s_waitcnt vmcnt(0)" ::: "memory");
    }
    __builtin_amdgcn_s_barrier();
    asm volatile("" ::: "memory");
    const short* L = &lds[cur][0];
#pragma unroll
    for (int kk = 0; kk < 2; ++kk) {
      const int off = (kk * 32 + kof) ^ rsw;
      bf16x8 ah = *(const bf16x8*)(L + ar * 64 + off);
      bf16x8 al = *(const bf16x8*)(L + (64 + ar) * 64 + off);
#pragma unroll
      for (int j = 0; j < 8; ++j) {
        bf16x8 bj = *(const bf16x8*)(L + (128 + j * 16 + (lane & 15)) * 64 + off);
        acc1[j] = __builtin_amdgcn_mfma_f32_16x16x32_bf16(ah, bj, acc1[j], 0, 0, 0);
        if (j < 4) acc2[j] = __builtin_amdgcn_mfma_f32_16x16x32_bf16(al, bj, acc2[j], 0, 0, 0);
      }
    }
    asm volatile("" ::: "memory");
    __builtin_amdgcn_s_barrier();
    asm volatile("" ::: "memory");
    cur ^= 1;
  }

  const int crow = (lane >> 4) * 4;
  float* P = PD + (size_t)ks * BATCH * NHEADS * SEQ;
#pragma unroll
  for (int j = 0; j < 4; ++j) {
    int h = j * 16 + (lane & 15);
#pragma unroll
    for (int r = 0; r < 4; ++r) {
      int row = m0 + w * 16 + crow + r;
      float v = acc1[j][r] + acc1[j + 4][r] + acc2[j][r];
      P[(size_t)((row >> 11) * NHEADS + h) * SEQ + (row & 2047)] = v;
    }
  }
}

// ---- dt reduce + softplus -> dtt; fused per-chunk cumsum -> acum ----
__global__ __launch_bounds__(256) void k_dtred(const float* __restrict__ PD, const float* __restrict__ dt_bias,
                                               const float* __restrict__ A_log,
                                               float* __restrict__ dt_t, float* __restrict__ A_cum) {
  const int bh = blockIdx.x;
  const int h = bh & 63;
  const int t = threadIdx.x;
  const float bias = dt_bias[h];
  const float A = -__expf(A_log[h]);
  const size_t base = (size_t)bh * SEQ;
  const size_t pstride = (size_t)BATCH * NHEADS * SEQ;
  __shared__ float s[256];
  for (int c = 0; c < NCHUNK; ++c) {
    int l = c * CHUNK + t;
    float v = PD[base + l] + PD[pstride + base + l] + PD[2 * pstride + base + l] + PD[3 * pstride + base + l] + bias;
    float dtv = (v > 20.f) ? v : log1pf(expf(v));
    dt_t[base + l] = dtv;
    s[t] = dtv * A;
    __syncthreads();
    for (int off = 1; off < 256; off <<= 1) {
      float x = (t >= off) ? s[t - off] : 0.f;
      __syncthreads();
      s[t] += x;
      __syncthreads();
    }
    A_cum[((size_t)bh * NCHUNK + c) * CHUNK + t] = s[t];
    __syncthreads();
  }
}

// ---- 256x256 BK=64 8-phase GEMM (T2+T3+T4+T5), grouped-raster XCD swizzle ----
__global__ __launch_bounds__(512, 2) void k_gemm8p(const unsigned short* __restrict__ A,
                                                   const unsigned short* __restrict__ B,
                                                   unsigned short* __restrict__ C, int M, int N, int K) {
  __shared__ __align__(16) short lds[2][32768];
  const int t = threadIdx.x;
  const int lane = t & 63;
  const int wid = t >> 6;
  const int wr = wid >> 2;
  const int wc = wid & 3;
  const int ntx = N / 256;
  const int nwg = (int)gridDim.x;
  const int bid = (int)blockIdx.x;
  const int swz = (bid & 7) * (nwg >> 3) + (bid >> 3);
  const int grp = ntx << 3;
  const int gid = swz / grp;
  const int rem = swz - gid * grp;
  const int m0 = ((gid << 3) + (rem & 7)) * 256;
  const int n0 = (rem >> 3) * 256;

  f32x4 acc[8][4];
#pragma unroll
  for (int i = 0; i < 8; ++i)
#pragma unroll
    for (int j = 0; j < 4; ++j) { f32x4 z = {0.f, 0.f, 0.f, 0.f}; acc[i][j] = z; }

  const int srow = t >> 3;
  const int schunk = (t & 7) ^ (srow & 7);
  const unsigned short* gA = A + (size_t)(m0 + srow) * K + schunk * 8;
  const unsigned short* gB = B + (size_t)(n0 + srow) * K + schunk * 8;

  auto STAGE_HALF = [&](int buf, int kt, int which) {
    const unsigned short* g = (which < 2 ? gA : gB) + (size_t)(which & 1) * 128 * K + (size_t)kt * 64;
    char* d = (char*)lds + buf * 65536 + which * 16384 + t * 16;
    __builtin_amdgcn_global_load_lds((const AS1 void*)g, (AS3 void*)d, 16, 0, 0);
    __builtin_amdgcn_global_load_lds((const AS1 void*)(g + (size_t)64 * K), (AS3 void*)(d + 8192), 16, 0, 0);
  };

  const int NT = K / 64;
  STAGE_HALF(0, 0, 0); STAGE_HALF(0, 0, 1); STAGE_HALF(0, 0, 2); STAGE_HALF(0, 0, 3);
  STAGE_HALF(1, 1, 2); STAGE_HALF(1, 1, 0); STAGE_HALF(1, 1, 1);
  asm volatile("s_waitcnt vmcnt(6)" ::: "memory");
  BAR();

  const int ar = wr * 128 + (lane & 15);
  const int br = wc * 64 + (lane & 15);
  const int kof = (lane >> 4) * 8;
  const int rsw = (lane & 7) * 8;

  for (int kt = 0; kt < NT; ++kt) {
    const int buf = kt & 1;
    const short* As = &lds[buf][0];
    const short* Bs = &lds[buf][16384];
    const bool s1 = (kt + 1 < NT);
    const bool s2 = (kt + 2 < NT);
    bf16x8 aLo[4][2], aHi[4][2], bLo[2][2], bHi[2][2];

#pragma unroll
    for (int i = 0; i < 4; ++i)
#pragma unroll
      for (int k = 0; k < 2; ++k) aLo[i][k] = *(const bf16x8*)(As + (ar + i * 16) * 64 + ((k * 32 + kof) ^ rsw));
#pragma unroll
    for (int j = 0; j < 2; ++j)
#pragma unroll
      for (int k = 0; k < 2; ++k) bLo[j][k] = *(const bf16x8*)(Bs + (br + j * 16) * 64 + ((k * 32 + kof) ^ rsw));
    if (s1) STAGE_HALF(buf ^ 1, kt + 1, 3);
    BAR();
    __builtin_amdgcn_s_setprio(1);
#pragma unroll
    for (int k = 0; k < 2; ++k)
#pragma unroll
      for (int i = 0; i < 4; ++i)
#pragma unroll
        for (int j = 0; j < 2; ++j)
          acc[i][j] = __builtin_amdgcn_mfma_f32_16x16x32_bf16(aLo[i][k], bLo[j][k], acc[i][j], 0, 0, 0);
    __builtin_amdgcn_s_setprio(0);
    BAR();

#pragma unroll
    for (int j = 0; j < 2; ++j)
#pragma unroll
      for (int k = 0; k < 2; ++k) bHi[j][k] = *(const bf16x8*)(Bs + (br + (j + 2) * 16) * 64 + ((k * 32 + kof) ^ rsw));
    BAR();
    __builtin_amdgcn_s_setprio(1);
#pragma unroll
    for (int k = 0; k < 2; ++k)
#pragma unroll
      for (int i = 0; i < 4; ++i)
#pragma unroll
        for (int j = 0; j < 2; ++j)
          acc[i][j + 2] = __builtin_amdgcn_mfma_f32_16x16x32_bf16(aLo[i][k], bHi[j][k], acc[i][j + 2], 0, 0, 0);
    __builtin_amdgcn_s_setprio(0);
    BAR();

#pragma unroll
    for (int i = 0; i < 4; ++i)
#pragma unroll
      for (int k = 0; k < 2; ++k) aHi[i][k] = *(const bf16x8*)(As + (ar + (i + 4) * 16) * 64 + ((k * 32 + kof) ^ rsw));
    if (s2) STAGE_HALF(buf, kt + 2, 2);
    BAR();
    __builtin_amdgcn_s_setprio(1);
#pragma unroll
    for (int k = 0; k < 2; ++k)
#pragma unroll
      for (int i = 0; i < 4; ++i)
#pragma unroll
        for (int j = 0; j < 2; ++j)
          acc[i + 4][j] = __builtin_amdgcn_mfma_f32_16x16x32_bf16(aHi[i][k], bLo[j][k], acc[i + 4][j], 0, 0, 0);
    __builtin_amdgcn_s_setprio(0);
    BAR();

    if (s2) { STAGE_HALF(buf, kt + 2, 0); STAGE_HALF(buf, kt + 2, 1); }
    if (s2) { asm volatile("s_waitcnt vmcnt(6)" ::: "memory"); }
    else    { asm volatile("s_waitcnt vmcnt(0)" ::: "memory"); }
    BAR();
    __builtin_amdgcn_s_setprio(1);
#pragma unroll
    for (int k = 0; k < 2; ++k)
#pragma unroll
      for (int i = 0; i < 4; ++i)
#pragma unroll
        for (int j = 0; j < 2; ++j)
          acc[i + 4][j + 2] = __builtin_amdgcn_mfma_f32_16x16x32_bf16(aHi[i][k], bHi[j][k], acc[i + 4][j + 2], 0, 0, 0);
    __builtin_amdgcn_s_setprio(0);
    BAR();
  }

  const int crow = (lane >> 4) * 4;
  const int ccol = lane & 15;
#pragma unroll
  for (int i = 0; i < 8; ++i)
#pragma unroll
    for (int j = 0; j < 4; ++j) {
      size_t base = (size_t)(m0 + wr * 128 + i * 16 + crow) * N + (n0 + wc * 64 + j * 16 + ccol);
#pragma unroll
      for (int r = 0; r < 4; ++r) C[base + (size_t)r * N] = f2bf(acc[i][j][r]);
    }
}

// ---- 128x128 BK=64 double-buffered GEMM, grouped-raster XCD swizzle ----
template <int BF16OUT>
__global__ __launch_bounds__(256, 2) void k_gemm128(const unsigned short* __restrict__ A,
                                                    const unsigned short* __restrict__ B,
                                                    void* __restrict__ Cv, int M, int N, int K) {
  constexpr int BK = 64;
  __shared__ __align__(16) short lds[2][256 * BK];
  const int t = threadIdx.x;
  const int lane = t & 63;
  const int wid = t >> 6;
  const int wr = wid >> 1;
  const int wc = wid & 1;
  const int ntx = N / 128;
  const int nwg = (int)gridDim.x;
  const int bid = (int)blockIdx.x;
  const int swz = (bid & 7) * (nwg >> 3) + (bid >> 3);
  const int grp = ntx << 3;
  const int gid = swz / grp;
  const int rem = swz - gid * grp;
  const int m0 = ((gid << 3) + (rem & 7)) * 128;
  const int n0 = (rem >> 3) * 128;

  f32x4 acc[4][4];
#pragma unroll
  for (int i = 0; i < 4; ++i)
#pragma unroll
    for (int j = 0; j < 4; ++j) { f32x4 z = {0.f, 0.f, 0.f, 0.f}; acc[i][j] = z; }

  const int srow = t >> 3;
  const int schunk = (t & 7) ^ (srow & 7);
  const unsigned short* gA = A + (size_t)(m0 + srow) * K + schunk * 8;
  const unsigned short* gB = B + (size_t)(n0 + srow) * K + schunk * 8;

  auto STAGE = [&](int buf, int kt) {
    char* dA = (char*)&lds[buf][0] + t * 16;
    char* dB = (char*)&lds[buf][128 * BK] + t * 16;
#pragma unroll
    for (int ii = 0; ii < 4; ++ii)
      __builtin_amdgcn_global_load_lds((const AS1 void*)(gA + (size_t)ii * 32 * K + kt * BK),
                                       (AS3 void*)(dA + ii * 4096), 16, 0, 0);
#pragma unroll
    for (int ii = 0; ii < 4; ++ii)
      __builtin_amdgcn_global_load_lds((const AS1 void*)(gB + (size_t)ii * 32 * K + kt * BK),
                                       (AS3 void*)(dB + ii * 4096), 16, 0, 0);
  };

  STAGE(0, 0);

  const int NT = K / BK;
  const int ar = wr * 64 + (lane & 15);
  const int br = wc * 64 + (lane & 15);
  const int kof = (lane >> 4) * 8;
  const int rsw = (lane & 7) * 8;
  int cur = 0;
  for (int kt = 0; kt < NT; ++kt) {
    if (kt + 1 < NT) {
      STAGE(cur ^ 1, kt + 1);
      asm volatile("s_waitcnt vmcnt(8)" ::: "memory");
    } else {
      asm volatile("s_waitcnt vmcnt(0)" ::: "memory");
    }
    __builtin_amdgcn_s_barrier();
    asm volatile("" ::: "memory");
    const short* As = &lds[cur][0];
    const short* Bs = &lds[cur][128 * BK];
#pragma unroll
    for (int kk = 0; kk < 2; ++kk) {
      bf16x8 bfr[4];
#pragma unroll
      for (int j = 0; j < 4; ++j)
        bfr[j] = *(const bf16x8*)(Bs + (br + j * 16) * BK + ((kk * 32 + kof) ^ rsw));
#pragma unroll
      for (int i = 0; i < 4; ++i) {
        bf16x8 af = *(const bf16x8*)(As + (ar + i * 16) * BK + ((kk * 32 + kof) ^ rsw));
#pragma unroll
        for (int j = 0; j < 4; ++j)
          acc[i][j] = __builtin_amdgcn_mfma_f32_16x16x32_bf16(af, bfr[j], acc[i][j], 0, 0, 0);
      }
    }
    asm volatile("" ::: "memory");
    __builtin_amdgcn_s_barrier();
    asm volatile("" ::: "memory");
    cur ^= 1;
  }

  const int crow = (lane >> 4) * 4;
  const int ccol = lane & 15;
#pragma unroll
  for (int i = 0; i < 4; ++i)
#pragma unroll
    for (int j = 0; j < 4; ++j) {
      size_t base = (size_t)(m0 + wr * 64 + i * 16 + crow) * N + (n0 + wc * 64 + j * 16 + ccol);
      if (BF16OUT) {
        unsigned short* C = (unsigned short*)Cv;
#pragma unroll
        for (int r = 0; r < 4; ++r) C[base + (size_t)r * N] = f2bf(acc[i][j][r]);
      } else {
        float* C = (float*)Cv;
#pragma unroll
        for (int r = 0; r < 4; ++r) C[base + (size_t)r * N] = acc[i][j][r];
      }
    }
}

// ---------------- conv1d + silu ----------------
__global__ __launch_bounds__(256) void k_conv_silu(const unsigned short* __restrict__ xb,
                                                   const unsigned short* __restrict__ wT,
                                                   const unsigned short* __restrict__ bT,
                                                   unsigned short* __restrict__ out) {
  long idx = (long)blockIdx.x * blockDim.x + threadIdx.x;
  if (idx >= (long)(NROWS / 4) * CG) return;
  int c8 = (int)(idx % CG);
  long rq = idx / CG;
  int l0 = (int)((rq & (SEQ / 4 - 1)) * 4);
  long brow = (rq >> 9) * (long)SEQ;
  int ch0 = c8 * 8;

  u16x8 wv[4];
#pragma unroll
  for (int w = 0; w < 4; ++w) wv[w] = *(const u16x8*)(wT + w * CONV_DIM + ch0);
  u16x8 bv = *(const u16x8*)(bT + ch0);

  u16x8 xr[7];
#pragma unroll
  for (int i = 0; i < 7; ++i) {
    int ls = l0 - 3 + i;
    if (ls >= 0) xr[i] = *(const u16x8*)(xb + (brow + ls) * (long)CONV_DIM + ch0);
    else { u16x8 z = {0, 0, 0, 0, 0, 0, 0, 0}; xr[i] = z; }
  }

#pragma unroll
  for (int r = 0; r < 4; ++r) {
    float acc[8];
#pragma unroll
    for (int e = 0; e < 8; ++e) acc[e] = bf2f(bv[e]);
#pragma unroll
    for (int w = 0; w < 4; ++w)
#pragma unroll
      for (int e = 0; e < 8; ++e) acc[e] += bf2f(xr[r + w][e]) * bf2f(wv[w][e]);
    u16x8 o;
#pragma unroll
    for (int e = 0; e < 8; ++e) o[e] = f2bf(acc[e] / (1.f + __expf(-acc[e])));
    *(u16x8*)(out + (brow + l0 + r) * (long)CONV_DIM + ch0) = o;
  }
}

// ---- CBT tiled layout: idx(l,s) = ((l>>4)*32 + (s>>3))*128 + (l&15)*8 + (s&7) ----
__global__ __launch_bounds__(256) void k_cbtt(const unsigned short* __restrict__ xbc, unsigned short* __restrict__ cbt_t) {
  const int bid = blockIdx.x;
  const int sp = bid & 3;
  const int bc = bid >> 2;
  const int b = bc >> 3, c = bc & 7;
  const int t = threadIdx.x;
  const int lane = t & 63;
  const int w = t >> 6;
  const int g = lane >> 4;
  __shared__ unsigned short Cs[256][72];
  __shared__ unsigned short Bs2[64][72];
  const long rowbase = (long)b * SEQ + c * CHUNK;
  f32x4 acc[4][4];
#pragma unroll
  for (int i = 0; i < 4; ++i)
#pragma unroll
    for (int j = 0; j < 4; ++j) { f32x4 z = {0.f, 0.f, 0.f, 0.f}; acc[i][j] = z; }

  for (int np = 0; np < 2; ++np) {
    __syncthreads();
    for (int i = t; i < 256 * 16; i += 256) {
      int row = i >> 4, c4 = (i & 15) * 4;
      ushort4 v = *(const ushort4*)(xbc + (rowbase + row) * (long)CONV_DIM + D_INNER + D_STATE + np * 64 + c4);
      *(ushort4*)&Cs[row][c4] = v;
    }
    for (int i = t; i < 64 * 16; i += 256) {
      int row = i >> 4, c4 = (i & 15) * 4;
      ushort4 v = *(const ushort4*)(xbc + (rowbase + sp * 64 + row) * (long)CONV_DIM + D_INNER + np * 64 + c4);
      *(ushort4*)&Bs2[row][c4] = v;
    }
    __syncthreads();
#pragma unroll
    for (int ks = 0; ks < 2; ++ks) {
      const int kofs = ks * 32 + g * 8;
      bf16x8 af[4], bfr[4];
#pragma unroll
      for (int i = 0; i < 4; ++i) af[i] = *(const bf16x8*)&Cs[w * 64 + i * 16 + (lane & 15)][kofs];
#pragma unroll
      for (int j = 0; j < 4; ++j) bfr[j] = *(const bf16x8*)&Bs2[j * 16 + (lane & 15)][kofs];
#pragma unroll
      for (int i = 0; i < 4; ++i)
#pragma unroll
        for (int j = 0; j < 4; ++j)
          acc[i][j] = __builtin_amdgcn_mfma_f32_16x16x32_bf16(af[i], bfr[j], acc[i][j], 0, 0, 0);
    }
  }
  unsigned short* ob = cbt_t + (long)bc * CHUNK * CHUNK;
#pragma unroll
  for (int i = 0; i < 4; ++i)
#pragma unroll
    for (int j = 0; j < 4; ++j) {
      int l0 = w * 64 + i * 16 + g * 4;
      int s = sp * 64 + j * 16 + (lane & 15);
#pragma unroll
      for (int r = 0; r < 4; ++r) {
        int l = l0 + r;
        ob[((long)(l >> 4) * 32 + (s >> 3)) * 128 + (l & 15) * 8 + (s & 7)] = f2bf(acc[i][j][r]);
      }
    }
}

// ---- states[n][p], MFMA, XOR-swizzled transpose staging ----
__global__ __launch_bounds__(256) void k_states(const unsigned short* __restrict__ xbc, const float* __restrict__ dt_t,
                                                const float* __restrict__ A_cum, float* __restrict__ states) {
  const int bid = blockIdx.x;
  const int h = bid & 63;
  const int bc = bid >> 6;
  const int b = bc >> 3, c = bc & 7;
  const int t = threadIdx.x;
  const int lane = t & 63;
  const int w = t >> 6;
  const int g = lane >> 4;
  __shared__ unsigned short BT[128][72];
  __shared__ unsigned short WXT[64][72];
  __shared__ float csL[256], dtL[256];
  const long rowbase = (long)b * SEQ + c * CHUNK;
  const long bh8 = ((long)(b * NHEADS + h)) * NCHUNK + c;
  const float* acum = A_cum + bh8 * CHUNK;
  if (t < 256) { csL[t] = acum[t]; dtL[t] = dt_t[((size_t)(b * NHEADS + h)) * SEQ + c * CHUNK + t]; }
  float cs_last = acum[255];
  f32x4 acc[2][4];
#pragma unroll
  for (int i = 0; i < 2; ++i)
#pragma unroll
    for (int j = 0; j < 4; ++j) { f32x4 z = {0.f, 0.f, 0.f, 0.f}; acc[i][j] = z; }

  for (int lp = 0; lp < 4; ++lp) {
    __syncthreads();
    for (int i = t; i < 64 * 32; i += 256) {
      int l = i >> 5, n4 = (i & 31) * 4;
      int sw = ((n4 >> 3) & 7) << 3;
      ushort4 v = *(const ushort4*)(xbc + (rowbase + lp * 64 + l) * (long)CONV_DIM + D_INNER + n4);
      BT[n4 + 0][l ^ sw] = v.x; BT[n4 + 1][l ^ sw] = v.y; BT[n4 + 2][l ^ sw] = v.z; BT[n4 + 3][l ^ sw] = v.w;
    }
    for (int i = t; i < 64 * 16; i += 256) {
      int l = i >> 4, p4 = (i & 15) * 4;
      int sw = ((p4 >> 3) & 7) << 3;
      int lg = lp * 64 + l;
      float wgt = __expf(cs_last - csL[lg]) * dtL[lg];
      ushort4 v = *(const ushort4*)(xbc + (rowbase + lg) * (long)CONV_DIM + h * HEADDIM + p4);
      WXT[p4 + 0][l ^ sw] = f2bf(bf2f(v.x) * wgt);
      WXT[p4 + 1][l ^ sw] = f2bf(bf2f(v.y) * wgt);
      WXT[p4 + 2][l ^ sw] = f2bf(bf2f(v.z) * wgt);
      WXT[p4 + 3][l ^ sw] = f2bf(bf2f(v.w) * wgt);
    }
    __syncthreads();
#pragma unroll
    for (int ks = 0; ks < 2; ++ks) {
      const int kofs = ks * 32 + g * 8;
      bf16x8 am[2], bp[4];
#pragma unroll
      for (int i = 0; i < 2; ++i) {
        int row = w * 32 + i * 16 + (lane & 15);
        am[i] = *(const bf16x8*)&BT[row][kofs ^ (((row >> 3) & 7) << 3)];
      }
#pragma unroll
      for (int j = 0; j < 4; ++j) {
        int row = j * 16 + (lane & 15);
        bp[j] = *(const bf16x8*)&WXT[row][kofs ^ (((row >> 3) & 7) << 3)];
      }
#pragma unroll
      for (int i = 0; i < 2; ++i)
#pragma unroll
        for (int j = 0; j < 4; ++j)
          acc[i][j] = __builtin_amdgcn_mfma_f32_16x16x32_bf16(am[i], bp[j], acc[i][j], 0, 0, 0);
    }
  }
  float* sp = states + ((long)bc * NHEADS + h) * (D_STATE * HEADDIM);
#pragma unroll
  for (int i = 0; i < 2; ++i)
#pragma unroll
    for (int j = 0; j < 4; ++j) {
      int n0 = w * 32 + i * 16 + g * 4;
      int p = j * 16 + (lane & 15);
#pragma unroll
      for (int r = 0; r < 4; ++r) sp[(long)(n0 + r) * HEADDIM + p] = acc[i][j][r];
    }
}

// ---------------- inter-chunk scan -> prev_states (bf16, [n][p]) ----------------
__global__ void k_scan(const float* __restrict__ states, const float* __restrict__ A_cum, unsigned short* __restrict__ psb) {
  long idx = (long)blockIdx.x * blockDim.x + threadIdx.x;
  if (idx >= (long)BATCH * NHEADS * D_STATE * HEADDIM) return;
  int p = idx & 63;
  int n = (int)((idx >> 6) & 127);
  long bh = idx >> 13;
  int h = (int)(bh & 63);
  int b = (int)(bh >> 6);
  float S = 0.f;
  for (int c = 0; c < NCHUNK; ++c) {
    long soff = (((long)(b * NCHUNK + c) * NHEADS + h) * (D_STATE * HEADDIM)) + (long)n * HEADDIM + p;
    psb[soff] = f2bf(S);
    float decay = __expf(A_cum[(bh * NCHUNK + c) * CHUNK + 255]);
    S = S * decay + states[soff];
  }
}

// ---- Y = Y_diag + Y_off + x*D: balanced waves, swizzled LDS, tiled cbt ----
__global__ __launch_bounds__(256) void k_y(const unsigned short* __restrict__ xbc, const float* __restrict__ dt_t,
                                           const float* __restrict__ A_cum, const unsigned short* __restrict__ cbt_t,
                                           const unsigned short* __restrict__ psb, const float* __restrict__ Dp,
                                           unsigned short* __restrict__ y) {
  const int bid = blockIdx.x;
  const int h = bid & 63;
  const int bc = bid >> 6;
  const int b = bc >> 3, c = bc & 7;
  const int t = threadIdx.x;
  const int lane = t & 63;
  const int w = t >> 6;
  const int g = lane >> 4;
  __shared__ unsigned short Abuf[256][56];   // Y_off A panel (K=32 + pad), 112B rows (16B-aligned)
  __shared__ unsigned short Bbuf[64][72];    // PS^T (ph1) / x^T (ph2), XOR-swizzled cols
  __shared__ float csL[256], dtL[256], expL[256];
  const long rowbase = (long)b * SEQ + c * CHUNK;
  const long bh8 = ((long)(b * NHEADS + h)) * NCHUNK + c;
  const float* acum = A_cum + bh8 * CHUNK;
  if (t < 256) {
    float cv = acum[t];
    csL[t] = cv;
    expL[t] = __expf(cv);
    dtL[t] = dt_t[((size_t)(b * NHEADS + h)) * SEQ + c * CHUNK + t];
  }
  f32x4 acc[4][4];
#pragma unroll
  for (int i = 0; i < 4; ++i)
#pragma unroll
    for (int j = 0; j < 4; ++j) { f32x4 z = {0.f, 0.f, 0.f, 0.f}; acc[i][j] = z; }

  // ---- phase 1: Y_off = (C .* exp(cs_l)) @ PS^T, 4 panels of K=32 ----
  const unsigned short* psbase = psb + ((long)bc * NHEADS + h) * (D_STATE * HEADDIM);
  for (int np = 0; np < 4; ++np) {
    __syncthreads();
    for (int i = t; i < 256 * 8; i += 256) {
      int row = i >> 3, c4 = (i & 7) * 4;
      float el = expL[row];
      ushort4 v = *(const ushort4*)(xbc + (rowbase + row) * (long)CONV_DIM + D_INNER + D_STATE + np * 32 + c4);
      ushort4 o = make_ushort4(f2bf(bf2f(v.x) * el), f2bf(bf2f(v.y) * el), f2bf(bf2f(v.z) * el), f2bf(bf2f(v.w) * el));
      *(ushort4*)&Abuf[row][c4] = o;
    }
    for (int i = t; i < 512; i += 256) {
      int nl = i >> 4, p4 = (i & 15) * 4;
      int sw = ((p4 >> 3) & 7) << 3;
      ushort4 v = *(const ushort4*)(psbase + (long)(np * 32 + nl) * HEADDIM + p4);
      Bbuf[p4 + 0][nl ^ sw] = v.x; Bbuf[p4 + 1][nl ^ sw] = v.y;
      Bbuf[p4 + 2][nl ^ sw] = v.z; Bbuf[p4 + 3][nl ^ sw] = v.w;
    }
    __syncthreads();
    bf16x8 bfr[4];
#pragma unroll
    for (int j = 0; j < 4; ++j) {
      int row = j * 16 + (lane & 15);
      bfr[j] = *(const bf16x8*)&Bbuf[row][(g * 8) ^ (((row >> 3) & 7) << 3)];
    }
#pragma unroll
    for (int i = 0; i < 4; ++i) {
      bf16x8 af = *(const bf16x8*)&Abuf[(i * 4 + w) * 16 + (lane & 15)][g * 8];
#pragma unroll
      for (int j = 0; j < 4; ++j)
        acc[i][j] = __builtin_amdgcn_mfma_f32_16x16x32_bf16(af, bfr[j], acc[i][j], 0, 0, 0);
    }
  }

  // ---- phase 2: Y_diag, balanced groups, in-register scores from tiled cbt ----
  const unsigned short* cbtb = cbt_t + (long)bc * CHUNK * CHUNK;
  for (int sp = 0; sp < 4; ++sp) {
    __syncthreads();
    for (int i = t; i < 512; i += 256) {
      int s = i >> 3, p0 = (i & 7) * 8;
      int sw = ((p0 >> 3) & 7) << 3;
      u16x8 v = *(const u16x8*)(xbc + (rowbase + sp * 64 + s) * (long)CONV_DIM + h * HEADDIM + p0);
#pragma unroll
      for (int e = 0; e < 8; ++e) Bbuf[p0 + e][s ^ sw] = v[e];
    }
    __syncthreads();
#pragma unroll
    for (int ks = 0; ks < 2; ++ks) {
      const int sb0 = sp * 64 + ks * 32;
      bf16x8 bfr[4];
#pragma unroll
      for (int j = 0; j < 4; ++j) {
        int row = j * 16 + (lane & 15);
        bfr[j] = *(const bf16x8*)&Bbuf[row][(ks * 32 + g * 8) ^ (((row >> 3) & 7) << 3)];
      }
      const int sbase = sb0 + g * 8;
#pragma unroll
      for (int i = 0; i < 4; ++i) {
        const int L0 = (i * 4 + w) * 16;
        if (sb0 > L0 + 15) continue;
        const int l = L0 + (lane & 15);
        u16x8 cv = *(const u16x8*)(cbtb + ((long)(L0 >> 4) * 32 + (sbase >> 3)) * 128 + (l & 15) * 8);
        const float cl = csL[l];
        bf16x8 af;
#pragma unroll
        for (int e = 0; e < 8; ++e) {
          int s = sbase + e;
          float val = (s <= l) ? bf2f(cv[e]) * __expf(cl - csL[s]) * dtL[s] : 0.f;
          af[e] = (short)f2bf(val);
        }
#pragma unroll
        for (int j = 0; j < 4; ++j)
          acc[i][j] = __builtin_amdgcn_mfma_f32_16x16x32_bf16(af, bfr[j], acc[i][j], 0, 0, 0);
      }
    }
  }

  // ---- epilogue: skip connection + bf16 store ----
  const float Dh = Dp[h];
#pragma unroll
  for (int i = 0; i < 4; ++i) {
    int l0 = (i * 4 + w) * 16 + g * 4;
#pragma unroll
    for (int r = 0; r < 4; ++r) {
      long grow = rowbase + l0 + r;
      const unsigned short* xrow = xbc + grow * (long)CONV_DIM + h * HEADDIM;
      unsigned short* yrow = y + grow * (long)D_INNER + h * HEADDIM;
#pragma unroll
      for (int j = 0; j < 4; ++j) {
        int p = j * 16 + (lane & 15);
        yrow[p] = f2bf(acc[i][j][r] + bf2f(xrow[p]) * Dh);
      }
    }
  }
}

// ---------------- gated RMSNorm ----------------
__global__ __launch_bounds__(256) void k_norm(unsigned short* yz, const unsigned short* __restrict__ zb,
                                              const float* __restrict__ norm_w, unsigned short* out) {
  const int row = blockIdx.x;
  const int t = threadIdx.x;
  const unsigned short* yr = yz + (size_t)row * D_INNER;
  const unsigned short* zr = zb + (size_t)row * D_INNER;
  float yv[16];
  float ss = 0.f;
#pragma unroll
  for (int j = 0; j < 4; ++j) {
    int e = (t + j * 256) * 4;
    ushort4 yy = *(const ushort4*)(yr + e);
    ushort4 zz = *(const ushort4*)(zr + e);
    float z0 = bf2f(zz.x), z1 = bf2f(zz.y), z2 = bf2f(zz.z), z3 = bf2f(zz.w);
    float g0 = bf2f(yy.x) * z0 / (1.f + __expf(-z0));
    float g1 = bf2f(yy.y) * z1 / (1.f + __expf(-z1));
    float g2 = bf2f(yy.z) * z2 / (1.f + __expf(-z2));
    float g3 = bf2f(yy.w) * z3 / (1.f + __expf(-z3));
    ss += g0 * g0 + g1 * g1 + g2 * g2 + g3 * g3;
    yv[j * 4 + 0] = g0; yv[j * 4 + 1] = g1; yv[j * 4 + 2] = g2; yv[j * 4 + 3] = g3;
  }
#pragma unroll
  for (int off = 32; off > 0; off >>= 1) ss += __shfl_xor(ss, off);
  __shared__ float red[4];
  if ((t & 63) == 0) red[t >> 6] = ss;
  __syncthreads();
  float tot = red[0] + red[1] + red[2] + red[3];
  float scale = rsqrtf(tot / (float)D_INNER + EPSV);
  unsigned short* orow = out + (size_t)row * D_INNER;
#pragma unroll
  for (int j = 0; j < 4; ++j) {
    int e = (t + j * 256) * 4;
    float4 w = *(const float4*)(norm_w + e);
    ushort4 o = make_ushort4(f2bf(yv[j * 4 + 0] * scale * w.x), f2bf(yv[j * 4 + 1] * scale * w.y),
                             f2bf(yv[j * 4 + 2] * scale * w.z), f2bf(yv[j * 4 + 3] * scale * w.w));
    *(ushort4*)(orow + e) = o;
  }
}

extern "C" void kernel_launch(void* const* d_in, const int* in_sizes, int n_in,
                              void* d_out, int out_size, void* d_ws, size_t ws_size,
                              hipStream_t stream) {
  const float* u       = (const float*)d_in[0];
  const float* W_in    = (const float*)d_in[1];
  const float* conv_w  = (const float*)d_in[2];
  const float* conv_b  = (const float*)d_in[3];
  const float* dt_bias = (const float*)d_in[4];
  const float* A_log   = (const float*)d_in[5];
  const float* Dp      = (const float*)d_in[6];
  const float* norm_w  = (const float*)d_in[7];
  const float* W_out   = (const float*)d_in[8];
  float* out = (float*)d_out;

  char* ws = (char*)d_ws;
  size_t off = 0;
  auto alloc = [&](size_t bytes) { char* p = ws + off; off += (bytes + 255) & ~(size_t)255; return p; };
  unsigned short* ub   = (unsigned short*)alloc((size_t)NROWS * D_MODEL * 2);
  unsigned short* winb = (unsigned short*)alloc((size_t)D_IN_PROJ * D_MODEL * 2);
  unsigned short* zb   = (unsigned short*)alloc((size_t)NROWS * D_INNER * 2);
  unsigned short* xb   = (unsigned short*)alloc((size_t)NROWS * CONV_DIM * 2);
  unsigned short* xbcb = (unsigned short*)alloc((size_t)NROWS * CONV_DIM * 2);
  float* dtt  = (float*)alloc((size_t)BATCH * NHEADS * SEQ * 4);
  float* acum = (float*)alloc((size_t)BATCH * NHEADS * NCHUNK * CHUNK * 4);
  unsigned short* cwT = (unsigned short*)alloc((size_t)4 * CONV_DIM * 2);
  unsigned short* cbT = (unsigned short*)alloc((size_t)CONV_DIM * 2);
  unsigned short* whl = (unsigned short*)alloc((size_t)128 * D_MODEL * 2);
  float* PD = (float*)alloc((size_t)4 * BATCH * NHEADS * SEQ * 4);
  unsigned short* wob = ub;
  unsigned short* cbt = winb;
  unsigned short* psb = winb + (size_t)BATCH * NCHUNK * CHUNK * CHUNK + 1024;
  unsigned short* ulob = xbcb;
  unsigned short* yb = xb;
  float* states = (float*)d_out;

  if (off > ws_size) {
    k_sentinel<<<1, 64, 0, stream>>>(out);
    return;
  }

  k_prep<<<6673, 256, 0, stream>>>(u, ub, ulob, W_in, winb, whl, conv_w, conv_b, cwT, cbT);
  k_gemm8p<<<(NROWS / 256) * (D_INNER / 256), 512, 0, stream>>>(ub, winb, zb, NROWS, D_INNER, D_MODEL);
  k_gemm128<1><<<(NROWS / 128) * (CONV_DIM / 128), 256, 0, stream>>>(ub, winb + (size_t)D_INNER * D_MODEL, xb, NROWS, CONV_DIM, D_MODEL);
  k_dtm<<<256, 256, 0, stream>>>(ub, ulob, whl, PD);
  k_dtred<<<BATCH * NHEADS, 256, 0, stream>>>(PD, dt_bias, A_log, dtt, acum);
  k_conv_silu<<<(int)(((long)(NROWS / 4) * CG + 255) / 256), 256, 0, stream>>>(xb, cwT, cbT, xbcb);
  k_cbtt<<<BATCH * NCHUNK * 4, 256, 0, stream>>>(xbcb, cbt);
  k_states<<<BATCH * NCHUNK * NHEADS, 256, 0, stream>>>(xbcb, dtt, acum, states);
  k_scan<<<(BATCH * NHEADS * D_STATE * HEADDIM + 255) / 256, 256, 0, stream>>>(states, acum, psb);
  k_y<<<BATCH * NCHUNK * NHEADS, 256, 0, stream>>>(xbcb, dtt, acum, cbt, psb, Dp, yb);
  k_norm<<<NROWS, 256, 0, stream>>>(yb, zb, norm_w, yb);
  k_f32_to_bf16_v4<<<2048, 256, 0, stream>>>(W_out, wob, (long)D_MODEL * D_INNER / 4);
  k_gemm128<0><<<(NROWS / 128) * (D_MODEL / 128), 256, 0, stream>>>(yb, wob, out, NROWS, D_MODEL, D_INNER);
}